// Round 9
// baseline (1286.862 us; speedup 1.0000x reference)
//
#include <hip/hip_runtime.h>
#include <math.h>

#define KNNK 20

typedef unsigned short u16;
typedef unsigned int u32;
typedef unsigned long long u64;
typedef __attribute__((ext_vector_type(8))) short short8v;   // 8 bf16 (4 VGPRs)
typedef __attribute__((ext_vector_type(4))) float f32x4;     // MFMA accumulator

__device__ __forceinline__ float lrelu(float v) { return v >= 0.f ? v : 0.2f * v; }

// round-to-nearest-even fp32 -> bf16 (bit trick)
__device__ __forceinline__ u16 f2bf(float v) {
    u32 u = __float_as_uint(v);
    u += 0x7fffu + ((u >> 16) & 1u);
    return (u16)(u >> 16);
}
__device__ __forceinline__ float bf2f(u16 h) { return __uint_as_float(((u32)h) << 16); }

// monotonic fp32 -> u32 map: a > b (float, no NaN)  <=>  ordf(a) > ordf(b) (uint)
__device__ __forceinline__ u32 ordf(float v) {
    u32 u = __float_as_uint(v);
    return u ^ ((u32)((int)u >> 31) | 0x80000000u);
}
// (value desc, index asc) total order as single u64
__device__ __forceinline__ u64 mkkey(float v, int g) {
    return ((u64)ordf(v) << 32) | (u32)(~(u32)g);
}

// 8 contiguous fp32 (LDS) -> three bf16x8 limb fragments (exact 3-way split, round-2-validated)
__device__ __forceinline__ void cvt8(const float* __restrict__ p, short8v& H8, short8v& M8, short8v& L8) {
    float4 a = *(const float4*)(p);
    float4 b4 = *(const float4*)(p + 4);
    float v[8] = {a.x, a.y, a.z, a.w, b4.x, b4.y, b4.z, b4.w};
    short8v H, M, L;
#pragma unroll
    for (int i = 0; i < 8; ++i) {
        float x = v[i];
        u16 h = f2bf(x);
        float r1 = x - bf2f(h);    // exact
        u16 m = f2bf(r1);
        float r2 = r1 - bf2f(m);   // exact
        H[i] = (short)h;
        M[i] = (short)m;
        L[i] = (short)f2bf(r2);
    }
    H8 = H; M8 = M; L8 = L;
}

// ---------------- xx[b][n] = sum_c f[b][c][n]^2 ----------------
__global__ __launch_bounds__(256) void xx_kernel(const float* __restrict__ f, long bstride, int C,
                                                 float* __restrict__ xx) {
    int i = blockIdx.x * 256 + threadIdx.x;   // over B*N
    int b = i >> 11, n = i & 2047;
    const float* fb = f + (long)b * bstride;
    float s = 0.f;
    for (int c = 0; c < C; ++c) { float v = fb[c * 2048 + n]; s = fmaf(v, v, s); }
    xx[i] = s;
}

// ---------------- shared top-20 selection over 2048 (exact, order = JAX top_k) ----------------
__device__ __forceinline__ void topk_row(const float* __restrict__ srow, int lane, int* __restrict__ orow) {
    float b1 = -INFINITY, b2 = -INFINITY, b3 = -INFINITY;
    int j1 = 0, j2 = 0, j3 = 0;
#pragma unroll
    for (int j = 0; j < 32; ++j) {
        float vv = srow[lane + 64 * j];
        bool c1 = vv > b1;
        bool c2 = vv > b2;
        bool c3 = vv > b3;
        b3 = c2 ? b2 : (c3 ? vv : b3);
        j3 = c2 ? j2 : (c3 ? j : j3);
        b2 = c1 ? b1 : (c2 ? vv : b2);
        j2 = c1 ? j1 : (c2 ? j : j2);
        b1 = c1 ? vv : b1;
        j1 = c1 ? j : j1;
    }
    u64 ka = mkkey(b1, lane + (j1 << 6));
#pragma unroll
    for (int size = 2; size <= 64; size <<= 1) {
#pragma unroll
        for (int stride = size >> 1; stride >= 1; stride >>= 1) {
            u64 ok = __shfl_xor(ka, stride);
            bool low = (lane & stride) == 0;
            bool asc = (lane & size) == 0;
            bool f = ka > ok;
            bool take = (low == asc) ? f : !f;
            ka = take ? ka : ok;
        }
    }
    u64 w19 = __shfl(ka, 19);
    unsigned used = (1u << j1) | (1u << j2) | (1u << j3);
    u64 pend = mkkey(b2, lane + (j2 << 6));
    int pstate = 0;
    while (__any(pend > w19)) {
        u64 act = __ballot(pend > w19);
        int L = __ffsll((long long)act) - 1;
        u64 ck = __shfl(pend, L);
        u64 cfb = __ballot(lane < 20 && ck > ka);
        int p = 20 - __popcll(cfb);
        u64 up = __shfl_up(ka, 1);
        if (lane < 20) {
            if (lane > p) ka = up;
            else if (lane == p) ka = ck;
        }
        if (lane == L) {
            if (pstate == 0) {
                pend = mkkey(b3, lane + (j3 << 6));
                pstate = 1;
            } else {
                float nb = -INFINITY;
                int nj = 0;
#pragma unroll
                for (int j = 0; j < 32; ++j) {
                    float vvv = ((used >> j) & 1u) ? -INFINITY : srow[lane + 64 * j];
                    if (vvv > nb) { nb = vvv; nj = j; }
                }
                used |= 1u << nj;
                pend = mkkey(nb, lane + (nj << 6));
            }
        }
        w19 = __shfl(ka, 19);
    }
    if (lane < KNNK) orow[lane] = (int)(~(u32)ka) & 2047;
}

// ---------------- top-20 over a 1024-col half row; returns sorted key (lanes 0..19 = ranks) ----------------
// (r7-validated: exact same u64-key total order; indices are colbase-global)
__device__ __forceinline__ u64 topk20_half(const float* __restrict__ srow, int lane, int colbase) {
    float b1 = -INFINITY, b2 = -INFINITY, b3 = -INFINITY;
    int j1 = 0, j2 = 0, j3 = 0;
#pragma unroll
    for (int j = 0; j < 16; ++j) {
        float vv = srow[lane + 64 * j];
        bool c1 = vv > b1;
        bool c2 = vv > b2;
        bool c3 = vv > b3;
        b3 = c2 ? b2 : (c3 ? vv : b3);
        j3 = c2 ? j2 : (c3 ? j : j3);
        b2 = c1 ? b1 : (c2 ? vv : b2);
        j2 = c1 ? j1 : (c2 ? j : j2);
        b1 = c1 ? vv : b1;
        j1 = c1 ? j : j1;
    }
    u64 ka = mkkey(b1, colbase + lane + (j1 << 6));
#pragma unroll
    for (int size = 2; size <= 64; size <<= 1) {
#pragma unroll
        for (int stride = size >> 1; stride >= 1; stride >>= 1) {
            u64 ok = __shfl_xor(ka, stride);
            bool low = (lane & stride) == 0;
            bool asc = (lane & size) == 0;
            bool f = ka > ok;
            bool take = (low == asc) ? f : !f;
            ka = take ? ka : ok;
        }
    }
    u64 w19 = __shfl(ka, 19);
    unsigned used = (1u << j1) | (1u << j2) | (1u << j3);
    u64 pend = mkkey(b2, colbase + lane + (j2 << 6));
    int pstate = 0;
    while (__any(pend > w19)) {
        u64 act = __ballot(pend > w19);
        int L = __ffsll((long long)act) - 1;
        u64 ck = __shfl(pend, L);
        u64 cfb = __ballot(lane < 20 && ck > ka);
        int p = 20 - __popcll(cfb);
        u64 up = __shfl_up(ka, 1);
        if (lane < 20) {
            if (lane > p) ka = up;
            else if (lane == p) ka = ck;
        }
        if (lane == L) {
            if (pstate == 0) {
                pend = mkkey(b3, colbase + lane + (j3 << 6));
                pstate = 1;
            } else {
                float nb = -INFINITY;
                int nj = 0;
#pragma unroll
                for (int j = 0; j < 16; ++j) {
                    float vvv = ((used >> j) & 1u) ? -INFINITY : srow[lane + 64 * j];
                    if (vvv > nb) { nb = vvv; nj = j; }
                }
                used |= 1u << nj;
                pend = mkkey(nb, colbase + lane + (nj << 6));
            }
        }
        w19 = __shfl(ka, 19);
    }
    return ka;
}

// ---------------- exact merge of two sorted top-20 key lists (r7-validated) ----------------
__device__ __forceinline__ u64 merge20(u64 kA, u64 kB, int lane) {
    u64 kb = __shfl(kB, (lane - 20) & 63);
    u64 ka = lane < 20 ? kA : (lane < 40 ? kb : 0ULL);   // 0 < any real key (ordf>0)
#pragma unroll
    for (int size = 2; size <= 64; size <<= 1) {
#pragma unroll
        for (int stride = size >> 1; stride >= 1; stride >>= 1) {
            u64 ok = __shfl_xor(ka, stride);
            bool low = (lane & stride) == 0;
            bool asc = (lane & size) == 0;
            bool f = ka > ok;
            bool take = (low == asc) ? f : !f;
            ka = take ? ka : ok;
        }
    }
    return ka;
}

// ---------------- KNN (fp32 Gram, scalar fma): 16-row strip, two topk phases ----------------
// (stage 1 C=2 + fallback; r5-validated)
__global__ __launch_bounds__(512, 4) void knn_kernel(const float* __restrict__ f, long bstride, int C,
                                                     const float* __restrict__ xx, int* __restrict__ idx_out) {
    __shared__ __align__(16) float pd[8 * 2048];
    __shared__ __align__(16) float Asm[16 * 64];
    int b = blockIdx.y;
    int n0 = blockIdx.x * 16;
    int t = threadIdx.x;
    const float* fb = f + (long)b * bstride;

    for (int e = t; e < C * 16; e += 512) {
        int c = e >> 4, j = e & 15;
        Asm[e] = fb[c * 2048 + n0 + j];
    }
    __syncthreads();

    float acc[16][4];
#pragma unroll
    for (int i = 0; i < 16; ++i)
#pragma unroll
        for (int j = 0; j < 4; ++j) acc[i][j] = 0.f;
    int m0 = t * 4;
    for (int c = 0; c < C; ++c) {
        float4 b4 = *(const float4*)(fb + c * 2048 + m0);
        float bv[4] = {b4.x, b4.y, b4.z, b4.w};
        const float* ar = Asm + c * 16;
        float4 a0 = *(const float4*)(ar);
        float4 a1 = *(const float4*)(ar + 4);
        float4 a2 = *(const float4*)(ar + 8);
        float4 a3 = *(const float4*)(ar + 12);
        float av[16] = {a0.x, a0.y, a0.z, a0.w, a1.x, a1.y, a1.z, a1.w,
                        a2.x, a2.y, a2.z, a2.w, a3.x, a3.y, a3.z, a3.w};
#pragma unroll
        for (int i = 0; i < 16; ++i)
#pragma unroll
            for (int j = 0; j < 4; ++j) acc[i][j] = fmaf(av[i], bv[j], acc[i][j]);
    }
    float4 xm4 = *(const float4*)(xx + b * 2048 + m0);
    float xm[4] = {xm4.x, xm4.y, xm4.z, xm4.w};

    int wave = t >> 6, lane = t & 63;

    {
        float4 xa0 = *(const float4*)(xx + b * 2048 + n0);
        float4 xa1 = *(const float4*)(xx + b * 2048 + n0 + 4);
        float xn[8] = {xa0.x, xa0.y, xa0.z, xa0.w, xa1.x, xa1.y, xa1.z, xa1.w};
#pragma unroll
        for (int i = 0; i < 8; ++i) {
            float4 o;
            o.x = (2.f * acc[i][0] - xn[i]) - xm[0];
            o.y = (2.f * acc[i][1] - xn[i]) - xm[1];
            o.z = (2.f * acc[i][2] - xn[i]) - xm[2];
            o.w = (2.f * acc[i][3] - xn[i]) - xm[3];
            *(float4*)(pd + i * 2048 + m0) = o;
        }
    }
    __syncthreads();
    topk_row(pd + wave * 2048, lane, idx_out + ((long)b * 2048 + n0 + wave) * KNNK);
    __syncthreads();

    {
        float4 xb0 = *(const float4*)(xx + b * 2048 + n0 + 8);
        float4 xb1 = *(const float4*)(xx + b * 2048 + n0 + 12);
        float xn[8] = {xb0.x, xb0.y, xb0.z, xb0.w, xb1.x, xb1.y, xb1.z, xb1.w};
#pragma unroll
        for (int i = 0; i < 8; ++i) {
            float4 o;
            o.x = (2.f * acc[8 + i][0] - xn[i]) - xm[0];
            o.y = (2.f * acc[8 + i][1] - xn[i]) - xm[1];
            o.z = (2.f * acc[8 + i][2] - xn[i]) - xm[2];
            o.w = (2.f * acc[8 + i][3] - xn[i]) - xm[3];
            *(float4*)(pd + i * 2048 + m0) = o;
        }
    }
    __syncthreads();
    topk_row(pd + wave * 2048, lane, idx_out + ((long)b * 2048 + n0 + 8 + wave) * KNNK);
}

// ---------------- exact 3-way bf16 split + transpose: panel [64][2048] -> [b][2048][64] ----------------
__global__ __launch_bounds__(256) void split3t_kernel(const float* __restrict__ src, long bstride,
                                                      u16* __restrict__ oh, u16* __restrict__ om,
                                                      u16* __restrict__ ol) {
    __shared__ float lds[32][65];
    int b = blockIdx.y;
    int kt = blockIdx.x & 1, nt = blockIdx.x >> 1;
    int k0 = kt * 32, n0 = nt * 64, t = threadIdx.x;
#pragma unroll
    for (int i = 0; i < 8; ++i) {
        int e = t + i * 256;
        int k = e >> 6, n = e & 63;
        lds[k][n] = src[(long)b * bstride + (long)(k0 + k) * 2048 + n0 + n];
    }
    __syncthreads();
    int n = t >> 2, kq = t & 3;
    u16 hv[8], mv[8], lv[8];
#pragma unroll
    for (int i = 0; i < 8; ++i) {
        float v = lds[kq * 8 + i][n];
        u16 h = f2bf(v);
        float r1 = v - bf2f(h);
        u16 m = f2bf(r1);
        float r2 = r1 - bf2f(m);
        hv[i] = h; mv[i] = m; lv[i] = f2bf(r2);
    }
    long off = ((long)b * 2048 + n0 + n) * 64 + k0 + kq * 8;
    uint4 uh, um, ul;
    uh.x = (u32)hv[0] | ((u32)hv[1] << 16); uh.y = (u32)hv[2] | ((u32)hv[3] << 16);
    uh.z = (u32)hv[4] | ((u32)hv[5] << 16); uh.w = (u32)hv[6] | ((u32)hv[7] << 16);
    um.x = (u32)mv[0] | ((u32)mv[1] << 16); um.y = (u32)mv[2] | ((u32)mv[3] << 16);
    um.z = (u32)mv[4] | ((u32)mv[5] << 16); um.w = (u32)mv[6] | ((u32)mv[7] << 16);
    ul.x = (u32)lv[0] | ((u32)lv[1] << 16); ul.y = (u32)lv[2] | ((u32)lv[3] << 16);
    ul.z = (u32)lv[4] | ((u32)lv[5] << 16); ul.w = (u32)lv[6] | ((u32)lv[7] << 16);
    *(uint4*)(oh + off) = uh;
    *(uint4*)(om + off) = um;
    *(uint4*)(ol + off) = ul;
}

// ---------------- KNN hybrid (C=64, stages 2 & 3): MFMA waves + VALU waves co-scheduled ----------------
// Waves 0-1: bf16x6 MFMA Gram (r7-validated chain, 2-deep prefetch), 320 cols/half each.
// Waves 2-7: scalar fp32 Gram (reference-bitwise chains), 64 cols/half each (1 col/thread, 16 rows).
// m114: MFMA and VALU pipes co-schedule -> MFMA latency hidden by VALU waves and vice versa.
// Selection: r7-validated topk20_half per column-half + exact merge20.
__global__ __launch_bounds__(512, 4) void knn_hybrid_kernel(
    const float* __restrict__ f, long bstride, const u16* __restrict__ Sh, const u16* __restrict__ Sm,
    const u16* __restrict__ Sl, const float* __restrict__ xx, int* __restrict__ idx_out) {
    __shared__ __align__(16) float pd[16 * 1028];
    __shared__ __align__(16) float Asm[64 * 16];   // [c][row]
    int b = blockIdx.y, n0 = blockIdx.x * 16, t = threadIdx.x;
    int wave = t >> 6, lane = t & 63, l15 = lane & 15, lq = lane >> 4;
    const float* fb = f + (long)b * bstride;
    const u16* bh_ = Sh + (long)b * 2048 * 64;
    const u16* bm_ = Sm + (long)b * 2048 * 64;
    const u16* bl_ = Sl + (long)b * 2048 * 64;

    for (int e = t; e < 64 * 16; e += 512) {
        int c = e >> 4, j = e & 15;
        Asm[e] = fb[c * 2048 + n0 + j];
    }

    // MFMA A fragments (rows n0..n0+15): row n0+l15, k-octet lq*8, two k-halves (r7 verbatim)
    short8v ah0 = {}, ah1 = {}, am0 = {}, am1 = {}, al0 = {}, al1 = {};
    float xnm[4] = {0.f, 0.f, 0.f, 0.f};
    float xnv[16];
    if (wave < 2) {
        long ab = (long)(n0 + l15) * 64 + lq * 8;
        ah0 = *(const short8v*)(bh_ + ab); ah1 = *(const short8v*)(bh_ + ab + 32);
        am0 = *(const short8v*)(bm_ + ab); am1 = *(const short8v*)(bm_ + ab + 32);
        al0 = *(const short8v*)(bl_ + ab); al1 = *(const short8v*)(bl_ + ab + 32);
        float4 xn4 = *(const float4*)(xx + b * 2048 + n0 + lq * 4);
        xnm[0] = xn4.x; xnm[1] = xn4.y; xnm[2] = xn4.z; xnm[3] = xn4.w;
    } else {
#pragma unroll
        for (int i = 0; i < 16; ++i) xnv[i] = xx[b * 2048 + n0 + i];
    }
    __syncthreads();

    u64 kA0 = 0, kA1 = 0, kB0 = 0, kB1 = 0;
#pragma unroll 1
    for (int half = 0; half < 2; ++half) {
        if (wave < 2) {
            // ---- MFMA waves: 20 tiles of 16 cols, 2-deep prefetch (r7 pattern) ----
            int jb = half * 1024 + wave * 320;
            short8v Bh0[2], Bh1[2], Bm0[2], Bm1[2], Bl0[2], Bl1[2];
            {
                long bb = (long)(jb + l15) * 64 + lq * 8;
                Bh0[0] = *(const short8v*)(bh_ + bb); Bh1[0] = *(const short8v*)(bh_ + bb + 32);
                Bm0[0] = *(const short8v*)(bm_ + bb); Bm1[0] = *(const short8v*)(bm_ + bb + 32);
                Bl0[0] = *(const short8v*)(bl_ + bb); Bl1[0] = *(const short8v*)(bl_ + bb + 32);
            }
#pragma unroll 2
            for (int tt = 0; tt < 20; ++tt) {
                const int cur = tt & 1, nxt = cur ^ 1;
                if (tt < 19) {
                    long bb = (long)(jb + (tt + 1) * 16 + l15) * 64 + lq * 8;
                    Bh0[nxt] = *(const short8v*)(bh_ + bb); Bh1[nxt] = *(const short8v*)(bh_ + bb + 32);
                    Bm0[nxt] = *(const short8v*)(bm_ + bb); Bm1[nxt] = *(const short8v*)(bm_ + bb + 32);
                    Bl0[nxt] = *(const short8v*)(bl_ + bb); Bl1[nxt] = *(const short8v*)(bl_ + bb + 32);
                }
                f32x4 p = {0.f, 0.f, 0.f, 0.f}, q = {0.f, 0.f, 0.f, 0.f};
                p = __builtin_amdgcn_mfma_f32_16x16x32_bf16(ah0, Bh0[cur], p, 0, 0, 0);
                q = __builtin_amdgcn_mfma_f32_16x16x32_bf16(ah0, Bm0[cur], q, 0, 0, 0);
                p = __builtin_amdgcn_mfma_f32_16x16x32_bf16(am0, Bh0[cur], p, 0, 0, 0);
                q = __builtin_amdgcn_mfma_f32_16x16x32_bf16(am0, Bm0[cur], q, 0, 0, 0);
                p = __builtin_amdgcn_mfma_f32_16x16x32_bf16(ah0, Bl0[cur], p, 0, 0, 0);
                q = __builtin_amdgcn_mfma_f32_16x16x32_bf16(al0, Bh0[cur], q, 0, 0, 0);
                p = __builtin_amdgcn_mfma_f32_16x16x32_bf16(ah1, Bh1[cur], p, 0, 0, 0);
                q = __builtin_amdgcn_mfma_f32_16x16x32_bf16(ah1, Bm1[cur], q, 0, 0, 0);
                p = __builtin_amdgcn_mfma_f32_16x16x32_bf16(am1, Bh1[cur], p, 0, 0, 0);
                q = __builtin_amdgcn_mfma_f32_16x16x32_bf16(am1, Bm1[cur], q, 0, 0, 0);
                p = __builtin_amdgcn_mfma_f32_16x16x32_bf16(ah1, Bl1[cur], p, 0, 0, 0);
                q = __builtin_amdgcn_mfma_f32_16x16x32_bf16(al1, Bh1[cur], q, 0, 0, 0);
                int col = jb + tt * 16 + l15;
                float xmc = xx[(long)b * 2048 + col];
                f32x4 r = p + q;
                int lcol = col - half * 1024;
                pd[(lq * 4 + 0) * 1028 + lcol] = (2.f * r[0] - xnm[0]) - xmc;
                pd[(lq * 4 + 1) * 1028 + lcol] = (2.f * r[1] - xnm[1]) - xmc;
                pd[(lq * 4 + 2) * 1028 + lcol] = (2.f * r[2] - xnm[2]) - xmc;
                pd[(lq * 4 + 3) * 1028 + lcol] = (2.f * r[3] - xnm[3]) - xmc;
            }
        } else {
            // ---- VALU waves: 64 cols each, 1 col/thread x 16 rows (reference-bitwise chains) ----
            int col = half * 1024 + 640 + (wave - 2) * 64 + lane;
            float acc[16];
#pragma unroll
            for (int i = 0; i < 16; ++i) acc[i] = 0.f;
            for (int c = 0; c < 64; ++c) {
                float bv = fb[c * 2048 + col];
                const float* ar = Asm + c * 16;
                float4 a0 = *(const float4*)(ar);
                float4 a1 = *(const float4*)(ar + 4);
                float4 a2 = *(const float4*)(ar + 8);
                float4 a3 = *(const float4*)(ar + 12);
                float av[16] = {a0.x, a0.y, a0.z, a0.w, a1.x, a1.y, a1.z, a1.w,
                                a2.x, a2.y, a2.z, a2.w, a3.x, a3.y, a3.z, a3.w};
#pragma unroll
                for (int i = 0; i < 16; ++i) acc[i] = fmaf(av[i], bv, acc[i]);
            }
            float xmc = xx[(long)b * 2048 + col];
            int lcol = col - half * 1024;
#pragma unroll
            for (int i = 0; i < 16; ++i) pd[i * 1028 + lcol] = (2.f * acc[i] - xnv[i]) - xmc;
        }
        __syncthreads();   // pd complete for this half
        if (half == 0) {
            kA0 = topk20_half(pd + (2 * wave) * 1028, lane, 0);
            kA1 = topk20_half(pd + (2 * wave + 1) * 1028, lane, 0);
            __syncthreads();   // all reads done before half-1 overwrites pd
        } else {
            kB0 = topk20_half(pd + (2 * wave) * 1028, lane, 1024);
            kB1 = topk20_half(pd + (2 * wave + 1) * 1028, lane, 1024);
        }
    }
    u64 f0 = merge20(kA0, kB0, lane);
    u64 f1 = merge20(kA1, kB1, lane);
    if (lane < KNNK) {
        idx_out[((long)b * 2048 + n0 + 2 * wave) * KNNK + lane] = (int)(~(u32)f0) & 2047;
        idx_out[((long)b * 2048 + n0 + 2 * wave + 1) * KNNK + lane] = (int)(~(u32)f1) & 2047;
    }
}

// ---------------- P = Wa @ f, Q = (Wb - Wa) @ f, stored (B, N, 64) n-major ----------------
__global__ __launch_bounds__(256) void pq_kernel(const float* __restrict__ f, long bstride, int C,
                                                 const float* __restrict__ W, float* __restrict__ P,
                                                 float* __restrict__ Q) {
    __shared__ __align__(16) float wa[64 * 64];
    __shared__ __align__(16) float wq[64 * 64];
    __shared__ __align__(16) float X[64 * 64];
    int b = blockIdx.y, n0 = blockIdx.x * 64, t = threadIdx.x;
    const float* fb = f + (long)b * bstride;
    for (int e = t; e < C * 64; e += 256) {
        int k = e >> 6, c = e & 63;
        float a = W[c * 2 * C + k];
        float bv = W[c * 2 * C + C + k];
        wa[k * 64 + c] = a;
        wq[k * 64 + c] = bv - a;
    }
    for (int e = t; e < C * 64; e += 256) {
        int k = e >> 6, j = e & 63;
        X[e] = fb[k * 2048 + n0 + j];
    }
    __syncthreads();
    int cg = t >> 4, ng = t & 15;
    float accP[4][4] = {}, accQ[4][4] = {};
    for (int k = 0; k < C; ++k) {
        float4 a4 = *(const float4*)(wa + k * 64 + cg * 4);
        float4 q4 = *(const float4*)(wq + k * 64 + cg * 4);
        float4 x4 = *(const float4*)(X + k * 64 + ng * 4);
        float av[4] = {a4.x, a4.y, a4.z, a4.w};
        float qv[4] = {q4.x, q4.y, q4.z, q4.w};
        float xv[4] = {x4.x, x4.y, x4.z, x4.w};
#pragma unroll
        for (int i = 0; i < 4; ++i)
#pragma unroll
            for (int j = 0; j < 4; ++j) {
                accP[i][j] = fmaf(av[i], xv[j], accP[i][j]);
                accQ[i][j] = fmaf(qv[i], xv[j], accQ[i][j]);
            }
    }
#pragma unroll
    for (int j = 0; j < 4; ++j) {
        long n = n0 + ng * 4 + j;
        float4 pv = {accP[0][j], accP[1][j], accP[2][j], accP[3][j]};
        float4 qv = {accQ[0][j], accQ[1][j], accQ[2][j], accQ[3][j]};
        *(float4*)(P + ((long)b * 2048 + n) * 64 + cg * 4) = pv;
        *(float4*)(Q + ((long)b * 2048 + n) * 64 + cg * 4) = qv;
    }
}

// ---------------- 3-limb bf16 split of a 64x64 weight (elementwise, [co][ci] kept) ----------------
__global__ __launch_bounds__(256) void splitw3_kernel(const float* __restrict__ W, u16* __restrict__ h,
                                                      u16* __restrict__ m, u16* __restrict__ l) {
    int i = blockIdx.x * 256 + threadIdx.x;   // < 4096
    float v = W[i];
    u16 hh = f2bf(v);
    float r1 = v - bf2f(hh);
    u16 mm = f2bf(r1);
    float r2 = r1 - bf2f(mm);
    h[i] = hh;
    m[i] = mm;
    l[i] = f2bf(r2);
}

// ---------------- EdgeConv layer-2 + max over k via MFMA (bf16x6, stages 1 & 2) ----------------
__global__ __launch_bounds__(256) void edge2_mfma_kernel(
    const float* __restrict__ P, const float* __restrict__ Q, const int* __restrict__ idx,
    const u16* __restrict__ Wh, const u16* __restrict__ Wm, const u16* __restrict__ Wl,
    const float* __restrict__ sa, const float* __restrict__ ta, const float* __restrict__ sb,
    const float* __restrict__ tb, float* __restrict__ out, int cofs) {
    __shared__ __align__(16) float h1t[192 * 68];   // [col][ci] fp32, pad 68; reused as h2 [col][co]
    __shared__ int idxl[160];
    int b = blockIdx.y, n0 = blockIdx.x * 8, t = threadIdx.x;
    if (t < 160) idxl[t] = idx[((long)b * 2048 + n0) * KNNK + t];
    __syncthreads();

    for (int it = t; it < 2560; it += 256) {
        int col = it % 160, cg = it / 160;
        int p = col / 20;
        int j = idxl[col];
        int n = n0 + p;
        float4 pv = *(const float4*)(P + ((long)b * 2048 + j) * 64 + cg * 4);
        float4 qv = *(const float4*)(Q + ((long)b * 2048 + n) * 64 + cg * 4);
        float4 sv = *(const float4*)(sa + cg * 4);
        float4 tv = *(const float4*)(ta + cg * 4);
        float4 o;
        o.x = lrelu(fmaf(sv.x, pv.x + qv.x, tv.x));
        o.y = lrelu(fmaf(sv.y, pv.y + qv.y, tv.y));
        o.z = lrelu(fmaf(sv.z, pv.z + qv.z, tv.z));
        o.w = lrelu(fmaf(sv.w, pv.w + qv.w, tv.w));
        *(float4*)(h1t + col * 68 + cg * 4) = o;
    }
    for (int it = t; it < 512; it += 256) {
        int col = 160 + (it & 31), cg = it >> 5;
        float4 z = {0.f, 0.f, 0.f, 0.f};
        *(float4*)(h1t + col * 68 + cg * 4) = z;
    }
    __syncthreads();

    int wave = t >> 6, lane = t & 63, l15 = lane & 15, lq = lane >> 4;
    f32x4 acc[3][4];
#pragma unroll
    for (int ct = 0; ct < 3; ++ct)
#pragma unroll
        for (int mt = 0; mt < 4; ++mt) {
            f32x4 z = {0.f, 0.f, 0.f, 0.f};
            acc[ct][mt] = z;
        }

#pragma unroll
    for (int ct = 0; ct < 3; ++ct) {
        int col = (wave * 3 + ct) * 16 + l15;
        short8v bh[2], bm[2], bl[2];
#pragma unroll
        for (int kh = 0; kh < 2; ++kh) cvt8(h1t + col * 68 + kh * 32 + lq * 8, bh[kh], bm[kh], bl[kh]);
#pragma unroll
        for (int mt = 0; mt < 4; ++mt) {
#pragma unroll
            for (int kh = 0; kh < 2; ++kh) {
                int wo = (mt * 16 + l15) * 64 + kh * 32 + lq * 8;
                short8v ah = *(const short8v*)(Wh + wo);
                short8v am = *(const short8v*)(Wm + wo);
                short8v al = *(const short8v*)(Wl + wo);
                acc[ct][mt] = __builtin_amdgcn_mfma_f32_16x16x32_bf16(ah, bh[kh], acc[ct][mt], 0, 0, 0);
                acc[ct][mt] = __builtin_amdgcn_mfma_f32_16x16x32_bf16(ah, bm[kh], acc[ct][mt], 0, 0, 0);
                acc[ct][mt] = __builtin_amdgcn_mfma_f32_16x16x32_bf16(am, bh[kh], acc[ct][mt], 0, 0, 0);
                acc[ct][mt] = __builtin_amdgcn_mfma_f32_16x16x32_bf16(am, bm[kh], acc[ct][mt], 0, 0, 0);
                acc[ct][mt] = __builtin_amdgcn_mfma_f32_16x16x32_bf16(ah, bl[kh], acc[ct][mt], 0, 0, 0);
                acc[ct][mt] = __builtin_amdgcn_mfma_f32_16x16x32_bf16(al, bh[kh], acc[ct][mt], 0, 0, 0);
            }
        }
    }
    __syncthreads();

#pragma unroll
    for (int ct = 0; ct < 3; ++ct) {
        int col = (wave * 3 + ct) * 16 + l15;
#pragma unroll
        for (int mt = 0; mt < 4; ++mt) {
            float4 d = {acc[ct][mt][0], acc[ct][mt][1], acc[ct][mt][2], acc[ct][mt][3]};
            *(float4*)(h1t + col * 68 + mt * 16 + lq * 4) = d;
        }
    }
    __syncthreads();

    for (int id = t; id < 512; id += 256) {
        int co = id & 63, p = id >> 6;
        float sv = sb[co], tv = tb[co];
        float m = -INFINITY;
#pragma unroll 4
        for (int kk = 0; kk < KNNK; ++kk)
            m = fmaxf(m, lrelu(fmaf(sv, h1t[(p * 20 + kk) * 68 + co], tv)));
        out[(long)b * (192 * 2048) + (long)(cofs + co) * 2048 + n0 + p] = m;
    }
}

// ---------------- EdgeConv layer-2 fp32 (fallback path) ----------------
__global__ __launch_bounds__(256) void edge2_kernel(
    const float* __restrict__ P, const float* __restrict__ Q, const int* __restrict__ idx,
    const float* __restrict__ W2, const float* __restrict__ sa, const float* __restrict__ ta,
    const float* __restrict__ sb, const float* __restrict__ tb, float* __restrict__ out, int cofs) {
    __shared__ __align__(16) float h1[64 * 164];
    __shared__ __align__(16) float w2l[64 * 64];
    __shared__ int idxl[160];
    int b = blockIdx.y, n0 = blockIdx.x * 8, t = threadIdx.x;
    if (t < 160) idxl[t] = idx[((long)b * 2048 + n0) * KNNK + t];
    for (int e = t; e < 4096; e += 256) { int co = e >> 6, ci = e & 63; w2l[ci * 64 + co] = W2[e]; }
    __syncthreads();
    for (int it = t; it < 2560; it += 256) {
        int col = it % 160, cg = it / 160;
        int p = col / 20;
        int j = idxl[col];
        int n = n0 + p;
        float4 pv = *(const float4*)(P + ((long)b * 2048 + j) * 64 + cg * 4);
        float4 qv = *(const float4*)(Q + ((long)b * 2048 + n) * 64 + cg * 4);
        float4 sv = *(const float4*)(sa + cg * 4);
        float4 tv = *(const float4*)(ta + cg * 4);
        h1[(cg * 4 + 0) * 164 + col] = lrelu(fmaf(sv.x, pv.x + qv.x, tv.x));
        h1[(cg * 4 + 1) * 164 + col] = lrelu(fmaf(sv.y, pv.y + qv.y, tv.y));
        h1[(cg * 4 + 2) * 164 + col] = lrelu(fmaf(sv.z, pv.z + qv.z, tv.z));
        h1[(cg * 4 + 3) * 164 + col] = lrelu(fmaf(sv.w, pv.w + qv.w, tv.w));
    }
    __syncthreads();
    int p = t & 7, co2 = t >> 3, c0 = co2 * 2;
    float acc0[20], acc1[20];
#pragma unroll
    for (int q = 0; q < 20; ++q) { acc0[q] = 0.f; acc1[q] = 0.f; }
#pragma unroll 4
    for (int k = 0; k < 64; ++k) {
        float2 w = *(const float2*)(w2l + k * 64 + c0);
        const float* hr = h1 + k * 164 + p * 20;
#pragma unroll
        for (int q = 0; q < 5; ++q) {
            float4 h4 = *(const float4*)(hr + q * 4);
            acc0[q * 4 + 0] = fmaf(w.x, h4.x, acc0[q * 4 + 0]);
            acc0[q * 4 + 1] = fmaf(w.x, h4.y, acc0[q * 4 + 1]);
            acc0[q * 4 + 2] = fmaf(w.x, h4.z, acc0[q * 4 + 2]);
            acc0[q * 4 + 3] = fmaf(w.x, h4.w, acc0[q * 4 + 3]);
            acc1[q * 4 + 0] = fmaf(w.y, h4.x, acc1[q * 4 + 0]);
            acc1[q * 4 + 1] = fmaf(w.y, h4.y, acc1[q * 4 + 1]);
            acc1[q * 4 + 2] = fmaf(w.y, h4.z, acc1[q * 4 + 2]);
            acc1[q * 4 + 3] = fmaf(w.y, h4.w, acc1[q * 4 + 3]);
        }
    }
    float s0 = sb[c0], t0v = tb[c0], s1 = sb[c0 + 1], t1v = tb[c0 + 1];
    float m0 = -INFINITY, m1 = -INFINITY;
#pragma unroll
    for (int q = 0; q < 20; ++q) {
        m0 = fmaxf(m0, lrelu(fmaf(s0, acc0[q], t0v)));
        m1 = fmaxf(m1, lrelu(fmaf(s1, acc1[q], t1v)));
    }
    out[(long)b * (192 * 2048) + (long)(cofs + c0) * 2048 + n0 + p] = m0;
    out[(long)b * (192 * 2048) + (long)(cofs + c0 + 1) * 2048 + n0 + p] = m1;
}

// ---------------- Stage 3: gather + affine + lrelu + max over k ----------------
__global__ __launch_bounds__(256) void edge1_kernel(const float* __restrict__ P, const float* __restrict__ Q,
                                                    const int* __restrict__ idx, const float* __restrict__ s,
                                                    const float* __restrict__ tt, float* __restrict__ out,
                                                    int cofs) {
    __shared__ int idxl[80];
    int b = blockIdx.y, n0 = blockIdx.x * 4, t = threadIdx.x;
    int c = t & 63, p = t >> 6;
    if (t < 80) idxl[t] = idx[((long)b * 2048 + n0) * KNNK + t];
    __syncthreads();
    float qv = Q[((long)b * 2048 + n0 + p) * 64 + c];
    float sc = s[c], tc = tt[c];
    float m = -INFINITY;
    for (int kk = 0; kk < KNNK; ++kk) {
        int j = idxl[p * KNNK + kk];
        float v = P[((long)b * 2048 + j) * 64 + c];
        m = fmaxf(m, lrelu(fmaf(sc, v + qv, tc)));
    }
    out[(long)b * (192 * 2048) + (long)(cofs + c) * 2048 + n0 + p] = m;
}

// ---------------- FP32 head GEMM (fallback only, if workspace too small) ----------------
__global__ __launch_bounds__(256) void gemm_kernel(
    const float* __restrict__ W, int ldw, int Kdim, const float* __restrict__ X, long xbstride,
    const float* __restrict__ s, const float* __restrict__ tvec, const float* __restrict__ bias, int M,
    float* __restrict__ out, long obstride, float* __restrict__ maxout) {
    __shared__ __align__(16) float wl[32 * 68];
    __shared__ __align__(16) float xl[32 * 132];
    int b = blockIdx.z, ct = blockIdx.x * 64, nt = blockIdx.y * 128, t = threadIdx.x;
    const float* Xb = X + (long)b * xbstride;
    int cg = t >> 4, ng = t & 15;
    float acc[4][8];
#pragma unroll
    for (int i = 0; i < 4; ++i)
#pragma unroll
        for (int j = 0; j < 8; ++j) acc[i][j] = 0.f;
    for (int k0 = 0; k0 < Kdim; k0 += 32) {
        __syncthreads();
        for (int e = t; e < 2048; e += 256) {
            int c = e >> 5, k = e & 31;
            wl[k * 68 + c] = W[(long)(ct + c) * ldw + k0 + k];
        }
        for (int e = t; e < 4096; e += 256) {
            int k = e >> 7, j = e & 127;
            xl[k * 132 + j] = Xb[(long)(k0 + k) * 2048 + nt + j];
        }
        __syncthreads();
#pragma unroll 8
        for (int k = 0; k < 32; ++k) {
            float4 w4 = *(const float4*)(wl + k * 68 + cg * 4);
            float4 xa = *(const float4*)(xl + k * 132 + ng * 4);
            float4 xb = *(const float4*)(xl + k * 132 + 64 + ng * 4);
            float wv[4] = {w4.x, w4.y, w4.z, w4.w};
            float xv[8] = {xa.x, xa.y, xa.z, xa.w, xb.x, xb.y, xb.z, xb.w};
#pragma unroll
            for (int i = 0; i < 4; ++i)
#pragma unroll
                for (int j = 0; j < 8; ++j) acc[i][j] = fmaf(wv[i], xv[j], acc[i][j]);
        }
    }
    if (maxout) {
        __syncthreads();
        float* scr = xl;
#pragma unroll
        for (int i = 0; i < 4; ++i) {
            int c = ct + cg * 4 + i;
            float sv = s[c], tv = tvec[c];
            float m = -INFINITY;
#pragma unroll
            for (int j = 0; j < 8; ++j) m = fmaxf(m, lrelu(fmaf(sv, acc[i][j], tv)));
            scr[(cg * 4 + i) * 16 + ng] = m;
        }
        __syncthreads();
        if (t < 64) {
            float m = scr[t * 16];
            for (int j = 1; j < 16; ++j) m = fmaxf(m, scr[t * 16 + j]);
            maxout[((long)b * M + ct + t) * 16 + blockIdx.y] = m;
        }
    } else {
#pragma unroll
        for (int i = 0; i < 4; ++i) {
            int c = ct + cg * 4 + i;
            float bv = bias ? bias[b * M + c] : 0.f;
            float sv = s[c], tv = tvec[c];
            float4 o0, o1;
            o0.x = lrelu(fmaf(sv, acc[i][0] + bv, tv));
            o0.y = lrelu(fmaf(sv, acc[i][1] + bv, tv));
            o0.z = lrelu(fmaf(sv, acc[i][2] + bv, tv));
            o0.w = lrelu(fmaf(sv, acc[i][3] + bv, tv));
            o1.x = lrelu(fmaf(sv, acc[i][4] + bv, tv));
            o1.y = lrelu(fmaf(sv, acc[i][5] + bv, tv));
            o1.z = lrelu(fmaf(sv, acc[i][6] + bv, tv));
            o1.w = lrelu(fmaf(sv, acc[i][7] + bv, tv));
            float* op = out + (long)b * obstride + (long)c * 2048 + nt + ng * 4;
            *(float4*)op = o0;
            *(float4*)(op + 64) = o1;
        }
    }
}

// ---------------- bf16 hi/lo split of a weight matrix: W[m][koff+k] -> packed [M][K] ----------------
__global__ __launch_bounds__(256) void splitw_kernel(const float* __restrict__ W, int ldw, int koff, int K,
                                                     long total, u16* __restrict__ hi, u16* __restrict__ lo) {
    long i = (long)blockIdx.x * 256 + threadIdx.x;
    if (i >= total) return;
    long m = i / K, k = i - m * K;
    float v = W[m * ldw + koff + k];
    u16 h = f2bf(v);
    hi[i] = h;
    lo[i] = f2bf(v - bf2f(h));
}

// ---------------- cat f32 [b][192][2048] -> split-transposed bf16 [b][2048][192] ----------------
__global__ __launch_bounds__(256) void splitx_kernel(const float* __restrict__ cat, u16* __restrict__ hi,
                                                     u16* __restrict__ lo) {
    __shared__ float lds[32][65];
    int b = blockIdx.y;
    int kt = blockIdx.x % 6, nt = blockIdx.x / 6;
    int k0 = kt * 32, n0 = nt * 64;
    int t = threadIdx.x;
#pragma unroll
    for (int i = 0; i < 8; ++i) {
        int e = t + i * 256;
        int k = e >> 6, n = e & 63;
        lds[k][n] = cat[(long)b * (192 * 2048) + (long)(k0 + k) * 2048 + n0 + n];
    }
    __syncthreads();
    int n = t >> 2, kq = t & 3;
    u16 hv[8], lv[8];
#pragma unroll
    for (int i = 0; i < 8; ++i) {
        float v = lds[kq * 8 + i][n];
        u16 h = f2bf(v);
        hv[i] = h;
        lv[i] = f2bf(v - bf2f(h));
    }
    long off = ((long)b * 2048 + n0 + n) * 192 + k0 + kq * 8;
    uint4 uh, ul;
    uh.x = (u32)hv[0] | ((u32)hv[1] << 16); uh.y = (u32)hv[2] | ((u32)hv[3] << 16);
    uh.z = (u32)hv[4] | ((u32)hv[5] << 16); uh.w = (u32)hv[6] | ((u32)hv[7] << 16);
    ul.x = (u32)lv[0] | ((u32)lv[1] << 16); ul.y = (u32)lv[2] | ((u32)lv[3] << 16);
    ul.z = (u32)lv[4] | ((u32)lv[5] << 16); ul.w = (u32)lv[6] | ((u32)lv[7] << 16);
    *(uint4*)(hi + off) = uh;
    *(uint4*)(lo + off) = ul;
}

// ---------------- bf16x3 MFMA head GEMM ----------------
template <int MT, int NT, bool MAXOUT>
__global__ __launch_bounds__(256, 2) void gemm_mfma(
    const u16* __restrict__ Whi, const u16* __restrict__ Wlo, const u16* __restrict__ Xhi,
    const u16* __restrict__ Xlo, int K, int M, const float* __restrict__ s,
    const float* __restrict__ tvec, const float* __restrict__ bias, float* __restrict__ outf,
    long obstride, u16* __restrict__ ohi, u16* __restrict__ olo, int oK, float* __restrict__ maxout) {
    constexpr int BM = MT * 32, BN = NT * 32;
    __shared__ __align__(16) u16 Ah[BM * 32], Al[BM * 32], Bh[BN * 32], Bl[BN * 32];
    __shared__ float scr[MAXOUT ? BM * 2 : 1];

    int b = blockIdx.z;
    int m0 = blockIdx.x * BM;
    int n0 = blockIdx.y * BN;
    int t = threadIdx.x;
    int wave = t >> 6, lane = t & 63;
    int wm = (wave >> 1) * (MT * 16);
    int wn = (wave & 1) * (NT * 16);
    const int l15 = lane & 15, lq = lane >> 4;
    const int kcs = lq ^ ((l15 >> 1) & 3);

    const u16* Xbh = Xhi + (long)b * 2048 * K;
    const u16* Xbl = Xlo + (long)b * 2048 * K;

    f32x4 zero4 = {0.f, 0.f, 0.f, 0.f};
    f32x4 acc[MT][NT];
#pragma unroll
    for (int i = 0; i < MT; ++i)
#pragma unroll
        for (int j = 0; j < NT; ++j) acc[i][j] = zero4;

    for (int k0 = 0; k0 < K; k0 += 32) {
        __syncthreads();
#pragma unroll
        for (int u = t; u < BM * 4; u += 256) {
            int row = u >> 2, kc = (u & 3) ^ ((row >> 1) & 3);
            long ga = (long)(m0 + row) * K + k0 + kc * 8;
            *(uint4*)(Ah + u * 8) = *(const uint4*)(Whi + ga);
            *(uint4*)(Al + u * 8) = *(const uint4*)(Wlo + ga);
        }
#pragma unroll
        for (int u = t; u < BN * 4; u += 256) {
            int row = u >> 2, kc = (u & 3) ^ ((row >> 1) & 3);
            long ga = (long)(n0 + row) * K + k0 + kc * 8;
            *(uint4*)(Bh + u * 8) = *(const uint4*)(Xbh + ga);
            *(uint4*)(Bl + u * 8) = *(const uint4*)(Xbl + ga);
        }
        __syncthreads();
        short8v a_h[MT], a_l[MT], b_h[NT], b_l[NT];
#pragma unroll
        for (int i = 0; i < MT; ++i) {
            int u = (wm + i * 16 + l15) * 4 + kcs;
            a_h[i] = *(const short8v*)(Ah + u * 8);
            a_l[i] = *(const short8v*)(Al + u * 8);
        }
#pragma unroll
        for (int j = 0; j < NT; ++j) {
            int u = (wn + j * 16 + l15) * 4 + kcs;
            b_h[j] = *(const short8v*)(Bh + u * 8);
            b_l[j] = *(const short8v*)(Bl + u * 8);
        }
#pragma unroll
        for (int i = 0; i < MT; ++i)
#pragma unroll
            for (int j = 0; j < NT; ++j) {
                acc[i][j] = __builtin_amdgcn_mfma_f32_16x16x32_bf16(a_h[i], b_h[j], acc[i][j], 0, 0, 0);
                acc[i][j] = __builtin_amdgcn_mfma_f32_16x16x32_bf16(a_h[i], b_l[j], acc[i][j], 0, 0, 0);
                acc[i][j] = __builtin_amdgcn_mfma_f32_16x16x32_bf16(a_l[i], b_h[j], acc[i][j], 0, 0, 0);
            }
    }

    if constexpr (MAXOUT) {
#pragma unroll
        for (int i = 0; i < MT; ++i)
#pragma unroll
            for (int r = 0; r < 4; ++r) {
                int ml = wm + i * 16 + lq * 4 + r;
                int c = m0 + ml;
                float sv = s[c], tv = tvec[c];
                float mx = -INFINITY;
#pragma unroll
                for (int j = 0; j < NT; ++j) mx = fmaxf(mx, lrelu(fmaf(sv, acc[i][j][r], tv)));
                mx = fmaxf(mx, __shfl_xor(mx, 1));
                mx = fmaxf(mx, __shfl_xor(mx, 2));
                mx = fmaxf(mx, __shfl_xor(mx, 4));
                mx = fmaxf(mx, __shfl_xor(mx, 8));
                if (l15 == 0) scr[ml * 2 + (wave & 1)] = mx;
            }
        __syncthreads();
        if (t < BM) maxout[((long)b * M + m0 + t) * 16 + blockIdx.y] = fmaxf(scr[t * 2], scr[t * 2 + 1]);
    } else if (outf) {
#pragma unroll
        for (int i = 0; i < MT; ++i)
#pragma unroll
            for (int r = 0; r < 4; ++r) {
                int c = m0 + wm + i * 16 + lq * 4 + r;
                float sv = s[c], tv = tvec[c];
                float bv = bias ? bias[b * M + c] : 0.f;
                float* op = outf + (long)b * obstride + (long)c * 2048 + n0 + wn;
#pragma unroll
                for (int j = 0; j < NT; ++j) op[j * 16 + l15] = lrelu(fmaf(sv, acc[i][j][r] + bv, tv));
            }
    } else {
#pragma unroll
        for (int i = 0; i < MT; ++i) {
            float sv[4], tv[4], bv[4];
#pragma unroll
            for (int r = 0; r < 4; ++r) {
                int c = m0 + wm + i * 16 + lq * 4 + r;
                sv[r] = s[c];
                tv[r] = tvec[c];
                bv[r] = bias ? bias[b * M + c] : 0.f;
            }
#pragma unroll
            for (int j = 0; j < NT; ++j) {
                long nb = ((long)b * 2048 + n0 + wn + j * 16 + l15) * oK + m0 + wm + i * 16 + lq * 4;
                ushort4 uh, ul;
                float v0 = lrelu(fmaf(sv[0], acc[i][j][0] + bv[0], tv[0]));
                float v1 = lrelu(fmaf(sv[1], acc[i][j][1] + bv[1], tv[1]));
                float v2 = lrelu(fmaf(sv[2], acc[i][j][2] + bv[2], tv[2]));
                float v3 = lrelu(fmaf(sv[3], acc[i][j][3] + bv[3], tv[3]));
                u16 h0 = f2bf(v0), h1 = f2bf(v1), h2 = f2bf(v2), h3 = f2bf(v3);
                uh.x = h0; uh.y = h1; uh.z = h2; uh.w = h3;
                ul.x = f2bf(v0 - bf2f(h0));
                ul.y = f2bf(v1 - bf2f(h1));
                ul.z = f2bf(v2 - bf2f(h2));
                ul.w = f2bf(v3 - bf2f(h3));
                *(ushort4*)(ohi + nb) = uh;
                *(ushort4*)(olo + nb) = ul;
            }
        }
    }
}

// ---------------- finalize g = max over the 16 n-tile partials ----------------
__global__ __launch_bounds__(256) void gmax_final(const float* __restrict__ ep, float* __restrict__ g) {
    int i = blockIdx.x * 256 + threadIdx.x;
    float m = ep[i * 16];
    for (int j = 1; j < 16; ++j) m = fmaxf(m, ep[i * 16 + j]);
    g[i] = m;
}

// ---------------- bias7[b][co] = w7[co, :1024] @ g[b] ----------------
__global__ __launch_bounds__(64) void bias7_kernel(const float* __restrict__ w7, const float* __restrict__ g,
                                                   float* __restrict__ bias7) {
    int o = blockIdx.x;
    int b = o >> 9, co = o & 511;
    int lane = threadIdx.x;
    float acc = 0.f;
    for (int j = lane; j < 1024; j += 64) acc = fmaf(w7[(long)co * 1216 + j], g[b * 1024 + j], acc);
#pragma unroll
    for (int off = 32; off >= 1; off >>= 1) acc += __shfl_xor(acc, off);
    if (lane == 0) bias7[o] = acc;
}

// ---------------- y[b][n] = sigmoid(w9 @ h8[:, n]) ----------------
__global__ __launch_bounds__(256) void w9_kernel(const float* __restrict__ w9, const float* __restrict__ h8,
                                                 float* __restrict__ out) {
    int i = blockIdx.x * 256 + threadIdx.x;
    int b = i >> 11, n = i & 2047;
    const float* hb = h8 + (long)b * 256 * 2048 + n;
    float acc = 0.f;
    for (int c = 0; c < 256; ++c) acc = fmaf(w9[c], hb[c * 2048], acc);
    out[i] = 1.f / (1.f + expf(-acc));
}

extern "C" void kernel_launch(void* const* d_in, const int* in_sizes, int n_in,
                              void* d_out, int out_size, void* d_ws, size_t ws_size,
                              hipStream_t stream) {
    (void)in_sizes; (void)n_in; (void)out_size;
    const float* x  = (const float*)d_in[0];
    const float* w1 = (const float*)d_in[1];
    const float* w2 = (const float*)d_in[2];
    const float* w3 = (const float*)d_in[3];
    const float* w4 = (const float*)d_in[4];
    const float* w5 = (const float*)d_in[5];
    const float* w6 = (const float*)d_in[6];
    const float* w7 = (const float*)d_in[7];
    const float* w8 = (const float*)d_in[8];
    const float* w9 = (const float*)d_in[9];
    const float* s1 = (const float*)d_in[10]; const float* t1 = (const float*)d_in[11];
    const float* s2 = (const float*)d_in[12]; const float* t2 = (const float*)d_in[13];
    const float* s3 = (const float*)d_in[14]; const float* t3 = (const float*)d_in[15];
    const float* s4 = (const float*)d_in[16]; const float* t4 = (const float*)d_in[17];
    const float* s5 = (const float*)d_in[18]; const float* t5 = (const float*)d_in[19];
    const float* s6 = (const float*)d_in[20]; const float* t6 = (const float*)d_in[21];
    const float* s7 = (const float*)d_in[22]; const float* t7 = (const float*)d_in[23];
    const float* s8 = (const float*)d_in[24]; const float* t8 = (const float*)d_in[25];

    // workspace partition (floats, then ushorts)
    float* cat = (float*)d_ws;                       // 16*192*2048      = 6291456
    float* xxb = cat + (long)6291456;                // 16*2048          = 32768
    int* idxb = (int*)(xxb + 32768);                 // 16*2048*20 ints  = 655360
    float* ep = (float*)(idxb + 655360);             // 16*1024*16       = 262144
    float* g  = ep + 262144;                         // 16*1024          = 16384
    float* b7 = g + 16384;                           // 16*512           = 8192
    float* h8 = b7 + 8192;                           // 16*256*2048      = 8388608
    float* P  = h8 + 8388608;                        // 16*2048*64       = 2097152
    float* Q  = P + 2097152;                         // 16*2048*64       = 2097152
    u16* h7hi = (u16*)(Q + 2097152);                 // 16*2048*512 u16  = 16777216
    u16* h7lo = h7hi + 16777216;
    u16* cathi = h7lo + 16777216;                    // 16*2048*192 u16  = 6291456
    u16* catlo = cathi + 6291456;
    u16* w6h = catlo + 6291456;                      // 1024*192 = 196608
    u16* w6l = w6h + 196608;
    u16* w7h = w6l + 196608;                         // 512*192 = 98304
    u16* w7l = w7h + 98304;
    u16* w8h = w7l + 98304;                          // 256*512 = 131072
    u16* w8l = w8h + 131072;
    const size_t NEED = 173375488;                   // bytes for the full mfma layout
    bool big = ws_size >= NEED;

    // edge2 weight limbs alias the start of the h7 region (dead until the head)
    u16* w2L = h7hi;            // w2: h at +0, m at +4096, l at +8192
    u16* w4L = h7hi + 12288;    // w4 likewise
    // Gram split arrays also alias h7 region, AFTER the edge2 limbs (3 x 2,097,152 u16)
    u16* Sh = h7hi + 32768;
    u16* Sm = Sh + 2097152;
    u16* Sl = Sm + 2097152;

    dim3 blk(256);
    dim3 blk512(512);
    long catstride = 192 * 2048;

    if (big) {
        splitw3_kernel<<<16, blk, 0, stream>>>(w2, w2L, w2L + 4096, w2L + 8192);
        splitw3_kernel<<<16, blk, 0, stream>>>(w4, w4L, w4L + 4096, w4L + 8192);
    }

    // ---- stage 1 (C=2, fp32 knn) ----
    xx_kernel<<<128, blk, 0, stream>>>(x, 2 * 2048, 2, xxb);
    knn_kernel<<<dim3(128, 16), blk512, 0, stream>>>(x, 2 * 2048, 2, xxb, idxb);
    pq_kernel<<<dim3(32, 16), blk, 0, stream>>>(x, 2 * 2048, 2, w1, P, Q);
    if (big)
        edge2_mfma_kernel<<<dim3(256, 16), blk, 0, stream>>>(P, Q, idxb, w2L, w2L + 4096, w2L + 8192,
                                                             s1, t1, s2, t2, cat, 0);
    else
        edge2_kernel<<<dim3(256, 16), blk, 0, stream>>>(P, Q, idxb, w2, s1, t1, s2, t2, cat, 0);
    // ---- stage 2 (C=64 on x1) ----
    xx_kernel<<<128, blk, 0, stream>>>(cat, catstride, 64, xxb);
    if (big) {
        split3t_kernel<<<dim3(64, 16), blk, 0, stream>>>(cat, catstride, Sh, Sm, Sl);
        knn_hybrid_kernel<<<dim3(128, 16), blk512, 0, stream>>>(cat, catstride, Sh, Sm, Sl, xxb, idxb);
    } else {
        knn_kernel<<<dim3(128, 16), blk512, 0, stream>>>(cat, catstride, 64, xxb, idxb);
    }
    pq_kernel<<<dim3(32, 16), blk, 0, stream>>>(cat, catstride, 64, w3, P, Q);
    if (big)
        edge2_mfma_kernel<<<dim3(256, 16), blk, 0, stream>>>(P, Q, idxb, w4L, w4L + 4096, w4L + 8192,
                                                             s3, t3, s4, t4, cat, 64);
    else
        edge2_kernel<<<dim3(256, 16), blk, 0, stream>>>(P, Q, idxb, w4, s3, t3, s4, t4, cat, 64);
    // ---- stage 3 (C=64 on x2) ----
    xx_kernel<<<128, blk, 0, stream>>>(cat + 64 * 2048, catstride, 64, xxb);
    if (big) {
        split3t_kernel<<<dim3(64, 16), blk, 0, stream>>>(cat + 64 * 2048, catstride, Sh, Sm, Sl);
        knn_hybrid_kernel<<<dim3(128, 16), blk512, 0, stream>>>(cat + 64 * 2048, catstride, Sh, Sm, Sl,
                                                                xxb, idxb);
    } else {
        knn_kernel<<<dim3(128, 16), blk512, 0, stream>>>(cat + 64 * 2048, catstride, 64, xxb, idxb);
    }
    pq_kernel<<<dim3(32, 16), blk, 0, stream>>>(cat + 64 * 2048, catstride, 64, w5, P, Q);
    edge1_kernel<<<dim3(512, 16), blk, 0, stream>>>(P, Q, idxb, s5, t5, cat, 128);

    if (big) {
        // ---- head: bf16x3 MFMA path ----
        splitw_kernel<<<768, blk, 0, stream>>>(w6, 192, 0, 192, 196608, w6h, w6l);
        splitw_kernel<<<384, blk, 0, stream>>>(w7, 1216, 1024, 192, 98304, w7h, w7l);
        splitw_kernel<<<512, blk, 0, stream>>>(w8, 512, 0, 512, 131072, w8h, w8l);
        splitx_kernel<<<dim3(192, 16), blk, 0, stream>>>(cat, cathi, catlo);
        gemm_mfma<4, 4, true><<<dim3(8, 16, 16), blk, 0, stream>>>(
            w6h, w6l, cathi, catlo, 192, 1024, s6, t6, nullptr, nullptr, 0, nullptr, nullptr, 0, ep);
        gmax_final<<<64, blk, 0, stream>>>(ep, g);
        bias7_kernel<<<dim3(16 * 512), dim3(64), 0, stream>>>(w7, g, b7);
        gemm_mfma<4, 4, false><<<dim3(4, 16, 16), blk, 0, stream>>>(
            w7h, w7l, cathi, catlo, 192, 512, s7, t7, b7, nullptr, 0, h7hi, h7lo, 512, nullptr);
        gemm_mfma<2, 4, false><<<dim3(4, 16, 16), blk, 0, stream>>>(
            w8h, w8l, h7hi, h7lo, 512, 256, s8, t8, nullptr, h8, (long)256 * 2048, nullptr, nullptr, 0,
            nullptr);
        w9_kernel<<<128, blk, 0, stream>>>(w9, h8, (float*)d_out);
    } else {
        // ---- head: fp32 fallback ----
        float* h7f = (float*)h7hi;
        gemm_kernel<<<dim3(16, 16, 16), blk, 0, stream>>>(w6, 192, 192, cat, catstride, s6, t6, nullptr,
                                                          1024, nullptr, 0, ep);
        gmax_final<<<64, blk, 0, stream>>>(ep, g);
        bias7_kernel<<<dim3(16 * 512), dim3(64), 0, stream>>>(w7, g, b7);
        gemm_kernel<<<dim3(8, 16, 16), blk, 0, stream>>>(w7 + 1024, 1216, 192, cat, catstride, s7, t7, b7,
                                                         512, h7f, (long)512 * 2048, nullptr);
        gemm_kernel<<<dim3(4, 16, 16), blk, 0, stream>>>(w8, 512, 512, h7f, (long)512 * 2048, s8, t8,
                                                         nullptr, 256, h8, (long)256 * 2048, nullptr);
        w9_kernel<<<128, blk, 0, stream>>>(w9, h8, (float*)d_out);
    }
}

// Round 10
// 1168.555 us; speedup vs baseline: 1.1012x; 1.1012x over previous
//
#include <hip/hip_runtime.h>
#include <math.h>

#define KNNK 20

typedef unsigned short u16;
typedef unsigned int u32;
typedef unsigned long long u64;
typedef __attribute__((ext_vector_type(8))) short short8v;   // 8 bf16 (4 VGPRs)
typedef __attribute__((ext_vector_type(4))) float f32x4;     // MFMA accumulator

__device__ __forceinline__ float lrelu(float v) { return v >= 0.f ? v : 0.2f * v; }

// round-to-nearest-even fp32 -> bf16 (bit trick)
__device__ __forceinline__ u16 f2bf(float v) {
    u32 u = __float_as_uint(v);
    u += 0x7fffu + ((u >> 16) & 1u);
    return (u16)(u >> 16);
}
__device__ __forceinline__ float bf2f(u16 h) { return __uint_as_float(((u32)h) << 16); }

// monotonic fp32 -> u32 map: a > b (float, no NaN)  <=>  ordf(a) > ordf(b) (uint)
__device__ __forceinline__ u32 ordf(float v) {
    u32 u = __float_as_uint(v);
    return u ^ ((u32)((int)u >> 31) | 0x80000000u);
}
// (value desc, index asc) total order as single u64
__device__ __forceinline__ u64 mkkey(float v, int g) {
    return ((u64)ordf(v) << 32) | (u32)(~(u32)g);
}

// 8 contiguous fp32 (LDS) -> three bf16x8 limb fragments (exact 3-way split, round-2-validated)
__device__ __forceinline__ void cvt8(const float* __restrict__ p, short8v& H8, short8v& M8, short8v& L8) {
    float4 a = *(const float4*)(p);
    float4 b4 = *(const float4*)(p + 4);
    float v[8] = {a.x, a.y, a.z, a.w, b4.x, b4.y, b4.z, b4.w};
    short8v H, M, L;
#pragma unroll
    for (int i = 0; i < 8; ++i) {
        float x = v[i];
        u16 h = f2bf(x);
        float r1 = x - bf2f(h);    // exact
        u16 m = f2bf(r1);
        float r2 = r1 - bf2f(m);   // exact
        H[i] = (short)h;
        M[i] = (short)m;
        L[i] = (short)f2bf(r2);
    }
    H8 = H; M8 = M; L8 = L;
}

// ---------------- xx[b][n] = sum_c f[b][c][n]^2 ----------------
__global__ __launch_bounds__(256) void xx_kernel(const float* __restrict__ f, long bstride, int C,
                                                 float* __restrict__ xx) {
    int i = blockIdx.x * 256 + threadIdx.x;   // over B*N
    int b = i >> 11, n = i & 2047;
    const float* fb = f + (long)b * bstride;
    float s = 0.f;
    for (int c = 0; c < C; ++c) { float v = fb[c * 2048 + n]; s = fmaf(v, v, s); }
    xx[i] = s;
}

// ---------------- top-20 over a 1024-col half row; returns sorted key (lanes 0..19 = ranks) ----------------
// (r7/r9-validated: exact u64-key total order = JAX top_k; indices are colbase-global)
__device__ __forceinline__ u64 topk20_half(const float* __restrict__ srow, int lane, int colbase) {
    float b1 = -INFINITY, b2 = -INFINITY, b3 = -INFINITY;
    int j1 = 0, j2 = 0, j3 = 0;
#pragma unroll
    for (int j = 0; j < 16; ++j) {
        float vv = srow[lane + 64 * j];
        bool c1 = vv > b1;
        bool c2 = vv > b2;
        bool c3 = vv > b3;
        b3 = c2 ? b2 : (c3 ? vv : b3);
        j3 = c2 ? j2 : (c3 ? j : j3);
        b2 = c1 ? b1 : (c2 ? vv : b2);
        j2 = c1 ? j1 : (c2 ? j : j2);
        b1 = c1 ? vv : b1;
        j1 = c1 ? j : j1;
    }
    u64 ka = mkkey(b1, colbase + lane + (j1 << 6));
#pragma unroll
    for (int size = 2; size <= 64; size <<= 1) {
#pragma unroll
        for (int stride = size >> 1; stride >= 1; stride >>= 1) {
            u64 ok = __shfl_xor(ka, stride);
            bool low = (lane & stride) == 0;
            bool asc = (lane & size) == 0;
            bool f = ka > ok;
            bool take = (low == asc) ? f : !f;
            ka = take ? ka : ok;
        }
    }
    u64 w19 = __shfl(ka, 19);
    unsigned used = (1u << j1) | (1u << j2) | (1u << j3);
    u64 pend = mkkey(b2, colbase + lane + (j2 << 6));
    int pstate = 0;
    while (__any(pend > w19)) {
        u64 act = __ballot(pend > w19);
        int L = __ffsll((long long)act) - 1;
        u64 ck = __shfl(pend, L);
        u64 cfb = __ballot(lane < 20 && ck > ka);
        int p = 20 - __popcll(cfb);
        u64 up = __shfl_up(ka, 1);
        if (lane < 20) {
            if (lane > p) ka = up;
            else if (lane == p) ka = ck;
        }
        if (lane == L) {
            if (pstate == 0) {
                pend = mkkey(b3, colbase + lane + (j3 << 6));
                pstate = 1;
            } else {
                float nb = -INFINITY;
                int nj = 0;
#pragma unroll
                for (int j = 0; j < 16; ++j) {
                    float vvv = ((used >> j) & 1u) ? -INFINITY : srow[lane + 64 * j];
                    if (vvv > nb) { nb = vvv; nj = j; }
                }
                used |= 1u << nj;
                pend = mkkey(nb, colbase + lane + (nj << 6));
            }
        }
        w19 = __shfl(ka, 19);
    }
    return ka;
}

// ---------------- exact merge of two sorted top-20 key lists (r7/r9-validated) ----------------
__device__ __forceinline__ u64 merge20(u64 kA, u64 kB, int lane) {
    u64 kb = __shfl(kB, (lane - 20) & 63);
    u64 ka = lane < 20 ? kA : (lane < 40 ? kb : 0ULL);   // 0 < any real key (ordf>0)
#pragma unroll
    for (int size = 2; size <= 64; size <<= 1) {
#pragma unroll
        for (int stride = size >> 1; stride >= 1; stride >>= 1) {
            u64 ok = __shfl_xor(ka, stride);
            bool low = (lane & stride) == 0;
            bool asc = (lane & size) == 0;
            bool f = ka > ok;
            bool take = (low == asc) ? f : !f;
            ka = take ? ka : ok;
        }
    }
    return ka;
}

// ---------------- KNN (fp32 Gram): 8-row strip, half-col selection, 35 KB LDS -> 4 blocks/CU ----------------
// Per-output c-ascending fma chain (bitwise = reference ordering). Wave w owns row w.
// Selection: topk20_half per column-half (r7-validated) + exact merge20.
__global__ __launch_bounds__(512, 8) void knn_kernel(const float* __restrict__ f, long bstride, int C,
                                                     const float* __restrict__ xx, int* __restrict__ idx_out) {
    __shared__ __align__(16) float pd[8 * 1028];   // ~32.9 KB
    __shared__ __align__(16) float Asm[64 * 8];    // [c][row], 2 KB (C<=64)
    int b = blockIdx.y;
    int n0 = blockIdx.x * 8;
    int t = threadIdx.x;
    const float* fb = f + (long)b * bstride;

    for (int e = t; e < C * 8; e += 512) {
        int c = e >> 3, j = e & 7;
        Asm[e] = fb[c * 2048 + n0 + j];
    }
    __syncthreads();

    float acc[8][4];
#pragma unroll
    for (int i = 0; i < 8; ++i)
#pragma unroll
        for (int j = 0; j < 4; ++j) acc[i][j] = 0.f;
    int m0 = t * 4;   // this thread's 4 columns (fixed)
    for (int c = 0; c < C; ++c) {
        float4 b4 = *(const float4*)(fb + c * 2048 + m0);
        float bv[4] = {b4.x, b4.y, b4.z, b4.w};
        const float* ar = Asm + c * 8;
        float4 a0 = *(const float4*)(ar);
        float4 a1 = *(const float4*)(ar + 4);
        float av[8] = {a0.x, a0.y, a0.z, a0.w, a1.x, a1.y, a1.z, a1.w};
#pragma unroll
        for (int i = 0; i < 8; ++i)
#pragma unroll
            for (int j = 0; j < 4; ++j) acc[i][j] = fmaf(av[i], bv[j], acc[i][j]);
    }
    float xn[8];
#pragma unroll
    for (int i = 0; i < 8; ++i) xn[i] = xx[b * 2048 + n0 + i];
    float4 xm4 = *(const float4*)(xx + b * 2048 + m0);
    float xm[4] = {xm4.x, xm4.y, xm4.z, xm4.w};

    int wave = t >> 6, lane = t & 63;

    // ---- half 0: cols 0..1023 (threads with m0 < 1024; wave-uniform branch) ----
    if (m0 < 1024) {
#pragma unroll
        for (int i = 0; i < 8; ++i) {
            float4 o;
            o.x = (2.f * acc[i][0] - xn[i]) - xm[0];
            o.y = (2.f * acc[i][1] - xn[i]) - xm[1];
            o.z = (2.f * acc[i][2] - xn[i]) - xm[2];
            o.w = (2.f * acc[i][3] - xn[i]) - xm[3];
            *(float4*)(pd + i * 1028 + m0) = o;
        }
    }
    __syncthreads();
    u64 kA = topk20_half(pd + wave * 1028, lane, 0);
    __syncthreads();   // all reads done before half-1 overwrites pd

    // ---- half 1: cols 1024..2047 ----
    if (m0 >= 1024) {
        int lc = m0 - 1024;
#pragma unroll
        for (int i = 0; i < 8; ++i) {
            float4 o;
            o.x = (2.f * acc[i][0] - xn[i]) - xm[0];
            o.y = (2.f * acc[i][1] - xn[i]) - xm[1];
            o.z = (2.f * acc[i][2] - xn[i]) - xm[2];
            o.w = (2.f * acc[i][3] - xn[i]) - xm[3];
            *(float4*)(pd + i * 1028 + lc) = o;
        }
    }
    __syncthreads();
    u64 kB = topk20_half(pd + wave * 1028, lane, 1024);

    u64 fk = merge20(kA, kB, lane);
    if (lane < KNNK) idx_out[((long)b * 2048 + n0 + wave) * KNNK + lane] = (int)(~(u32)fk) & 2047;
}

// ---------------- P = Wa @ f, Q = (Wb - Wa) @ f, stored (B, N, 64) n-major ----------------
__global__ __launch_bounds__(256) void pq_kernel(const float* __restrict__ f, long bstride, int C,
                                                 const float* __restrict__ W, float* __restrict__ P,
                                                 float* __restrict__ Q) {
    __shared__ __align__(16) float wa[64 * 64];
    __shared__ __align__(16) float wq[64 * 64];
    __shared__ __align__(16) float X[64 * 64];
    int b = blockIdx.y, n0 = blockIdx.x * 64, t = threadIdx.x;
    const float* fb = f + (long)b * bstride;
    for (int e = t; e < C * 64; e += 256) {
        int k = e >> 6, c = e & 63;
        float a = W[c * 2 * C + k];
        float bv = W[c * 2 * C + C + k];
        wa[k * 64 + c] = a;
        wq[k * 64 + c] = bv - a;
    }
    for (int e = t; e < C * 64; e += 256) {
        int k = e >> 6, j = e & 63;
        X[e] = fb[k * 2048 + n0 + j];
    }
    __syncthreads();
    int cg = t >> 4, ng = t & 15;
    float accP[4][4] = {}, accQ[4][4] = {};
    for (int k = 0; k < C; ++k) {
        float4 a4 = *(const float4*)(wa + k * 64 + cg * 4);
        float4 q4 = *(const float4*)(wq + k * 64 + cg * 4);
        float4 x4 = *(const float4*)(X + k * 64 + ng * 4);
        float av[4] = {a4.x, a4.y, a4.z, a4.w};
        float qv[4] = {q4.x, q4.y, q4.z, q4.w};
        float xv[4] = {x4.x, x4.y, x4.z, x4.w};
#pragma unroll
        for (int i = 0; i < 4; ++i)
#pragma unroll
            for (int j = 0; j < 4; ++j) {
                accP[i][j] = fmaf(av[i], xv[j], accP[i][j]);
                accQ[i][j] = fmaf(qv[i], xv[j], accQ[i][j]);
            }
    }
#pragma unroll
    for (int j = 0; j < 4; ++j) {
        long n = n0 + ng * 4 + j;
        float4 pv = {accP[0][j], accP[1][j], accP[2][j], accP[3][j]};
        float4 qv = {accQ[0][j], accQ[1][j], accQ[2][j], accQ[3][j]};
        *(float4*)(P + ((long)b * 2048 + n) * 64 + cg * 4) = pv;
        *(float4*)(Q + ((long)b * 2048 + n) * 64 + cg * 4) = qv;
    }
}

// ---------------- 3-limb bf16 split of a 64x64 weight (elementwise, [co][ci] kept) ----------------
__global__ __launch_bounds__(256) void splitw3_kernel(const float* __restrict__ W, u16* __restrict__ h,
                                                      u16* __restrict__ m, u16* __restrict__ l) {
    int i = blockIdx.x * 256 + threadIdx.x;   // < 4096
    float v = W[i];
    u16 hh = f2bf(v);
    float r1 = v - bf2f(hh);
    u16 mm = f2bf(r1);
    float r2 = r1 - bf2f(mm);
    h[i] = hh;
    m[i] = mm;
    l[i] = f2bf(r2);
}

// ---------------- EdgeConv layer-2 + max over k via MFMA (bf16x6, stages 1 & 2) ----------------
__global__ __launch_bounds__(256) void edge2_mfma_kernel(
    const float* __restrict__ P, const float* __restrict__ Q, const int* __restrict__ idx,
    const u16* __restrict__ Wh, const u16* __restrict__ Wm, const u16* __restrict__ Wl,
    const float* __restrict__ sa, const float* __restrict__ ta, const float* __restrict__ sb,
    const float* __restrict__ tb, float* __restrict__ out, int cofs) {
    __shared__ __align__(16) float h1t[192 * 68];   // [col][ci] fp32, pad 68; reused as h2 [col][co]
    __shared__ int idxl[160];
    int b = blockIdx.y, n0 = blockIdx.x * 8, t = threadIdx.x;
    if (t < 160) idxl[t] = idx[((long)b * 2048 + n0) * KNNK + t];
    __syncthreads();

    for (int it = t; it < 2560; it += 256) {
        int col = it % 160, cg = it / 160;
        int p = col / 20;
        int j = idxl[col];
        int n = n0 + p;
        float4 pv = *(const float4*)(P + ((long)b * 2048 + j) * 64 + cg * 4);
        float4 qv = *(const float4*)(Q + ((long)b * 2048 + n) * 64 + cg * 4);
        float4 sv = *(const float4*)(sa + cg * 4);
        float4 tv = *(const float4*)(ta + cg * 4);
        float4 o;
        o.x = lrelu(fmaf(sv.x, pv.x + qv.x, tv.x));
        o.y = lrelu(fmaf(sv.y, pv.y + qv.y, tv.y));
        o.z = lrelu(fmaf(sv.z, pv.z + qv.z, tv.z));
        o.w = lrelu(fmaf(sv.w, pv.w + qv.w, tv.w));
        *(float4*)(h1t + col * 68 + cg * 4) = o;
    }
    for (int it = t; it < 512; it += 256) {
        int col = 160 + (it & 31), cg = it >> 5;
        float4 z = {0.f, 0.f, 0.f, 0.f};
        *(float4*)(h1t + col * 68 + cg * 4) = z;
    }
    __syncthreads();

    int wave = t >> 6, lane = t & 63, l15 = lane & 15, lq = lane >> 4;
    f32x4 acc[3][4];
#pragma unroll
    for (int ct = 0; ct < 3; ++ct)
#pragma unroll
        for (int mt = 0; mt < 4; ++mt) {
            f32x4 z = {0.f, 0.f, 0.f, 0.f};
            acc[ct][mt] = z;
        }

#pragma unroll
    for (int ct = 0; ct < 3; ++ct) {
        int col = (wave * 3 + ct) * 16 + l15;
        short8v bh[2], bm[2], bl[2];
#pragma unroll
        for (int kh = 0; kh < 2; ++kh) cvt8(h1t + col * 68 + kh * 32 + lq * 8, bh[kh], bm[kh], bl[kh]);
#pragma unroll
        for (int mt = 0; mt < 4; ++mt) {
#pragma unroll
            for (int kh = 0; kh < 2; ++kh) {
                int wo = (mt * 16 + l15) * 64 + kh * 32 + lq * 8;
                short8v ah = *(const short8v*)(Wh + wo);
                short8v am = *(const short8v*)(Wm + wo);
                short8v al = *(const short8v*)(Wl + wo);
                acc[ct][mt] = __builtin_amdgcn_mfma_f32_16x16x32_bf16(ah, bh[kh], acc[ct][mt], 0, 0, 0);
                acc[ct][mt] = __builtin_amdgcn_mfma_f32_16x16x32_bf16(ah, bm[kh], acc[ct][mt], 0, 0, 0);
                acc[ct][mt] = __builtin_amdgcn_mfma_f32_16x16x32_bf16(am, bh[kh], acc[ct][mt], 0, 0, 0);
                acc[ct][mt] = __builtin_amdgcn_mfma_f32_16x16x32_bf16(am, bm[kh], acc[ct][mt], 0, 0, 0);
                acc[ct][mt] = __builtin_amdgcn_mfma_f32_16x16x32_bf16(ah, bl[kh], acc[ct][mt], 0, 0, 0);
                acc[ct][mt] = __builtin_amdgcn_mfma_f32_16x16x32_bf16(al, bh[kh], acc[ct][mt], 0, 0, 0);
            }
        }
    }
    __syncthreads();

#pragma unroll
    for (int ct = 0; ct < 3; ++ct) {
        int col = (wave * 3 + ct) * 16 + l15;
#pragma unroll
        for (int mt = 0; mt < 4; ++mt) {
            float4 d = {acc[ct][mt][0], acc[ct][mt][1], acc[ct][mt][2], acc[ct][mt][3]};
            *(float4*)(h1t + col * 68 + mt * 16 + lq * 4) = d;
        }
    }
    __syncthreads();

    for (int id = t; id < 512; id += 256) {
        int co = id & 63, p = id >> 6;
        float sv = sb[co], tv = tb[co];
        float m = -INFINITY;
#pragma unroll 4
        for (int kk = 0; kk < KNNK; ++kk)
            m = fmaxf(m, lrelu(fmaf(sv, h1t[(p * 20 + kk) * 68 + co], tv)));
        out[(long)b * (192 * 2048) + (long)(cofs + co) * 2048 + n0 + p] = m;
    }
}

// ---------------- EdgeConv layer-2 fp32 (fallback path) ----------------
__global__ __launch_bounds__(256) void edge2_kernel(
    const float* __restrict__ P, const float* __restrict__ Q, const int* __restrict__ idx,
    const float* __restrict__ W2, const float* __restrict__ sa, const float* __restrict__ ta,
    const float* __restrict__ sb, const float* __restrict__ tb, float* __restrict__ out, int cofs) {
    __shared__ __align__(16) float h1[64 * 164];
    __shared__ __align__(16) float w2l[64 * 64];
    __shared__ int idxl[160];
    int b = blockIdx.y, n0 = blockIdx.x * 8, t = threadIdx.x;
    if (t < 160) idxl[t] = idx[((long)b * 2048 + n0) * KNNK + t];
    for (int e = t; e < 4096; e += 256) { int co = e >> 6, ci = e & 63; w2l[ci * 64 + co] = W2[e]; }
    __syncthreads();
    for (int it = t; it < 2560; it += 256) {
        int col = it % 160, cg = it / 160;
        int p = col / 20;
        int j = idxl[col];
        int n = n0 + p;
        float4 pv = *(const float4*)(P + ((long)b * 2048 + j) * 64 + cg * 4);
        float4 qv = *(const float4*)(Q + ((long)b * 2048 + n) * 64 + cg * 4);
        float4 sv = *(const float4*)(sa + cg * 4);
        float4 tv = *(const float4*)(ta + cg * 4);
        h1[(cg * 4 + 0) * 164 + col] = lrelu(fmaf(sv.x, pv.x + qv.x, tv.x));
        h1[(cg * 4 + 1) * 164 + col] = lrelu(fmaf(sv.y, pv.y + qv.y, tv.y));
        h1[(cg * 4 + 2) * 164 + col] = lrelu(fmaf(sv.z, pv.z + qv.z, tv.z));
        h1[(cg * 4 + 3) * 164 + col] = lrelu(fmaf(sv.w, pv.w + qv.w, tv.w));
    }
    __syncthreads();
    int p = t & 7, co2 = t >> 3, c0 = co2 * 2;
    float acc0[20], acc1[20];
#pragma unroll
    for (int q = 0; q < 20; ++q) { acc0[q] = 0.f; acc1[q] = 0.f; }
#pragma unroll 4
    for (int k = 0; k < 64; ++k) {
        float2 w = *(const float2*)(w2l + k * 64 + c0);
        const float* hr = h1 + k * 164 + p * 20;
#pragma unroll
        for (int q = 0; q < 5; ++q) {
            float4 h4 = *(const float4*)(hr + q * 4);
            acc0[q * 4 + 0] = fmaf(w.x, h4.x, acc0[q * 4 + 0]);
            acc0[q * 4 + 1] = fmaf(w.x, h4.y, acc0[q * 4 + 1]);
            acc0[q * 4 + 2] = fmaf(w.x, h4.z, acc0[q * 4 + 2]);
            acc0[q * 4 + 3] = fmaf(w.x, h4.w, acc0[q * 4 + 3]);
            acc1[q * 4 + 0] = fmaf(w.y, h4.x, acc1[q * 4 + 0]);
            acc1[q * 4 + 1] = fmaf(w.y, h4.y, acc1[q * 4 + 1]);
            acc1[q * 4 + 2] = fmaf(w.y, h4.z, acc1[q * 4 + 2]);
            acc1[q * 4 + 3] = fmaf(w.y, h4.w, acc1[q * 4 + 3]);
        }
    }
    float s0 = sb[c0], t0v = tb[c0], s1 = sb[c0 + 1], t1v = tb[c0 + 1];
    float m0 = -INFINITY, m1 = -INFINITY;
#pragma unroll
    for (int q = 0; q < 20; ++q) {
        m0 = fmaxf(m0, lrelu(fmaf(s0, acc0[q], t0v)));
        m1 = fmaxf(m1, lrelu(fmaf(s1, acc1[q], t1v)));
    }
    out[(long)b * (192 * 2048) + (long)(cofs + c0) * 2048 + n0 + p] = m0;
    out[(long)b * (192 * 2048) + (long)(cofs + c0 + 1) * 2048 + n0 + p] = m1;
}

// ---------------- Stage 3: gather + affine + lrelu + max over k ----------------
__global__ __launch_bounds__(256) void edge1_kernel(const float* __restrict__ P, const float* __restrict__ Q,
                                                    const int* __restrict__ idx, const float* __restrict__ s,
                                                    const float* __restrict__ tt, float* __restrict__ out,
                                                    int cofs) {
    __shared__ int idxl[80];
    int b = blockIdx.y, n0 = blockIdx.x * 4, t = threadIdx.x;
    int c = t & 63, p = t >> 6;
    if (t < 80) idxl[t] = idx[((long)b * 2048 + n0) * KNNK + t];
    __syncthreads();
    float qv = Q[((long)b * 2048 + n0 + p) * 64 + c];
    float sc = s[c], tc = tt[c];
    float m = -INFINITY;
    for (int kk = 0; kk < KNNK; ++kk) {
        int j = idxl[p * KNNK + kk];
        float v = P[((long)b * 2048 + j) * 64 + c];
        m = fmaxf(m, lrelu(fmaf(sc, v + qv, tc)));
    }
    out[(long)b * (192 * 2048) + (long)(cofs + c) * 2048 + n0 + p] = m;
}

// ---------------- FP32 head GEMM (fallback only, if workspace too small) ----------------
__global__ __launch_bounds__(256) void gemm_kernel(
    const float* __restrict__ W, int ldw, int Kdim, const float* __restrict__ X, long xbstride,
    const float* __restrict__ s, const float* __restrict__ tvec, const float* __restrict__ bias, int M,
    float* __restrict__ out, long obstride, float* __restrict__ maxout) {
    __shared__ __align__(16) float wl[32 * 68];
    __shared__ __align__(16) float xl[32 * 132];
    int b = blockIdx.z, ct = blockIdx.x * 64, nt = blockIdx.y * 128, t = threadIdx.x;
    const float* Xb = X + (long)b * xbstride;
    int cg = t >> 4, ng = t & 15;
    float acc[4][8];
#pragma unroll
    for (int i = 0; i < 4; ++i)
#pragma unroll
        for (int j = 0; j < 8; ++j) acc[i][j] = 0.f;
    for (int k0 = 0; k0 < Kdim; k0 += 32) {
        __syncthreads();
        for (int e = t; e < 2048; e += 256) {
            int c = e >> 5, k = e & 31;
            wl[k * 68 + c] = W[(long)(ct + c) * ldw + k0 + k];
        }
        for (int e = t; e < 4096; e += 256) {
            int k = e >> 7, j = e & 127;
            xl[k * 132 + j] = Xb[(long)(k0 + k) * 2048 + nt + j];
        }
        __syncthreads();
#pragma unroll 8
        for (int k = 0; k < 32; ++k) {
            float4 w4 = *(const float4*)(wl + k * 68 + cg * 4);
            float4 xa = *(const float4*)(xl + k * 132 + ng * 4);
            float4 xb = *(const float4*)(xl + k * 132 + 64 + ng * 4);
            float wv[4] = {w4.x, w4.y, w4.z, w4.w};
            float xv[8] = {xa.x, xa.y, xa.z, xa.w, xb.x, xb.y, xb.z, xb.w};
#pragma unroll
            for (int i = 0; i < 4; ++i)
#pragma unroll
                for (int j = 0; j < 8; ++j) acc[i][j] = fmaf(wv[i], xv[j], acc[i][j]);
        }
    }
    if (maxout) {
        __syncthreads();
        float* scr = xl;
#pragma unroll
        for (int i = 0; i < 4; ++i) {
            int c = ct + cg * 4 + i;
            float sv = s[c], tv = tvec[c];
            float m = -INFINITY;
#pragma unroll
            for (int j = 0; j < 8; ++j) m = fmaxf(m, lrelu(fmaf(sv, acc[i][j], tv)));
            scr[(cg * 4 + i) * 16 + ng] = m;
        }
        __syncthreads();
        if (t < 64) {
            float m = scr[t * 16];
            for (int j = 1; j < 16; ++j) m = fmaxf(m, scr[t * 16 + j]);
            maxout[((long)b * M + ct + t) * 16 + blockIdx.y] = m;
        }
    } else {
#pragma unroll
        for (int i = 0; i < 4; ++i) {
            int c = ct + cg * 4 + i;
            float bv = bias ? bias[b * M + c] : 0.f;
            float sv = s[c], tv = tvec[c];
            float4 o0, o1;
            o0.x = lrelu(fmaf(sv, acc[i][0] + bv, tv));
            o0.y = lrelu(fmaf(sv, acc[i][1] + bv, tv));
            o0.z = lrelu(fmaf(sv, acc[i][2] + bv, tv));
            o0.w = lrelu(fmaf(sv, acc[i][3] + bv, tv));
            o1.x = lrelu(fmaf(sv, acc[i][4] + bv, tv));
            o1.y = lrelu(fmaf(sv, acc[i][5] + bv, tv));
            o1.z = lrelu(fmaf(sv, acc[i][6] + bv, tv));
            o1.w = lrelu(fmaf(sv, acc[i][7] + bv, tv));
            float* op = out + (long)b * obstride + (long)c * 2048 + nt + ng * 4;
            *(float4*)op = o0;
            *(float4*)(op + 64) = o1;
        }
    }
}

// ---------------- bf16 hi/lo split of a weight matrix: W[m][koff+k] -> packed [M][K] ----------------
__global__ __launch_bounds__(256) void splitw_kernel(const float* __restrict__ W, int ldw, int koff, int K,
                                                     long total, u16* __restrict__ hi, u16* __restrict__ lo) {
    long i = (long)blockIdx.x * 256 + threadIdx.x;
    if (i >= total) return;
    long m = i / K, k = i - m * K;
    float v = W[m * ldw + koff + k];
    u16 h = f2bf(v);
    hi[i] = h;
    lo[i] = f2bf(v - bf2f(h));
}

// ---------------- cat f32 [b][192][2048] -> split-transposed bf16 [b][2048][192] ----------------
__global__ __launch_bounds__(256) void splitx_kernel(const float* __restrict__ cat, u16* __restrict__ hi,
                                                     u16* __restrict__ lo) {
    __shared__ float lds[32][65];
    int b = blockIdx.y;
    int kt = blockIdx.x % 6, nt = blockIdx.x / 6;
    int k0 = kt * 32, n0 = nt * 64;
    int t = threadIdx.x;
#pragma unroll
    for (int i = 0; i < 8; ++i) {
        int e = t + i * 256;
        int k = e >> 6, n = e & 63;
        lds[k][n] = cat[(long)b * (192 * 2048) + (long)(k0 + k) * 2048 + n0 + n];
    }
    __syncthreads();
    int n = t >> 2, kq = t & 3;
    u16 hv[8], lv[8];
#pragma unroll
    for (int i = 0; i < 8; ++i) {
        float v = lds[kq * 8 + i][n];
        u16 h = f2bf(v);
        hv[i] = h;
        lv[i] = f2bf(v - bf2f(h));
    }
    long off = ((long)b * 2048 + n0 + n) * 192 + k0 + kq * 8;
    uint4 uh, ul;
    uh.x = (u32)hv[0] | ((u32)hv[1] << 16); uh.y = (u32)hv[2] | ((u32)hv[3] << 16);
    uh.z = (u32)hv[4] | ((u32)hv[5] << 16); uh.w = (u32)hv[6] | ((u32)hv[7] << 16);
    ul.x = (u32)lv[0] | ((u32)lv[1] << 16); ul.y = (u32)lv[2] | ((u32)lv[3] << 16);
    ul.z = (u32)lv[4] | ((u32)lv[5] << 16); ul.w = (u32)lv[6] | ((u32)lv[7] << 16);
    *(uint4*)(hi + off) = uh;
    *(uint4*)(lo + off) = ul;
}

// ---------------- bf16x3 MFMA head GEMM ----------------
template <int MT, int NT, bool MAXOUT>
__global__ __launch_bounds__(256, 2) void gemm_mfma(
    const u16* __restrict__ Whi, const u16* __restrict__ Wlo, const u16* __restrict__ Xhi,
    const u16* __restrict__ Xlo, int K, int M, const float* __restrict__ s,
    const float* __restrict__ tvec, const float* __restrict__ bias, float* __restrict__ outf,
    long obstride, u16* __restrict__ ohi, u16* __restrict__ olo, int oK, float* __restrict__ maxout) {
    constexpr int BM = MT * 32, BN = NT * 32;
    __shared__ __align__(16) u16 Ah[BM * 32], Al[BM * 32], Bh[BN * 32], Bl[BN * 32];
    __shared__ float scr[MAXOUT ? BM * 2 : 1];

    int b = blockIdx.z;
    int m0 = blockIdx.x * BM;
    int n0 = blockIdx.y * BN;
    int t = threadIdx.x;
    int wave = t >> 6, lane = t & 63;
    int wm = (wave >> 1) * (MT * 16);
    int wn = (wave & 1) * (NT * 16);
    const int l15 = lane & 15, lq = lane >> 4;
    const int kcs = lq ^ ((l15 >> 1) & 3);

    const u16* Xbh = Xhi + (long)b * 2048 * K;
    const u16* Xbl = Xlo + (long)b * 2048 * K;

    f32x4 zero4 = {0.f, 0.f, 0.f, 0.f};
    f32x4 acc[MT][NT];
#pragma unroll
    for (int i = 0; i < MT; ++i)
#pragma unroll
        for (int j = 0; j < NT; ++j) acc[i][j] = zero4;

    for (int k0 = 0; k0 < K; k0 += 32) {
        __syncthreads();
#pragma unroll
        for (int u = t; u < BM * 4; u += 256) {
            int row = u >> 2, kc = (u & 3) ^ ((row >> 1) & 3);
            long ga = (long)(m0 + row) * K + k0 + kc * 8;
            *(uint4*)(Ah + u * 8) = *(const uint4*)(Whi + ga);
            *(uint4*)(Al + u * 8) = *(const uint4*)(Wlo + ga);
        }
#pragma unroll
        for (int u = t; u < BN * 4; u += 256) {
            int row = u >> 2, kc = (u & 3) ^ ((row >> 1) & 3);
            long ga = (long)(n0 + row) * K + k0 + kc * 8;
            *(uint4*)(Bh + u * 8) = *(const uint4*)(Xbh + ga);
            *(uint4*)(Bl + u * 8) = *(const uint4*)(Xbl + ga);
        }
        __syncthreads();
        short8v a_h[MT], a_l[MT], b_h[NT], b_l[NT];
#pragma unroll
        for (int i = 0; i < MT; ++i) {
            int u = (wm + i * 16 + l15) * 4 + kcs;
            a_h[i] = *(const short8v*)(Ah + u * 8);
            a_l[i] = *(const short8v*)(Al + u * 8);
        }
#pragma unroll
        for (int j = 0; j < NT; ++j) {
            int u = (wn + j * 16 + l15) * 4 + kcs;
            b_h[j] = *(const short8v*)(Bh + u * 8);
            b_l[j] = *(const short8v*)(Bl + u * 8);
        }
#pragma unroll
        for (int i = 0; i < MT; ++i)
#pragma unroll
            for (int j = 0; j < NT; ++j) {
                acc[i][j] = __builtin_amdgcn_mfma_f32_16x16x32_bf16(a_h[i], b_h[j], acc[i][j], 0, 0, 0);
                acc[i][j] = __builtin_amdgcn_mfma_f32_16x16x32_bf16(a_h[i], b_l[j], acc[i][j], 0, 0, 0);
                acc[i][j] = __builtin_amdgcn_mfma_f32_16x16x32_bf16(a_l[i], b_h[j], acc[i][j], 0, 0, 0);
            }
    }

    if constexpr (MAXOUT) {
#pragma unroll
        for (int i = 0; i < MT; ++i)
#pragma unroll
            for (int r = 0; r < 4; ++r) {
                int ml = wm + i * 16 + lq * 4 + r;
                int c = m0 + ml;
                float sv = s[c], tv = tvec[c];
                float mx = -INFINITY;
#pragma unroll
                for (int j = 0; j < NT; ++j) mx = fmaxf(mx, lrelu(fmaf(sv, acc[i][j][r], tv)));
                mx = fmaxf(mx, __shfl_xor(mx, 1));
                mx = fmaxf(mx, __shfl_xor(mx, 2));
                mx = fmaxf(mx, __shfl_xor(mx, 4));
                mx = fmaxf(mx, __shfl_xor(mx, 8));
                if (l15 == 0) scr[ml * 2 + (wave & 1)] = mx;
            }
        __syncthreads();
        if (t < BM) maxout[((long)b * M + m0 + t) * 16 + blockIdx.y] = fmaxf(scr[t * 2], scr[t * 2 + 1]);
    } else if (outf) {
#pragma unroll
        for (int i = 0; i < MT; ++i)
#pragma unroll
            for (int r = 0; r < 4; ++r) {
                int c = m0 + wm + i * 16 + lq * 4 + r;
                float sv = s[c], tv = tvec[c];
                float bv = bias ? bias[b * M + c] : 0.f;
                float* op = outf + (long)b * obstride + (long)c * 2048 + n0 + wn;
#pragma unroll
                for (int j = 0; j < NT; ++j) op[j * 16 + l15] = lrelu(fmaf(sv, acc[i][j][r] + bv, tv));
            }
    } else {
#pragma unroll
        for (int i = 0; i < MT; ++i) {
            float sv[4], tv[4], bv[4];
#pragma unroll
            for (int r = 0; r < 4; ++r) {
                int c = m0 + wm + i * 16 + lq * 4 + r;
                sv[r] = s[c];
                tv[r] = tvec[c];
                bv[r] = bias ? bias[b * M + c] : 0.f;
            }
#pragma unroll
            for (int j = 0; j < NT; ++j) {
                long nb = ((long)b * 2048 + n0 + wn + j * 16 + l15) * oK + m0 + wm + i * 16 + lq * 4;
                ushort4 uh, ul;
                float v0 = lrelu(fmaf(sv[0], acc[i][j][0] + bv[0], tv[0]));
                float v1 = lrelu(fmaf(sv[1], acc[i][j][1] + bv[1], tv[1]));
                float v2 = lrelu(fmaf(sv[2], acc[i][j][2] + bv[2], tv[2]));
                float v3 = lrelu(fmaf(sv[3], acc[i][j][3] + bv[3], tv[3]));
                u16 h0 = f2bf(v0), h1 = f2bf(v1), h2 = f2bf(v2), h3 = f2bf(v3);
                uh.x = h0; uh.y = h1; uh.z = h2; uh.w = h3;
                ul.x = f2bf(v0 - bf2f(h0));
                ul.y = f2bf(v1 - bf2f(h1));
                ul.z = f2bf(v2 - bf2f(h2));
                ul.w = f2bf(v3 - bf2f(h3));
                *(ushort4*)(ohi + nb) = uh;
                *(ushort4*)(olo + nb) = ul;
            }
        }
    }
}

// ---------------- finalize g = max over the 16 n-tile partials ----------------
__global__ __launch_bounds__(256) void gmax_final(const float* __restrict__ ep, float* __restrict__ g) {
    int i = blockIdx.x * 256 + threadIdx.x;
    float m = ep[i * 16];
    for (int j = 1; j < 16; ++j) m = fmaxf(m, ep[i * 16 + j]);
    g[i] = m;
}

// ---------------- bias7[b][co] = w7[co, :1024] @ g[b] ----------------
__global__ __launch_bounds__(64) void bias7_kernel(const float* __restrict__ w7, const float* __restrict__ g,
                                                   float* __restrict__ bias7) {
    int o = blockIdx.x;
    int b = o >> 9, co = o & 511;
    int lane = threadIdx.x;
    float acc = 0.f;
    for (int j = lane; j < 1024; j += 64) acc = fmaf(w7[(long)co * 1216 + j], g[b * 1024 + j], acc);
#pragma unroll
    for (int off = 32; off >= 1; off >>= 1) acc += __shfl_xor(acc, off);
    if (lane == 0) bias7[o] = acc;
}

// ---------------- y[b][n] = sigmoid(w9 @ h8[:, n]) ----------------
__global__ __launch_bounds__(256) void w9_kernel(const float* __restrict__ w9, const float* __restrict__ h8,
                                                 float* __restrict__ out) {
    int i = blockIdx.x * 256 + threadIdx.x;
    int b = i >> 11, n = i & 2047;
    const float* hb = h8 + (long)b * 256 * 2048 + n;
    float acc = 0.f;
    for (int c = 0; c < 256; ++c) acc = fmaf(w9[c], hb[c * 2048], acc);
    out[i] = 1.f / (1.f + expf(-acc));
}

extern "C" void kernel_launch(void* const* d_in, const int* in_sizes, int n_in,
                              void* d_out, int out_size, void* d_ws, size_t ws_size,
                              hipStream_t stream) {
    (void)in_sizes; (void)n_in; (void)out_size;
    const float* x  = (const float*)d_in[0];
    const float* w1 = (const float*)d_in[1];
    const float* w2 = (const float*)d_in[2];
    const float* w3 = (const float*)d_in[3];
    const float* w4 = (const float*)d_in[4];
    const float* w5 = (const float*)d_in[5];
    const float* w6 = (const float*)d_in[6];
    const float* w7 = (const float*)d_in[7];
    const float* w8 = (const float*)d_in[8];
    const float* w9 = (const float*)d_in[9];
    const float* s1 = (const float*)d_in[10]; const float* t1 = (const float*)d_in[11];
    const float* s2 = (const float*)d_in[12]; const float* t2 = (const float*)d_in[13];
    const float* s3 = (const float*)d_in[14]; const float* t3 = (const float*)d_in[15];
    const float* s4 = (const float*)d_in[16]; const float* t4 = (const float*)d_in[17];
    const float* s5 = (const float*)d_in[18]; const float* t5 = (const float*)d_in[19];
    const float* s6 = (const float*)d_in[20]; const float* t6 = (const float*)d_in[21];
    const float* s7 = (const float*)d_in[22]; const float* t7 = (const float*)d_in[23];
    const float* s8 = (const float*)d_in[24]; const float* t8 = (const float*)d_in[25];

    // workspace partition (floats, then ushorts)
    float* cat = (float*)d_ws;                       // 16*192*2048      = 6291456
    float* xxb = cat + (long)6291456;                // 16*2048          = 32768
    int* idxb = (int*)(xxb + 32768);                 // 16*2048*20 ints  = 655360
    float* ep = (float*)(idxb + 655360);             // 16*1024*16       = 262144
    float* g  = ep + 262144;                         // 16*1024          = 16384
    float* b7 = g + 16384;                           // 16*512           = 8192
    float* h8 = b7 + 8192;                           // 16*256*2048      = 8388608
    float* P  = h8 + 8388608;                        // 16*2048*64       = 2097152
    float* Q  = P + 2097152;                         // 16*2048*64       = 2097152
    u16* h7hi = (u16*)(Q + 2097152);                 // 16*2048*512 u16  = 16777216
    u16* h7lo = h7hi + 16777216;
    u16* cathi = h7lo + 16777216;                    // 16*2048*192 u16  = 6291456
    u16* catlo = cathi + 6291456;
    u16* w6h = catlo + 6291456;                      // 1024*192 = 196608
    u16* w6l = w6h + 196608;
    u16* w7h = w6l + 196608;                         // 512*192 = 98304
    u16* w7l = w7h + 98304;
    u16* w8h = w7l + 98304;                          // 256*512 = 131072
    u16* w8l = w8h + 131072;
    const size_t NEED = 173375488;                   // bytes for the full mfma layout
    bool big = ws_size >= NEED;

    // edge2 weight limbs alias the start of the h7 region (dead until the head)
    u16* w2L = h7hi;            // w2: h at +0, m at +4096, l at +8192
    u16* w4L = h7hi + 12288;    // w4 likewise

    dim3 blk(256);
    dim3 blk512(512);
    long catstride = 192 * 2048;

    if (big) {
        splitw3_kernel<<<16, blk, 0, stream>>>(w2, w2L, w2L + 4096, w2L + 8192);
        splitw3_kernel<<<16, blk, 0, stream>>>(w4, w4L, w4L + 4096, w4L + 8192);
    }

    // ---- stage 1 (C=2) ----
    xx_kernel<<<128, blk, 0, stream>>>(x, 2 * 2048, 2, xxb);
    knn_kernel<<<dim3(256, 16), blk512, 0, stream>>>(x, 2 * 2048, 2, xxb, idxb);
    pq_kernel<<<dim3(32, 16), blk, 0, stream>>>(x, 2 * 2048, 2, w1, P, Q);
    if (big)
        edge2_mfma_kernel<<<dim3(256, 16), blk, 0, stream>>>(P, Q, idxb, w2L, w2L + 4096, w2L + 8192,
                                                             s1, t1, s2, t2, cat, 0);
    else
        edge2_kernel<<<dim3(256, 16), blk, 0, stream>>>(P, Q, idxb, w2, s1, t1, s2, t2, cat, 0);
    // ---- stage 2 (C=64 on x1) ----
    xx_kernel<<<128, blk, 0, stream>>>(cat, catstride, 64, xxb);
    knn_kernel<<<dim3(256, 16), blk512, 0, stream>>>(cat, catstride, 64, xxb, idxb);
    pq_kernel<<<dim3(32, 16), blk, 0, stream>>>(cat, catstride, 64, w3, P, Q);
    if (big)
        edge2_mfma_kernel<<<dim3(256, 16), blk, 0, stream>>>(P, Q, idxb, w4L, w4L + 4096, w4L + 8192,
                                                             s3, t3, s4, t4, cat, 64);
    else
        edge2_kernel<<<dim3(256, 16), blk, 0, stream>>>(P, Q, idxb, w4, s3, t3, s4, t4, cat, 64);
    // ---- stage 3 (C=64 on x2) ----
    xx_kernel<<<128, blk, 0, stream>>>(cat + 64 * 2048, catstride, 64, xxb);
    knn_kernel<<<dim3(256, 16), blk512, 0, stream>>>(cat + 64 * 2048, catstride, 64, xxb, idxb);
    pq_kernel<<<dim3(32, 16), blk, 0, stream>>>(cat + 64 * 2048, catstride, 64, w5, P, Q);
    edge1_kernel<<<dim3(512, 16), blk, 0, stream>>>(P, Q, idxb, s5, t5, cat, 128);

    if (big) {
        // ---- head: bf16x3 MFMA path ----
        splitw_kernel<<<768, blk, 0, stream>>>(w6, 192, 0, 192, 196608, w6h, w6l);
        splitw_kernel<<<384, blk, 0, stream>>>(w7, 1216, 1024, 192, 98304, w7h, w7l);
        splitw_kernel<<<512, blk, 0, stream>>>(w8, 512, 0, 512, 131072, w8h, w8l);
        splitx_kernel<<<dim3(192, 16), blk, 0, stream>>>(cat, cathi, catlo);
        gemm_mfma<4, 4, true><<<dim3(8, 16, 16), blk, 0, stream>>>(
            w6h, w6l, cathi, catlo, 192, 1024, s6, t6, nullptr, nullptr, 0, nullptr, nullptr, 0, ep);
        gmax_final<<<64, blk, 0, stream>>>(ep, g);
        bias7_kernel<<<dim3(16 * 512), dim3(64), 0, stream>>>(w7, g, b7);
        gemm_mfma<4, 4, false><<<dim3(4, 16, 16), blk, 0, stream>>>(
            w7h, w7l, cathi, catlo, 192, 512, s7, t7, b7, nullptr, 0, h7hi, h7lo, 512, nullptr);
        gemm_mfma<2, 4, false><<<dim3(4, 16, 16), blk, 0, stream>>>(
            w8h, w8l, h7hi, h7lo, 512, 256, s8, t8, nullptr, h8, (long)256 * 2048, nullptr, nullptr, 0,
            nullptr);
        w9_kernel<<<128, blk, 0, stream>>>(w9, h8, (float*)d_out);
    } else {
        // ---- head: fp32 fallback ----
        float* h7f = (float*)h7hi;
        gemm_kernel<<<dim3(16, 16, 16), blk, 0, stream>>>(w6, 192, 192, cat, catstride, s6, t6, nullptr,
                                                          1024, nullptr, 0, ep);
        gmax_final<<<64, blk, 0, stream>>>(ep, g);
        bias7_kernel<<<dim3(16 * 512), dim3(64), 0, stream>>>(w7, g, b7);
        gemm_kernel<<<dim3(8, 16, 16), blk, 0, stream>>>(w7 + 1024, 1216, 192, cat, catstride, s7, t7, b7,
                                                         512, h7f, (long)512 * 2048, nullptr);
        gemm_kernel<<<dim3(4, 16, 16), blk, 0, stream>>>(w8, 512, 512, h7f, (long)512 * 2048, s8, t8,
                                                         nullptr, 256, h8, (long)256 * 2048, nullptr);
        w9_kernel<<<128, blk, 0, stream>>>(w9, h8, (float*)d_out);
    }
}

// Round 11
// 1080.013 us; speedup vs baseline: 1.1915x; 1.0820x over previous
//
#include <hip/hip_runtime.h>
#include <math.h>

#define KNNK 20

typedef unsigned short u16;
typedef unsigned int u32;
typedef unsigned long long u64;
typedef __attribute__((ext_vector_type(8))) short short8v;   // 8 bf16 (4 VGPRs)
typedef __attribute__((ext_vector_type(4))) float f32x4;     // MFMA accumulator

__device__ __forceinline__ float lrelu(float v) { return v >= 0.f ? v : 0.2f * v; }

// round-to-nearest-even fp32 -> bf16 (bit trick)
__device__ __forceinline__ u16 f2bf(float v) {
    u32 u = __float_as_uint(v);
    u += 0x7fffu + ((u >> 16) & 1u);
    return (u16)(u >> 16);
}
__device__ __forceinline__ float bf2f(u16 h) { return __uint_as_float(((u32)h) << 16); }

// monotonic fp32 -> u32 map: a > b (float, no NaN)  <=>  ordf(a) > ordf(b) (uint)
__device__ __forceinline__ u32 ordf(float v) {
    u32 u = __float_as_uint(v);
    return u ^ ((u32)((int)u >> 31) | 0x80000000u);
}
// (value desc, index asc) total order as single u64
__device__ __forceinline__ u64 mkkey(float v, int g) {
    return ((u64)ordf(v) << 32) | (u32)(~(u32)g);
}

// 8 contiguous fp32 (LDS) -> three bf16x8 limb fragments (exact 3-way split, round-2-validated)
__device__ __forceinline__ void cvt8(const float* __restrict__ p, short8v& H8, short8v& M8, short8v& L8) {
    float4 a = *(const float4*)(p);
    float4 b4 = *(const float4*)(p + 4);
    float v[8] = {a.x, a.y, a.z, a.w, b4.x, b4.y, b4.z, b4.w};
    short8v H, M, L;
#pragma unroll
    for (int i = 0; i < 8; ++i) {
        float x = v[i];
        u16 h = f2bf(x);
        float r1 = x - bf2f(h);    // exact
        u16 m = f2bf(r1);
        float r2 = r1 - bf2f(m);   // exact
        H[i] = (short)h;
        M[i] = (short)m;
        L[i] = (short)f2bf(r2);
    }
    H8 = H; M8 = M; L8 = L;
}

// ---------------- xx[b][n] = sum_c f[b][c][n]^2 ----------------
__global__ __launch_bounds__(256) void xx_kernel(const float* __restrict__ f, long bstride, int C,
                                                 float* __restrict__ xx) {
    int i = blockIdx.x * 256 + threadIdx.x;   // over B*N
    int b = i >> 11, n = i & 2047;
    const float* fb = f + (long)b * bstride;
    float s = 0.f;
    for (int c = 0; c < C; ++c) { float v = fb[c * 2048 + n]; s = fmaf(v, v, s); }
    xx[i] = s;
}

// ---------------- top-20 over a 1024-col half row; returns sorted key (lanes 0..19 = ranks) ----------------
// (r7/r9/r10-validated: exact u64-key total order = JAX top_k; indices are colbase-global)
__device__ __forceinline__ u64 topk20_half(const float* __restrict__ srow, int lane, int colbase) {
    float b1 = -INFINITY, b2 = -INFINITY, b3 = -INFINITY;
    int j1 = 0, j2 = 0, j3 = 0;
#pragma unroll
    for (int j = 0; j < 16; ++j) {
        float vv = srow[lane + 64 * j];
        bool c1 = vv > b1;
        bool c2 = vv > b2;
        bool c3 = vv > b3;
        b3 = c2 ? b2 : (c3 ? vv : b3);
        j3 = c2 ? j2 : (c3 ? j : j3);
        b2 = c1 ? b1 : (c2 ? vv : b2);
        j2 = c1 ? j1 : (c2 ? j : j2);
        b1 = c1 ? vv : b1;
        j1 = c1 ? j : j1;
    }
    u64 ka = mkkey(b1, colbase + lane + (j1 << 6));
#pragma unroll
    for (int size = 2; size <= 64; size <<= 1) {
#pragma unroll
        for (int stride = size >> 1; stride >= 1; stride >>= 1) {
            u64 ok = __shfl_xor(ka, stride);
            bool low = (lane & stride) == 0;
            bool asc = (lane & size) == 0;
            bool f = ka > ok;
            bool take = (low == asc) ? f : !f;
            ka = take ? ka : ok;
        }
    }
    u64 w19 = __shfl(ka, 19);
    unsigned used = (1u << j1) | (1u << j2) | (1u << j3);
    u64 pend = mkkey(b2, colbase + lane + (j2 << 6));
    int pstate = 0;
    while (__any(pend > w19)) {
        u64 act = __ballot(pend > w19);
        int L = __ffsll((long long)act) - 1;
        u64 ck = __shfl(pend, L);
        u64 cfb = __ballot(lane < 20 && ck > ka);
        int p = 20 - __popcll(cfb);
        u64 up = __shfl_up(ka, 1);
        if (lane < 20) {
            if (lane > p) ka = up;
            else if (lane == p) ka = ck;
        }
        if (lane == L) {
            if (pstate == 0) {
                pend = mkkey(b3, colbase + lane + (j3 << 6));
                pstate = 1;
            } else {
                float nb = -INFINITY;
                int nj = 0;
#pragma unroll
                for (int j = 0; j < 16; ++j) {
                    float vvv = ((used >> j) & 1u) ? -INFINITY : srow[lane + 64 * j];
                    if (vvv > nb) { nb = vvv; nj = j; }
                }
                used |= 1u << nj;
                pend = mkkey(nb, colbase + lane + (nj << 6));
            }
        }
        w19 = __shfl(ka, 19);
    }
    return ka;
}

// ---------------- exact merge of two sorted top-20 key lists (r7/r9/r10-validated) ----------------
__device__ __forceinline__ u64 merge20(u64 kA, u64 kB, int lane) {
    u64 kb = __shfl(kB, (lane - 20) & 63);
    u64 ka = lane < 20 ? kA : (lane < 40 ? kb : 0ULL);   // 0 < any real key (ordf>0)
#pragma unroll
    for (int size = 2; size <= 64; size <<= 1) {
#pragma unroll
        for (int stride = size >> 1; stride >= 1; stride >>= 1) {
            u64 ok = __shfl_xor(ka, stride);
            bool low = (lane & stride) == 0;
            bool asc = (lane & size) == 0;
            bool f = ka > ok;
            bool take = (low == asc) ? f : !f;
            ka = take ? ka : ok;
        }
    }
    return ka;
}

// ---------------- KNN (fp32 Gram): 8-row strip, half-col selection, 35 KB LDS -> 4 blocks/CU ----------------
// Per-output c-ascending fma chain (bitwise = reference ordering). Wave w owns row w.
// Selection: topk20_half per column-half (validated) + exact merge20.
// NOTE r10 lesson: do NOT force 8 waves/EU via launch_bounds — it caps VGPR at 64 and the
// allocator spills acc to scratch (266 MB of HBM writes, 227 us). (512,4) allows 128 VGPR;
// kernel uses ~56, so actual occupancy is LDS-limited at 4 blocks/CU = 32 waves/CU.
__global__ __launch_bounds__(512, 4) void knn_kernel(const float* __restrict__ f, long bstride, int C,
                                                     const float* __restrict__ xx, int* __restrict__ idx_out) {
    __shared__ __align__(16) float pd[8 * 1028];   // ~32.9 KB
    __shared__ __align__(16) float Asm[64 * 8];    // [c][row], 2 KB (C<=64)
    int b = blockIdx.y;
    int n0 = blockIdx.x * 8;
    int t = threadIdx.x;
    const float* fb = f + (long)b * bstride;

    for (int e = t; e < C * 8; e += 512) {
        int c = e >> 3, j = e & 7;
        Asm[e] = fb[c * 2048 + n0 + j];
    }
    __syncthreads();

    float acc[8][4];
#pragma unroll
    for (int i = 0; i < 8; ++i)
#pragma unroll
        for (int j = 0; j < 4; ++j) acc[i][j] = 0.f;
    int m0 = t * 4;   // this thread's 4 columns (fixed)
    for (int c = 0; c < C; ++c) {
        float4 b4 = *(const float4*)(fb + c * 2048 + m0);
        float bv[4] = {b4.x, b4.y, b4.z, b4.w};
        const float* ar = Asm + c * 8;
        float4 a0 = *(const float4*)(ar);
        float4 a1 = *(const float4*)(ar + 4);
        float av[8] = {a0.x, a0.y, a0.z, a0.w, a1.x, a1.y, a1.z, a1.w};
#pragma unroll
        for (int i = 0; i < 8; ++i)
#pragma unroll
            for (int j = 0; j < 4; ++j) acc[i][j] = fmaf(av[i], bv[j], acc[i][j]);
    }
    float xn[8];
#pragma unroll
    for (int i = 0; i < 8; ++i) xn[i] = xx[b * 2048 + n0 + i];
    float4 xm4 = *(const float4*)(xx + b * 2048 + m0);
    float xm[4] = {xm4.x, xm4.y, xm4.z, xm4.w};

    int wave = t >> 6, lane = t & 63;

    // ---- half 0: cols 0..1023 (threads with m0 < 1024; wave-uniform branch) ----
    if (m0 < 1024) {
#pragma unroll
        for (int i = 0; i < 8; ++i) {
            float4 o;
            o.x = (2.f * acc[i][0] - xn[i]) - xm[0];
            o.y = (2.f * acc[i][1] - xn[i]) - xm[1];
            o.z = (2.f * acc[i][2] - xn[i]) - xm[2];
            o.w = (2.f * acc[i][3] - xn[i]) - xm[3];
            *(float4*)(pd + i * 1028 + m0) = o;
        }
    }
    __syncthreads();
    u64 kA = topk20_half(pd + wave * 1028, lane, 0);
    __syncthreads();   // all reads done before half-1 overwrites pd

    // ---- half 1: cols 1024..2047 ----
    if (m0 >= 1024) {
        int lc = m0 - 1024;
#pragma unroll
        for (int i = 0; i < 8; ++i) {
            float4 o;
            o.x = (2.f * acc[i][0] - xn[i]) - xm[0];
            o.y = (2.f * acc[i][1] - xn[i]) - xm[1];
            o.z = (2.f * acc[i][2] - xn[i]) - xm[2];
            o.w = (2.f * acc[i][3] - xn[i]) - xm[3];
            *(float4*)(pd + i * 1028 + lc) = o;
        }
    }
    __syncthreads();
    u64 kB = topk20_half(pd + wave * 1028, lane, 1024);

    u64 fk = merge20(kA, kB, lane);
    if (lane < KNNK) idx_out[((long)b * 2048 + n0 + wave) * KNNK + lane] = (int)(~(u32)fk) & 2047;
}

// ---------------- P = Wa @ f, Q = (Wb - Wa) @ f, stored (B, N, 64) n-major ----------------
__global__ __launch_bounds__(256) void pq_kernel(const float* __restrict__ f, long bstride, int C,
                                                 const float* __restrict__ W, float* __restrict__ P,
                                                 float* __restrict__ Q) {
    __shared__ __align__(16) float wa[64 * 64];
    __shared__ __align__(16) float wq[64 * 64];
    __shared__ __align__(16) float X[64 * 64];
    int b = blockIdx.y, n0 = blockIdx.x * 64, t = threadIdx.x;
    const float* fb = f + (long)b * bstride;
    for (int e = t; e < C * 64; e += 256) {
        int k = e >> 6, c = e & 63;
        float a = W[c * 2 * C + k];
        float bv = W[c * 2 * C + C + k];
        wa[k * 64 + c] = a;
        wq[k * 64 + c] = bv - a;
    }
    for (int e = t; e < C * 64; e += 256) {
        int k = e >> 6, j = e & 63;
        X[e] = fb[k * 2048 + n0 + j];
    }
    __syncthreads();
    int cg = t >> 4, ng = t & 15;
    float accP[4][4] = {}, accQ[4][4] = {};
    for (int k = 0; k < C; ++k) {
        float4 a4 = *(const float4*)(wa + k * 64 + cg * 4);
        float4 q4 = *(const float4*)(wq + k * 64 + cg * 4);
        float4 x4 = *(const float4*)(X + k * 64 + ng * 4);
        float av[4] = {a4.x, a4.y, a4.z, a4.w};
        float qv[4] = {q4.x, q4.y, q4.z, q4.w};
        float xv[4] = {x4.x, x4.y, x4.z, x4.w};
#pragma unroll
        for (int i = 0; i < 4; ++i)
#pragma unroll
            for (int j = 0; j < 4; ++j) {
                accP[i][j] = fmaf(av[i], xv[j], accP[i][j]);
                accQ[i][j] = fmaf(qv[i], xv[j], accQ[i][j]);
            }
    }
#pragma unroll
    for (int j = 0; j < 4; ++j) {
        long n = n0 + ng * 4 + j;
        float4 pv = {accP[0][j], accP[1][j], accP[2][j], accP[3][j]};
        float4 qv = {accQ[0][j], accQ[1][j], accQ[2][j], accQ[3][j]};
        *(float4*)(P + ((long)b * 2048 + n) * 64 + cg * 4) = pv;
        *(float4*)(Q + ((long)b * 2048 + n) * 64 + cg * 4) = qv;
    }
}

// ---------------- 3-limb bf16 split of a 64x64 weight (elementwise, [co][ci] kept) ----------------
__global__ __launch_bounds__(256) void splitw3_kernel(const float* __restrict__ W, u16* __restrict__ h,
                                                      u16* __restrict__ m, u16* __restrict__ l) {
    int i = blockIdx.x * 256 + threadIdx.x;   // < 4096
    float v = W[i];
    u16 hh = f2bf(v);
    float r1 = v - bf2f(hh);
    u16 mm = f2bf(r1);
    float r2 = r1 - bf2f(mm);
    h[i] = hh;
    m[i] = mm;
    l[i] = f2bf(r2);
}

// ---------------- EdgeConv layer-2 + max over k via MFMA (bf16x6, stages 1 & 2) ----------------
__global__ __launch_bounds__(256) void edge2_mfma_kernel(
    const float* __restrict__ P, const float* __restrict__ Q, const int* __restrict__ idx,
    const u16* __restrict__ Wh, const u16* __restrict__ Wm, const u16* __restrict__ Wl,
    const float* __restrict__ sa, const float* __restrict__ ta, const float* __restrict__ sb,
    const float* __restrict__ tb, float* __restrict__ out, int cofs) {
    __shared__ __align__(16) float h1t[192 * 68];   // [col][ci] fp32, pad 68; reused as h2 [col][co]
    __shared__ int idxl[160];
    int b = blockIdx.y, n0 = blockIdx.x * 8, t = threadIdx.x;
    if (t < 160) idxl[t] = idx[((long)b * 2048 + n0) * KNNK + t];
    __syncthreads();

    for (int it = t; it < 2560; it += 256) {
        int col = it % 160, cg = it / 160;
        int p = col / 20;
        int j = idxl[col];
        int n = n0 + p;
        float4 pv = *(const float4*)(P + ((long)b * 2048 + j) * 64 + cg * 4);
        float4 qv = *(const float4*)(Q + ((long)b * 2048 + n) * 64 + cg * 4);
        float4 sv = *(const float4*)(sa + cg * 4);
        float4 tv = *(const float4*)(ta + cg * 4);
        float4 o;
        o.x = lrelu(fmaf(sv.x, pv.x + qv.x, tv.x));
        o.y = lrelu(fmaf(sv.y, pv.y + qv.y, tv.y));
        o.z = lrelu(fmaf(sv.z, pv.z + qv.z, tv.z));
        o.w = lrelu(fmaf(sv.w, pv.w + qv.w, tv.w));
        *(float4*)(h1t + col * 68 + cg * 4) = o;
    }
    for (int it = t; it < 512; it += 256) {
        int col = 160 + (it & 31), cg = it >> 5;
        float4 z = {0.f, 0.f, 0.f, 0.f};
        *(float4*)(h1t + col * 68 + cg * 4) = z;
    }
    __syncthreads();

    int wave = t >> 6, lane = t & 63, l15 = lane & 15, lq = lane >> 4;
    f32x4 acc[3][4];
#pragma unroll
    for (int ct = 0; ct < 3; ++ct)
#pragma unroll
        for (int mt = 0; mt < 4; ++mt) {
            f32x4 z = {0.f, 0.f, 0.f, 0.f};
            acc[ct][mt] = z;
        }

#pragma unroll
    for (int ct = 0; ct < 3; ++ct) {
        int col = (wave * 3 + ct) * 16 + l15;
        short8v bh[2], bm[2], bl[2];
#pragma unroll
        for (int kh = 0; kh < 2; ++kh) cvt8(h1t + col * 68 + kh * 32 + lq * 8, bh[kh], bm[kh], bl[kh]);
#pragma unroll
        for (int mt = 0; mt < 4; ++mt) {
#pragma unroll
            for (int kh = 0; kh < 2; ++kh) {
                int wo = (mt * 16 + l15) * 64 + kh * 32 + lq * 8;
                short8v ah = *(const short8v*)(Wh + wo);
                short8v am = *(const short8v*)(Wm + wo);
                short8v al = *(const short8v*)(Wl + wo);
                acc[ct][mt] = __builtin_amdgcn_mfma_f32_16x16x32_bf16(ah, bh[kh], acc[ct][mt], 0, 0, 0);
                acc[ct][mt] = __builtin_amdgcn_mfma_f32_16x16x32_bf16(ah, bm[kh], acc[ct][mt], 0, 0, 0);
                acc[ct][mt] = __builtin_amdgcn_mfma_f32_16x16x32_bf16(am, bh[kh], acc[ct][mt], 0, 0, 0);
                acc[ct][mt] = __builtin_amdgcn_mfma_f32_16x16x32_bf16(am, bm[kh], acc[ct][mt], 0, 0, 0);
                acc[ct][mt] = __builtin_amdgcn_mfma_f32_16x16x32_bf16(ah, bl[kh], acc[ct][mt], 0, 0, 0);
                acc[ct][mt] = __builtin_amdgcn_mfma_f32_16x16x32_bf16(al, bh[kh], acc[ct][mt], 0, 0, 0);
            }
        }
    }
    __syncthreads();

#pragma unroll
    for (int ct = 0; ct < 3; ++ct) {
        int col = (wave * 3 + ct) * 16 + l15;
#pragma unroll
        for (int mt = 0; mt < 4; ++mt) {
            float4 d = {acc[ct][mt][0], acc[ct][mt][1], acc[ct][mt][2], acc[ct][mt][3]};
            *(float4*)(h1t + col * 68 + mt * 16 + lq * 4) = d;
        }
    }
    __syncthreads();

    for (int id = t; id < 512; id += 256) {
        int co = id & 63, p = id >> 6;
        float sv = sb[co], tv = tb[co];
        float m = -INFINITY;
#pragma unroll 4
        for (int kk = 0; kk < KNNK; ++kk)
            m = fmaxf(m, lrelu(fmaf(sv, h1t[(p * 20 + kk) * 68 + co], tv)));
        out[(long)b * (192 * 2048) + (long)(cofs + co) * 2048 + n0 + p] = m;
    }
}

// ---------------- EdgeConv layer-2 fp32 (fallback path) ----------------
__global__ __launch_bounds__(256) void edge2_kernel(
    const float* __restrict__ P, const float* __restrict__ Q, const int* __restrict__ idx,
    const float* __restrict__ W2, const float* __restrict__ sa, const float* __restrict__ ta,
    const float* __restrict__ sb, const float* __restrict__ tb, float* __restrict__ out, int cofs) {
    __shared__ __align__(16) float h1[64 * 164];
    __shared__ __align__(16) float w2l[64 * 64];
    __shared__ int idxl[160];
    int b = blockIdx.y, n0 = blockIdx.x * 8, t = threadIdx.x;
    if (t < 160) idxl[t] = idx[((long)b * 2048 + n0) * KNNK + t];
    for (int e = t; e < 4096; e += 256) { int co = e >> 6, ci = e & 63; w2l[ci * 64 + co] = W2[e]; }
    __syncthreads();
    for (int it = t; it < 2560; it += 256) {
        int col = it % 160, cg = it / 160;
        int p = col / 20;
        int j = idxl[col];
        int n = n0 + p;
        float4 pv = *(const float4*)(P + ((long)b * 2048 + j) * 64 + cg * 4);
        float4 qv = *(const float4*)(Q + ((long)b * 2048 + n) * 64 + cg * 4);
        float4 sv = *(const float4*)(sa + cg * 4);
        float4 tv = *(const float4*)(ta + cg * 4);
        h1[(cg * 4 + 0) * 164 + col] = lrelu(fmaf(sv.x, pv.x + qv.x, tv.x));
        h1[(cg * 4 + 1) * 164 + col] = lrelu(fmaf(sv.y, pv.y + qv.y, tv.y));
        h1[(cg * 4 + 2) * 164 + col] = lrelu(fmaf(sv.z, pv.z + qv.z, tv.z));
        h1[(cg * 4 + 3) * 164 + col] = lrelu(fmaf(sv.w, pv.w + qv.w, tv.w));
    }
    __syncthreads();
    int p = t & 7, co2 = t >> 3, c0 = co2 * 2;
    float acc0[20], acc1[20];
#pragma unroll
    for (int q = 0; q < 20; ++q) { acc0[q] = 0.f; acc1[q] = 0.f; }
#pragma unroll 4
    for (int k = 0; k < 64; ++k) {
        float2 w = *(const float2*)(w2l + k * 64 + c0);
        const float* hr = h1 + k * 164 + p * 20;
#pragma unroll
        for (int q = 0; q < 5; ++q) {
            float4 h4 = *(const float4*)(hr + q * 4);
            acc0[q * 4 + 0] = fmaf(w.x, h4.x, acc0[q * 4 + 0]);
            acc0[q * 4 + 1] = fmaf(w.x, h4.y, acc0[q * 4 + 1]);
            acc0[q * 4 + 2] = fmaf(w.x, h4.z, acc0[q * 4 + 2]);
            acc0[q * 4 + 3] = fmaf(w.x, h4.w, acc0[q * 4 + 3]);
            acc1[q * 4 + 0] = fmaf(w.y, h4.x, acc1[q * 4 + 0]);
            acc1[q * 4 + 1] = fmaf(w.y, h4.y, acc1[q * 4 + 1]);
            acc1[q * 4 + 2] = fmaf(w.y, h4.z, acc1[q * 4 + 2]);
            acc1[q * 4 + 3] = fmaf(w.y, h4.w, acc1[q * 4 + 3]);
        }
    }
    float s0 = sb[c0], t0v = tb[c0], s1 = sb[c0 + 1], t1v = tb[c0 + 1];
    float m0 = -INFINITY, m1 = -INFINITY;
#pragma unroll
    for (int q = 0; q < 20; ++q) {
        m0 = fmaxf(m0, lrelu(fmaf(s0, acc0[q], t0v)));
        m1 = fmaxf(m1, lrelu(fmaf(s1, acc1[q], t1v)));
    }
    out[(long)b * (192 * 2048) + (long)(cofs + c0) * 2048 + n0 + p] = m0;
    out[(long)b * (192 * 2048) + (long)(cofs + c0 + 1) * 2048 + n0 + p] = m1;
}

// ---------------- Stage 3: gather + affine + lrelu + max over k ----------------
__global__ __launch_bounds__(256) void edge1_kernel(const float* __restrict__ P, const float* __restrict__ Q,
                                                    const int* __restrict__ idx, const float* __restrict__ s,
                                                    const float* __restrict__ tt, float* __restrict__ out,
                                                    int cofs) {
    __shared__ int idxl[80];
    int b = blockIdx.y, n0 = blockIdx.x * 4, t = threadIdx.x;
    int c = t & 63, p = t >> 6;
    if (t < 80) idxl[t] = idx[((long)b * 2048 + n0) * KNNK + t];
    __syncthreads();
    float qv = Q[((long)b * 2048 + n0 + p) * 64 + c];
    float sc = s[c], tc = tt[c];
    float m = -INFINITY;
    for (int kk = 0; kk < KNNK; ++kk) {
        int j = idxl[p * KNNK + kk];
        float v = P[((long)b * 2048 + j) * 64 + c];
        m = fmaxf(m, lrelu(fmaf(sc, v + qv, tc)));
    }
    out[(long)b * (192 * 2048) + (long)(cofs + c) * 2048 + n0 + p] = m;
}

// ---------------- FP32 head GEMM (fallback only, if workspace too small) ----------------
__global__ __launch_bounds__(256) void gemm_kernel(
    const float* __restrict__ W, int ldw, int Kdim, const float* __restrict__ X, long xbstride,
    const float* __restrict__ s, const float* __restrict__ tvec, const float* __restrict__ bias, int M,
    float* __restrict__ out, long obstride, float* __restrict__ maxout) {
    __shared__ __align__(16) float wl[32 * 68];
    __shared__ __align__(16) float xl[32 * 132];
    int b = blockIdx.z, ct = blockIdx.x * 64, nt = blockIdx.y * 128, t = threadIdx.x;
    const float* Xb = X + (long)b * xbstride;
    int cg = t >> 4, ng = t & 15;
    float acc[4][8];
#pragma unroll
    for (int i = 0; i < 4; ++i)
#pragma unroll
        for (int j = 0; j < 8; ++j) acc[i][j] = 0.f;
    for (int k0 = 0; k0 < Kdim; k0 += 32) {
        __syncthreads();
        for (int e = t; e < 2048; e += 256) {
            int c = e >> 5, k = e & 31;
            wl[k * 68 + c] = W[(long)(ct + c) * ldw + k0 + k];
        }
        for (int e = t; e < 4096; e += 256) {
            int k = e >> 7, j = e & 127;
            xl[k * 132 + j] = Xb[(long)(k0 + k) * 2048 + nt + j];
        }
        __syncthreads();
#pragma unroll 8
        for (int k = 0; k < 32; ++k) {
            float4 w4 = *(const float4*)(wl + k * 68 + cg * 4);
            float4 xa = *(const float4*)(xl + k * 132 + ng * 4);
            float4 xb = *(const float4*)(xl + k * 132 + 64 + ng * 4);
            float wv[4] = {w4.x, w4.y, w4.z, w4.w};
            float xv[8] = {xa.x, xa.y, xa.z, xa.w, xb.x, xb.y, xb.z, xb.w};
#pragma unroll
            for (int i = 0; i < 4; ++i)
#pragma unroll
                for (int j = 0; j < 8; ++j) acc[i][j] = fmaf(wv[i], xv[j], acc[i][j]);
        }
    }
    if (maxout) {
        __syncthreads();
        float* scr = xl;
#pragma unroll
        for (int i = 0; i < 4; ++i) {
            int c = ct + cg * 4 + i;
            float sv = s[c], tv = tvec[c];
            float m = -INFINITY;
#pragma unroll
            for (int j = 0; j < 8; ++j) m = fmaxf(m, lrelu(fmaf(sv, acc[i][j], tv)));
            scr[(cg * 4 + i) * 16 + ng] = m;
        }
        __syncthreads();
        if (t < 64) {
            float m = scr[t * 16];
            for (int j = 1; j < 16; ++j) m = fmaxf(m, scr[t * 16 + j]);
            maxout[((long)b * M + ct + t) * 16 + blockIdx.y] = m;
        }
    } else {
#pragma unroll
        for (int i = 0; i < 4; ++i) {
            int c = ct + cg * 4 + i;
            float bv = bias ? bias[b * M + c] : 0.f;
            float sv = s[c], tv = tvec[c];
            float4 o0, o1;
            o0.x = lrelu(fmaf(sv, acc[i][0] + bv, tv));
            o0.y = lrelu(fmaf(sv, acc[i][1] + bv, tv));
            o0.z = lrelu(fmaf(sv, acc[i][2] + bv, tv));
            o0.w = lrelu(fmaf(sv, acc[i][3] + bv, tv));
            o1.x = lrelu(fmaf(sv, acc[i][4] + bv, tv));
            o1.y = lrelu(fmaf(sv, acc[i][5] + bv, tv));
            o1.z = lrelu(fmaf(sv, acc[i][6] + bv, tv));
            o1.w = lrelu(fmaf(sv, acc[i][7] + bv, tv));
            float* op = out + (long)b * obstride + (long)c * 2048 + nt + ng * 4;
            *(float4*)op = o0;
            *(float4*)(op + 64) = o1;
        }
    }
}

// ---------------- bf16 hi/lo split of a weight matrix: W[m][koff+k] -> packed [M][K] ----------------
__global__ __launch_bounds__(256) void splitw_kernel(const float* __restrict__ W, int ldw, int koff, int K,
                                                     long total, u16* __restrict__ hi, u16* __restrict__ lo) {
    long i = (long)blockIdx.x * 256 + threadIdx.x;
    if (i >= total) return;
    long m = i / K, k = i - m * K;
    float v = W[m * ldw + koff + k];
    u16 h = f2bf(v);
    hi[i] = h;
    lo[i] = f2bf(v - bf2f(h));
}

// ---------------- cat f32 [b][192][2048] -> split-transposed bf16 [b][2048][192] ----------------
__global__ __launch_bounds__(256) void splitx_kernel(const float* __restrict__ cat, u16* __restrict__ hi,
                                                     u16* __restrict__ lo) {
    __shared__ float lds[32][65];
    int b = blockIdx.y;
    int kt = blockIdx.x % 6, nt = blockIdx.x / 6;
    int k0 = kt * 32, n0 = nt * 64;
    int t = threadIdx.x;
#pragma unroll
    for (int i = 0; i < 8; ++i) {
        int e = t + i * 256;
        int k = e >> 6, n = e & 63;
        lds[k][n] = cat[(long)b * (192 * 2048) + (long)(k0 + k) * 2048 + n0 + n];
    }
    __syncthreads();
    int n = t >> 2, kq = t & 3;
    u16 hv[8], lv[8];
#pragma unroll
    for (int i = 0; i < 8; ++i) {
        float v = lds[kq * 8 + i][n];
        u16 h = f2bf(v);
        hv[i] = h;
        lv[i] = f2bf(v - bf2f(h));
    }
    long off = ((long)b * 2048 + n0 + n) * 192 + k0 + kq * 8;
    uint4 uh, ul;
    uh.x = (u32)hv[0] | ((u32)hv[1] << 16); uh.y = (u32)hv[2] | ((u32)hv[3] << 16);
    uh.z = (u32)hv[4] | ((u32)hv[5] << 16); uh.w = (u32)hv[6] | ((u32)hv[7] << 16);
    ul.x = (u32)lv[0] | ((u32)lv[1] << 16); ul.y = (u32)lv[2] | ((u32)lv[3] << 16);
    ul.z = (u32)lv[4] | ((u32)lv[5] << 16); ul.w = (u32)lv[6] | ((u32)lv[7] << 16);
    *(uint4*)(hi + off) = uh;
    *(uint4*)(lo + off) = ul;
}

// ---------------- bf16x3 MFMA head GEMM ----------------
template <int MT, int NT, bool MAXOUT>
__global__ __launch_bounds__(256, 2) void gemm_mfma(
    const u16* __restrict__ Whi, const u16* __restrict__ Wlo, const u16* __restrict__ Xhi,
    const u16* __restrict__ Xlo, int K, int M, const float* __restrict__ s,
    const float* __restrict__ tvec, const float* __restrict__ bias, float* __restrict__ outf,
    long obstride, u16* __restrict__ ohi, u16* __restrict__ olo, int oK, float* __restrict__ maxout) {
    constexpr int BM = MT * 32, BN = NT * 32;
    __shared__ __align__(16) u16 Ah[BM * 32], Al[BM * 32], Bh[BN * 32], Bl[BN * 32];
    __shared__ float scr[MAXOUT ? BM * 2 : 1];

    int b = blockIdx.z;
    int m0 = blockIdx.x * BM;
    int n0 = blockIdx.y * BN;
    int t = threadIdx.x;
    int wave = t >> 6, lane = t & 63;
    int wm = (wave >> 1) * (MT * 16);
    int wn = (wave & 1) * (NT * 16);
    const int l15 = lane & 15, lq = lane >> 4;
    const int kcs = lq ^ ((l15 >> 1) & 3);

    const u16* Xbh = Xhi + (long)b * 2048 * K;
    const u16* Xbl = Xlo + (long)b * 2048 * K;

    f32x4 zero4 = {0.f, 0.f, 0.f, 0.f};
    f32x4 acc[MT][NT];
#pragma unroll
    for (int i = 0; i < MT; ++i)
#pragma unroll
        for (int j = 0; j < NT; ++j) acc[i][j] = zero4;

    for (int k0 = 0; k0 < K; k0 += 32) {
        __syncthreads();
#pragma unroll
        for (int u = t; u < BM * 4; u += 256) {
            int row = u >> 2, kc = (u & 3) ^ ((row >> 1) & 3);
            long ga = (long)(m0 + row) * K + k0 + kc * 8;
            *(uint4*)(Ah + u * 8) = *(const uint4*)(Whi + ga);
            *(uint4*)(Al + u * 8) = *(const uint4*)(Wlo + ga);
        }
#pragma unroll
        for (int u = t; u < BN * 4; u += 256) {
            int row = u >> 2, kc = (u & 3) ^ ((row >> 1) & 3);
            long ga = (long)(n0 + row) * K + k0 + kc * 8;
            *(uint4*)(Bh + u * 8) = *(const uint4*)(Xbh + ga);
            *(uint4*)(Bl + u * 8) = *(const uint4*)(Xbl + ga);
        }
        __syncthreads();
        short8v a_h[MT], a_l[MT], b_h[NT], b_l[NT];
#pragma unroll
        for (int i = 0; i < MT; ++i) {
            int u = (wm + i * 16 + l15) * 4 + kcs;
            a_h[i] = *(const short8v*)(Ah + u * 8);
            a_l[i] = *(const short8v*)(Al + u * 8);
        }
#pragma unroll
        for (int j = 0; j < NT; ++j) {
            int u = (wn + j * 16 + l15) * 4 + kcs;
            b_h[j] = *(const short8v*)(Bh + u * 8);
            b_l[j] = *(const short8v*)(Bl + u * 8);
        }
#pragma unroll
        for (int i = 0; i < MT; ++i)
#pragma unroll
            for (int j = 0; j < NT; ++j) {
                acc[i][j] = __builtin_amdgcn_mfma_f32_16x16x32_bf16(a_h[i], b_h[j], acc[i][j], 0, 0, 0);
                acc[i][j] = __builtin_amdgcn_mfma_f32_16x16x32_bf16(a_h[i], b_l[j], acc[i][j], 0, 0, 0);
                acc[i][j] = __builtin_amdgcn_mfma_f32_16x16x32_bf16(a_l[i], b_h[j], acc[i][j], 0, 0, 0);
            }
    }

    if constexpr (MAXOUT) {
#pragma unroll
        for (int i = 0; i < MT; ++i)
#pragma unroll
            for (int r = 0; r < 4; ++r) {
                int ml = wm + i * 16 + lq * 4 + r;
                int c = m0 + ml;
                float sv = s[c], tv = tvec[c];
                float mx = -INFINITY;
#pragma unroll
                for (int j = 0; j < NT; ++j) mx = fmaxf(mx, lrelu(fmaf(sv, acc[i][j][r], tv)));
                mx = fmaxf(mx, __shfl_xor(mx, 1));
                mx = fmaxf(mx, __shfl_xor(mx, 2));
                mx = fmaxf(mx, __shfl_xor(mx, 4));
                mx = fmaxf(mx, __shfl_xor(mx, 8));
                if (l15 == 0) scr[ml * 2 + (wave & 1)] = mx;
            }
        __syncthreads();
        if (t < BM) maxout[((long)b * M + m0 + t) * 16 + blockIdx.y] = fmaxf(scr[t * 2], scr[t * 2 + 1]);
    } else if (outf) {
#pragma unroll
        for (int i = 0; i < MT; ++i)
#pragma unroll
            for (int r = 0; r < 4; ++r) {
                int c = m0 + wm + i * 16 + lq * 4 + r;
                float sv = s[c], tv = tvec[c];
                float bv = bias ? bias[b * M + c] : 0.f;
                float* op = outf + (long)b * obstride + (long)c * 2048 + n0 + wn;
#pragma unroll
                for (int j = 0; j < NT; ++j) op[j * 16 + l15] = lrelu(fmaf(sv, acc[i][j][r] + bv, tv));
            }
    } else {
#pragma unroll
        for (int i = 0; i < MT; ++i) {
            float sv[4], tv[4], bv[4];
#pragma unroll
            for (int r = 0; r < 4; ++r) {
                int c = m0 + wm + i * 16 + lq * 4 + r;
                sv[r] = s[c];
                tv[r] = tvec[c];
                bv[r] = bias ? bias[b * M + c] : 0.f;
            }
#pragma unroll
            for (int j = 0; j < NT; ++j) {
                long nb = ((long)b * 2048 + n0 + wn + j * 16 + l15) * oK + m0 + wm + i * 16 + lq * 4;
                ushort4 uh, ul;
                float v0 = lrelu(fmaf(sv[0], acc[i][j][0] + bv[0], tv[0]));
                float v1 = lrelu(fmaf(sv[1], acc[i][j][1] + bv[1], tv[1]));
                float v2 = lrelu(fmaf(sv[2], acc[i][j][2] + bv[2], tv[2]));
                float v3 = lrelu(fmaf(sv[3], acc[i][j][3] + bv[3], tv[3]));
                u16 h0 = f2bf(v0), h1 = f2bf(v1), h2 = f2bf(v2), h3 = f2bf(v3);
                uh.x = h0; uh.y = h1; uh.z = h2; uh.w = h3;
                ul.x = f2bf(v0 - bf2f(h0));
                ul.y = f2bf(v1 - bf2f(h1));
                ul.z = f2bf(v2 - bf2f(h2));
                ul.w = f2bf(v3 - bf2f(h3));
                *(ushort4*)(ohi + nb) = uh;
                *(ushort4*)(olo + nb) = ul;
            }
        }
    }
}

// ---------------- finalize g = max over the 16 n-tile partials ----------------
__global__ __launch_bounds__(256) void gmax_final(const float* __restrict__ ep, float* __restrict__ g) {
    int i = blockIdx.x * 256 + threadIdx.x;
    float m = ep[i * 16];
    for (int j = 1; j < 16; ++j) m = fmaxf(m, ep[i * 16 + j]);
    g[i] = m;
}

// ---------------- bias7[b][co] = w7[co, :1024] @ g[b] ----------------
__global__ __launch_bounds__(64) void bias7_kernel(const float* __restrict__ w7, const float* __restrict__ g,
                                                   float* __restrict__ bias7) {
    int o = blockIdx.x;
    int b = o >> 9, co = o & 511;
    int lane = threadIdx.x;
    float acc = 0.f;
    for (int j = lane; j < 1024; j += 64) acc = fmaf(w7[(long)co * 1216 + j], g[b * 1024 + j], acc);
#pragma unroll
    for (int off = 32; off >= 1; off >>= 1) acc += __shfl_xor(acc, off);
    if (lane == 0) bias7[o] = acc;
}

// ---------------- y[b][n] = sigmoid(w9 @ h8[:, n]) ----------------
__global__ __launch_bounds__(256) void w9_kernel(const float* __restrict__ w9, const float* __restrict__ h8,
                                                 float* __restrict__ out) {
    int i = blockIdx.x * 256 + threadIdx.x;
    int b = i >> 11, n = i & 2047;
    const float* hb = h8 + (long)b * 256 * 2048 + n;
    float acc = 0.f;
    for (int c = 0; c < 256; ++c) acc = fmaf(w9[c], hb[c * 2048], acc);
    out[i] = 1.f / (1.f + expf(-acc));
}

extern "C" void kernel_launch(void* const* d_in, const int* in_sizes, int n_in,
                              void* d_out, int out_size, void* d_ws, size_t ws_size,
                              hipStream_t stream) {
    (void)in_sizes; (void)n_in; (void)out_size;
    const float* x  = (const float*)d_in[0];
    const float* w1 = (const float*)d_in[1];
    const float* w2 = (const float*)d_in[2];
    const float* w3 = (const float*)d_in[3];
    const float* w4 = (const float*)d_in[4];
    const float* w5 = (const float*)d_in[5];
    const float* w6 = (const float*)d_in[6];
    const float* w7 = (const float*)d_in[7];
    const float* w8 = (const float*)d_in[8];
    const float* w9 = (const float*)d_in[9];
    const float* s1 = (const float*)d_in[10]; const float* t1 = (const float*)d_in[11];
    const float* s2 = (const float*)d_in[12]; const float* t2 = (const float*)d_in[13];
    const float* s3 = (const float*)d_in[14]; const float* t3 = (const float*)d_in[15];
    const float* s4 = (const float*)d_in[16]; const float* t4 = (const float*)d_in[17];
    const float* s5 = (const float*)d_in[18]; const float* t5 = (const float*)d_in[19];
    const float* s6 = (const float*)d_in[20]; const float* t6 = (const float*)d_in[21];
    const float* s7 = (const float*)d_in[22]; const float* t7 = (const float*)d_in[23];
    const float* s8 = (const float*)d_in[24]; const float* t8 = (const float*)d_in[25];

    // workspace partition (floats, then ushorts)
    float* cat = (float*)d_ws;                       // 16*192*2048      = 6291456
    float* xxb = cat + (long)6291456;                // 16*2048          = 32768
    int* idxb = (int*)(xxb + 32768);                 // 16*2048*20 ints  = 655360
    float* ep = (float*)(idxb + 655360);             // 16*1024*16       = 262144
    float* g  = ep + 262144;                         // 16*1024          = 16384
    float* b7 = g + 16384;                           // 16*512           = 8192
    float* h8 = b7 + 8192;                           // 16*256*2048      = 8388608
    float* P  = h8 + 8388608;                        // 16*2048*64       = 2097152
    float* Q  = P + 2097152;                         // 16*2048*64       = 2097152
    u16* h7hi = (u16*)(Q + 2097152);                 // 16*2048*512 u16  = 16777216
    u16* h7lo = h7hi + 16777216;
    u16* cathi = h7lo + 16777216;                    // 16*2048*192 u16  = 6291456
    u16* catlo = cathi + 6291456;
    u16* w6h = catlo + 6291456;                      // 1024*192 = 196608
    u16* w6l = w6h + 196608;
    u16* w7h = w6l + 196608;                         // 512*192 = 98304
    u16* w7l = w7h + 98304;
    u16* w8h = w7l + 98304;                          // 256*512 = 131072
    u16* w8l = w8h + 131072;
    const size_t NEED = 173375488;                   // bytes for the full mfma layout
    bool big = ws_size >= NEED;

    // edge2 weight limbs alias the start of the h7 region (dead until the head)
    u16* w2L = h7hi;            // w2: h at +0, m at +4096, l at +8192
    u16* w4L = h7hi + 12288;    // w4 likewise

    dim3 blk(256);
    dim3 blk512(512);
    long catstride = 192 * 2048;

    if (big) {
        splitw3_kernel<<<16, blk, 0, stream>>>(w2, w2L, w2L + 4096, w2L + 8192);
        splitw3_kernel<<<16, blk, 0, stream>>>(w4, w4L, w4L + 4096, w4L + 8192);
    }

    // ---- stage 1 (C=2) ----
    xx_kernel<<<128, blk, 0, stream>>>(x, 2 * 2048, 2, xxb);
    knn_kernel<<<dim3(256, 16), blk512, 0, stream>>>(x, 2 * 2048, 2, xxb, idxb);
    pq_kernel<<<dim3(32, 16), blk, 0, stream>>>(x, 2 * 2048, 2, w1, P, Q);
    if (big)
        edge2_mfma_kernel<<<dim3(256, 16), blk, 0, stream>>>(P, Q, idxb, w2L, w2L + 4096, w2L + 8192,
                                                             s1, t1, s2, t2, cat, 0);
    else
        edge2_kernel<<<dim3(256, 16), blk, 0, stream>>>(P, Q, idxb, w2, s1, t1, s2, t2, cat, 0);
    // ---- stage 2 (C=64 on x1) ----
    xx_kernel<<<128, blk, 0, stream>>>(cat, catstride, 64, xxb);
    knn_kernel<<<dim3(256, 16), blk512, 0, stream>>>(cat, catstride, 64, xxb, idxb);
    pq_kernel<<<dim3(32, 16), blk, 0, stream>>>(cat, catstride, 64, w3, P, Q);
    if (big)
        edge2_mfma_kernel<<<dim3(256, 16), blk, 0, stream>>>(P, Q, idxb, w4L, w4L + 4096, w4L + 8192,
                                                             s3, t3, s4, t4, cat, 64);
    else
        edge2_kernel<<<dim3(256, 16), blk, 0, stream>>>(P, Q, idxb, w4, s3, t3, s4, t4, cat, 64);
    // ---- stage 3 (C=64 on x2) ----
    xx_kernel<<<128, blk, 0, stream>>>(cat + 64 * 2048, catstride, 64, xxb);
    knn_kernel<<<dim3(256, 16), blk512, 0, stream>>>(cat + 64 * 2048, catstride, 64, xxb, idxb);
    pq_kernel<<<dim3(32, 16), blk, 0, stream>>>(cat + 64 * 2048, catstride, 64, w5, P, Q);
    edge1_kernel<<<dim3(512, 16), blk, 0, stream>>>(P, Q, idxb, s5, t5, cat, 128);

    if (big) {
        // ---- head: bf16x3 MFMA path ----
        splitw_kernel<<<768, blk, 0, stream>>>(w6, 192, 0, 192, 196608, w6h, w6l);
        splitw_kernel<<<384, blk, 0, stream>>>(w7, 1216, 1024, 192, 98304, w7h, w7l);
        splitw_kernel<<<512, blk, 0, stream>>>(w8, 512, 0, 512, 131072, w8h, w8l);
        splitx_kernel<<<dim3(192, 16), blk, 0, stream>>>(cat, cathi, catlo);
        gemm_mfma<4, 4, true><<<dim3(8, 16, 16), blk, 0, stream>>>(
            w6h, w6l, cathi, catlo, 192, 1024, s6, t6, nullptr, nullptr, 0, nullptr, nullptr, 0, ep);
        gmax_final<<<64, blk, 0, stream>>>(ep, g);
        bias7_kernel<<<dim3(16 * 512), dim3(64), 0, stream>>>(w7, g, b7);
        gemm_mfma<4, 4, false><<<dim3(4, 16, 16), blk, 0, stream>>>(
            w7h, w7l, cathi, catlo, 192, 512, s7, t7, b7, nullptr, 0, h7hi, h7lo, 512, nullptr);
        gemm_mfma<2, 4, false><<<dim3(4, 16, 16), blk, 0, stream>>>(
            w8h, w8l, h7hi, h7lo, 512, 256, s8, t8, nullptr, h8, (long)256 * 2048, nullptr, nullptr, 0,
            nullptr);
        w9_kernel<<<128, blk, 0, stream>>>(w9, h8, (float*)d_out);
    } else {
        // ---- head: fp32 fallback ----
        float* h7f = (float*)h7hi;
        gemm_kernel<<<dim3(16, 16, 16), blk, 0, stream>>>(w6, 192, 192, cat, catstride, s6, t6, nullptr,
                                                          1024, nullptr, 0, ep);
        gmax_final<<<64, blk, 0, stream>>>(ep, g);
        bias7_kernel<<<dim3(16 * 512), dim3(64), 0, stream>>>(w7, g, b7);
        gemm_kernel<<<dim3(8, 16, 16), blk, 0, stream>>>(w7 + 1024, 1216, 192, cat, catstride, s7, t7, b7,
                                                         512, h7f, (long)512 * 2048, nullptr);
        gemm_kernel<<<dim3(4, 16, 16), blk, 0, stream>>>(w8, 512, 512, h7f, (long)512 * 2048, s8, t8,
                                                         nullptr, 256, h8, (long)256 * 2048, nullptr);
        w9_kernel<<<128, blk, 0, stream>>>(w9, h8, (float*)d_out);
    }
}

// Round 12
// 1010.104 us; speedup vs baseline: 1.2740x; 1.0692x over previous
//
#include <hip/hip_runtime.h>
#include <math.h>

#define KNNK 20

typedef unsigned short u16;
typedef unsigned int u32;
typedef unsigned long long u64;
typedef __attribute__((ext_vector_type(8))) short short8v;   // 8 bf16 (4 VGPRs)
typedef __attribute__((ext_vector_type(4))) float f32x4;     // MFMA accumulator

__device__ __forceinline__ float lrelu(float v) { return v >= 0.f ? v : 0.2f * v; }

// round-to-nearest-even fp32 -> bf16 (bit trick)
__device__ __forceinline__ u16 f2bf(float v) {
    u32 u = __float_as_uint(v);
    u += 0x7fffu + ((u >> 16) & 1u);
    return (u16)(u >> 16);
}
__device__ __forceinline__ float bf2f(u16 h) { return __uint_as_float(((u32)h) << 16); }

// monotonic fp32 -> u32 map: a > b (float, no NaN)  <=>  ordf(a) > ordf(b) (uint)
__device__ __forceinline__ u32 ordf(float v) {
    u32 u = __float_as_uint(v);
    return u ^ ((u32)((int)u >> 31) | 0x80000000u);
}
// (value desc, index asc) total order as single u64
__device__ __forceinline__ u64 mkkey(float v, int g) {
    return ((u64)ordf(v) << 32) | (u32)(~(u32)g);
}

// 8 contiguous fp32 (LDS) -> three bf16x8 limb fragments (exact 3-way split, round-2-validated)
__device__ __forceinline__ void cvt8(const float* __restrict__ p, short8v& H8, short8v& M8, short8v& L8) {
    float4 a = *(const float4*)(p);
    float4 b4 = *(const float4*)(p + 4);
    float v[8] = {a.x, a.y, a.z, a.w, b4.x, b4.y, b4.z, b4.w};
    short8v H, M, L;
#pragma unroll
    for (int i = 0; i < 8; ++i) {
        float x = v[i];
        u16 h = f2bf(x);
        float r1 = x - bf2f(h);    // exact
        u16 m = f2bf(r1);
        float r2 = r1 - bf2f(m);   // exact
        H[i] = (short)h;
        M[i] = (short)m;
        L[i] = (short)f2bf(r2);
    }
    H8 = H; M8 = M; L8 = L;
}

// ---------------- xx[b][n] = sum_c f[b][c][n]^2 ----------------
__global__ __launch_bounds__(256) void xx_kernel(const float* __restrict__ f, long bstride, int C,
                                                 float* __restrict__ xx) {
    int i = blockIdx.x * 256 + threadIdx.x;   // over B*N
    int b = i >> 11, n = i & 2047;
    const float* fb = f + (long)b * bstride;
    float s = 0.f;
    for (int c = 0; c < C; ++c) { float v = fb[c * 2048 + n]; s = fmaf(v, v, s); }
    xx[i] = s;
}

// ---------------- shared top-20 selection over 2048 (exact, order = JAX top_k) ----------------
__device__ __forceinline__ void topk_row(const float* __restrict__ srow, int lane, int* __restrict__ orow) {
    float b1 = -INFINITY, b2 = -INFINITY, b3 = -INFINITY;
    int j1 = 0, j2 = 0, j3 = 0;
#pragma unroll
    for (int j = 0; j < 32; ++j) {
        float vv = srow[lane + 64 * j];
        bool c1 = vv > b1;
        bool c2 = vv > b2;
        bool c3 = vv > b3;
        b3 = c2 ? b2 : (c3 ? vv : b3);
        j3 = c2 ? j2 : (c3 ? j : j3);
        b2 = c1 ? b1 : (c2 ? vv : b2);
        j2 = c1 ? j1 : (c2 ? j : j2);
        b1 = c1 ? vv : b1;
        j1 = c1 ? j : j1;
    }
    u64 ka = mkkey(b1, lane + (j1 << 6));
#pragma unroll
    for (int size = 2; size <= 64; size <<= 1) {
#pragma unroll
        for (int stride = size >> 1; stride >= 1; stride >>= 1) {
            u64 ok = __shfl_xor(ka, stride);
            bool low = (lane & stride) == 0;
            bool asc = (lane & size) == 0;
            bool f = ka > ok;
            bool take = (low == asc) ? f : !f;
            ka = take ? ka : ok;
        }
    }
    u64 w19 = __shfl(ka, 19);
    unsigned used = (1u << j1) | (1u << j2) | (1u << j3);
    u64 pend = mkkey(b2, lane + (j2 << 6));
    int pstate = 0;
    while (__any(pend > w19)) {
        u64 act = __ballot(pend > w19);
        int L = __ffsll((long long)act) - 1;
        u64 ck = __shfl(pend, L);
        u64 cfb = __ballot(lane < 20 && ck > ka);
        int p = 20 - __popcll(cfb);
        u64 up = __shfl_up(ka, 1);
        if (lane < 20) {
            if (lane > p) ka = up;
            else if (lane == p) ka = ck;
        }
        if (lane == L) {
            if (pstate == 0) {
                pend = mkkey(b3, lane + (j3 << 6));
                pstate = 1;
            } else {
                float nb = -INFINITY;
                int nj = 0;
#pragma unroll
                for (int j = 0; j < 32; ++j) {
                    float vvv = ((used >> j) & 1u) ? -INFINITY : srow[lane + 64 * j];
                    if (vvv > nb) { nb = vvv; nj = j; }
                }
                used |= 1u << nj;
                pend = mkkey(nb, lane + (nj << 6));
            }
        }
        w19 = __shfl(ka, 19);
    }
    if (lane < KNNK) orow[lane] = (int)(~(u32)ka) & 2047;
}

// ---------------- KNN (fp32 Gram): 16-row strip, acc in regs, two topk phases ----------------
// r5-validated best: 172 us per C=64 launch. Per-output c-ascending fma chain (bitwise = reference).
__global__ __launch_bounds__(512, 4) void knn_kernel(const float* __restrict__ f, long bstride, int C,
                                                     const float* __restrict__ xx, int* __restrict__ idx_out) {
    __shared__ __align__(16) float pd[8 * 2048];
    __shared__ __align__(16) float Asm[16 * 64];
    int b = blockIdx.y;
    int n0 = blockIdx.x * 16;
    int t = threadIdx.x;
    const float* fb = f + (long)b * bstride;

    for (int e = t; e < C * 16; e += 512) {
        int c = e >> 4, j = e & 15;
        Asm[e] = fb[c * 2048 + n0 + j];
    }
    __syncthreads();

    float acc[16][4];
#pragma unroll
    for (int i = 0; i < 16; ++i)
#pragma unroll
        for (int j = 0; j < 4; ++j) acc[i][j] = 0.f;
    int m0 = t * 4;
    for (int c = 0; c < C; ++c) {
        float4 b4 = *(const float4*)(fb + c * 2048 + m0);
        float bv[4] = {b4.x, b4.y, b4.z, b4.w};
        const float* ar = Asm + c * 16;
        float4 a0 = *(const float4*)(ar);
        float4 a1 = *(const float4*)(ar + 4);
        float4 a2 = *(const float4*)(ar + 8);
        float4 a3 = *(const float4*)(ar + 12);
        float av[16] = {a0.x, a0.y, a0.z, a0.w, a1.x, a1.y, a1.z, a1.w,
                        a2.x, a2.y, a2.z, a2.w, a3.x, a3.y, a3.z, a3.w};
#pragma unroll
        for (int i = 0; i < 16; ++i)
#pragma unroll
            for (int j = 0; j < 4; ++j) acc[i][j] = fmaf(av[i], bv[j], acc[i][j]);
    }
    float4 xm4 = *(const float4*)(xx + b * 2048 + m0);
    float xm[4] = {xm4.x, xm4.y, xm4.z, xm4.w};

    int wave = t >> 6, lane = t & 63;

    {
        float4 xa0 = *(const float4*)(xx + b * 2048 + n0);
        float4 xa1 = *(const float4*)(xx + b * 2048 + n0 + 4);
        float xn[8] = {xa0.x, xa0.y, xa0.z, xa0.w, xa1.x, xa1.y, xa1.z, xa1.w};
#pragma unroll
        for (int i = 0; i < 8; ++i) {
            float4 o;
            o.x = (2.f * acc[i][0] - xn[i]) - xm[0];
            o.y = (2.f * acc[i][1] - xn[i]) - xm[1];
            o.z = (2.f * acc[i][2] - xn[i]) - xm[2];
            o.w = (2.f * acc[i][3] - xn[i]) - xm[3];
            *(float4*)(pd + i * 2048 + m0) = o;
        }
    }
    __syncthreads();
    topk_row(pd + wave * 2048, lane, idx_out + ((long)b * 2048 + n0 + wave) * KNNK);
    __syncthreads();

    {
        float4 xb0 = *(const float4*)(xx + b * 2048 + n0 + 8);
        float4 xb1 = *(const float4*)(xx + b * 2048 + n0 + 12);
        float xn[8] = {xb0.x, xb0.y, xb0.z, xb0.w, xb1.x, xb1.y, xb1.z, xb1.w};
#pragma unroll
        for (int i = 0; i < 8; ++i) {
            float4 o;
            o.x = (2.f * acc[8 + i][0] - xn[i]) - xm[0];
            o.y = (2.f * acc[8 + i][1] - xn[i]) - xm[1];
            o.z = (2.f * acc[8 + i][2] - xn[i]) - xm[2];
            o.w = (2.f * acc[8 + i][3] - xn[i]) - xm[3];
            *(float4*)(pd + i * 2048 + m0) = o;
        }
    }
    __syncthreads();
    topk_row(pd + wave * 2048, lane, idx_out + ((long)b * 2048 + n0 + 8 + wave) * KNNK);
}

// ---------------- P = Wa @ f, Q = (Wb - Wa) @ f, stored (B, N, 64) n-major ----------------
__global__ __launch_bounds__(256) void pq_kernel(const float* __restrict__ f, long bstride, int C,
                                                 const float* __restrict__ W, float* __restrict__ P,
                                                 float* __restrict__ Q) {
    __shared__ __align__(16) float wa[64 * 64];
    __shared__ __align__(16) float wq[64 * 64];
    __shared__ __align__(16) float X[64 * 64];
    int b = blockIdx.y, n0 = blockIdx.x * 64, t = threadIdx.x;
    const float* fb = f + (long)b * bstride;
    for (int e = t; e < C * 64; e += 256) {
        int k = e >> 6, c = e & 63;
        float a = W[c * 2 * C + k];
        float bv = W[c * 2 * C + C + k];
        wa[k * 64 + c] = a;
        wq[k * 64 + c] = bv - a;
    }
    for (int e = t; e < C * 64; e += 256) {
        int k = e >> 6, j = e & 63;
        X[e] = fb[k * 2048 + n0 + j];
    }
    __syncthreads();
    int cg = t >> 4, ng = t & 15;
    float accP[4][4] = {}, accQ[4][4] = {};
    for (int k = 0; k < C; ++k) {
        float4 a4 = *(const float4*)(wa + k * 64 + cg * 4);
        float4 q4 = *(const float4*)(wq + k * 64 + cg * 4);
        float4 x4 = *(const float4*)(X + k * 64 + ng * 4);
        float av[4] = {a4.x, a4.y, a4.z, a4.w};
        float qv[4] = {q4.x, q4.y, q4.z, q4.w};
        float xv[4] = {x4.x, x4.y, x4.z, x4.w};
#pragma unroll
        for (int i = 0; i < 4; ++i)
#pragma unroll
            for (int j = 0; j < 4; ++j) {
                accP[i][j] = fmaf(av[i], xv[j], accP[i][j]);
                accQ[i][j] = fmaf(qv[i], xv[j], accQ[i][j]);
            }
    }
#pragma unroll
    for (int j = 0; j < 4; ++j) {
        long n = n0 + ng * 4 + j;
        float4 pv = {accP[0][j], accP[1][j], accP[2][j], accP[3][j]};
        float4 qv = {accQ[0][j], accQ[1][j], accQ[2][j], accQ[3][j]};
        *(float4*)(P + ((long)b * 2048 + n) * 64 + cg * 4) = pv;
        *(float4*)(Q + ((long)b * 2048 + n) * 64 + cg * 4) = qv;
    }
}

// ---------------- 3-limb bf16 split of a 64x64 weight (elementwise, [co][ci] kept) ----------------
__global__ __launch_bounds__(256) void splitw3_kernel(const float* __restrict__ W, u16* __restrict__ h,
                                                      u16* __restrict__ m, u16* __restrict__ l) {
    int i = blockIdx.x * 256 + threadIdx.x;   // < 4096
    float v = W[i];
    u16 hh = f2bf(v);
    float r1 = v - bf2f(hh);
    u16 mm = f2bf(r1);
    float r2 = r1 - bf2f(mm);
    h[i] = hh;
    m[i] = mm;
    l[i] = f2bf(r2);
}

// ---------------- EdgeConv layer-2 + max over k via MFMA (bf16x6, stages 1 & 2) ----------------
__global__ __launch_bounds__(256) void edge2_mfma_kernel(
    const float* __restrict__ P, const float* __restrict__ Q, const int* __restrict__ idx,
    const u16* __restrict__ Wh, const u16* __restrict__ Wm, const u16* __restrict__ Wl,
    const float* __restrict__ sa, const float* __restrict__ ta, const float* __restrict__ sb,
    const float* __restrict__ tb, float* __restrict__ out, int cofs) {
    __shared__ __align__(16) float h1t[192 * 68];   // [col][ci] fp32, pad 68; reused as h2 [col][co]
    __shared__ int idxl[160];
    int b = blockIdx.y, n0 = blockIdx.x * 8, t = threadIdx.x;
    if (t < 160) idxl[t] = idx[((long)b * 2048 + n0) * KNNK + t];
    __syncthreads();

    for (int it = t; it < 2560; it += 256) {
        int col = it % 160, cg = it / 160;
        int p = col / 20;
        int j = idxl[col];
        int n = n0 + p;
        float4 pv = *(const float4*)(P + ((long)b * 2048 + j) * 64 + cg * 4);
        float4 qv = *(const float4*)(Q + ((long)b * 2048 + n) * 64 + cg * 4);
        float4 sv = *(const float4*)(sa + cg * 4);
        float4 tv = *(const float4*)(ta + cg * 4);
        float4 o;
        o.x = lrelu(fmaf(sv.x, pv.x + qv.x, tv.x));
        o.y = lrelu(fmaf(sv.y, pv.y + qv.y, tv.y));
        o.z = lrelu(fmaf(sv.z, pv.z + qv.z, tv.z));
        o.w = lrelu(fmaf(sv.w, pv.w + qv.w, tv.w));
        *(float4*)(h1t + col * 68 + cg * 4) = o;
    }
    for (int it = t; it < 512; it += 256) {
        int col = 160 + (it & 31), cg = it >> 5;
        float4 z = {0.f, 0.f, 0.f, 0.f};
        *(float4*)(h1t + col * 68 + cg * 4) = z;
    }
    __syncthreads();

    int wave = t >> 6, lane = t & 63, l15 = lane & 15, lq = lane >> 4;
    f32x4 acc[3][4];
#pragma unroll
    for (int ct = 0; ct < 3; ++ct)
#pragma unroll
        for (int mt = 0; mt < 4; ++mt) {
            f32x4 z = {0.f, 0.f, 0.f, 0.f};
            acc[ct][mt] = z;
        }

#pragma unroll
    for (int ct = 0; ct < 3; ++ct) {
        int col = (wave * 3 + ct) * 16 + l15;
        short8v bh[2], bm[2], bl[2];
#pragma unroll
        for (int kh = 0; kh < 2; ++kh) cvt8(h1t + col * 68 + kh * 32 + lq * 8, bh[kh], bm[kh], bl[kh]);
#pragma unroll
        for (int mt = 0; mt < 4; ++mt) {
#pragma unroll
            for (int kh = 0; kh < 2; ++kh) {
                int wo = (mt * 16 + l15) * 64 + kh * 32 + lq * 8;
                short8v ah = *(const short8v*)(Wh + wo);
                short8v am = *(const short8v*)(Wm + wo);
                short8v al = *(const short8v*)(Wl + wo);
                acc[ct][mt] = __builtin_amdgcn_mfma_f32_16x16x32_bf16(ah, bh[kh], acc[ct][mt], 0, 0, 0);
                acc[ct][mt] = __builtin_amdgcn_mfma_f32_16x16x32_bf16(ah, bm[kh], acc[ct][mt], 0, 0, 0);
                acc[ct][mt] = __builtin_amdgcn_mfma_f32_16x16x32_bf16(am, bh[kh], acc[ct][mt], 0, 0, 0);
                acc[ct][mt] = __builtin_amdgcn_mfma_f32_16x16x32_bf16(am, bm[kh], acc[ct][mt], 0, 0, 0);
                acc[ct][mt] = __builtin_amdgcn_mfma_f32_16x16x32_bf16(ah, bl[kh], acc[ct][mt], 0, 0, 0);
                acc[ct][mt] = __builtin_amdgcn_mfma_f32_16x16x32_bf16(al, bh[kh], acc[ct][mt], 0, 0, 0);
            }
        }
    }
    __syncthreads();

#pragma unroll
    for (int ct = 0; ct < 3; ++ct) {
        int col = (wave * 3 + ct) * 16 + l15;
#pragma unroll
        for (int mt = 0; mt < 4; ++mt) {
            float4 d = {acc[ct][mt][0], acc[ct][mt][1], acc[ct][mt][2], acc[ct][mt][3]};
            *(float4*)(h1t + col * 68 + mt * 16 + lq * 4) = d;
        }
    }
    __syncthreads();

    for (int id = t; id < 512; id += 256) {
        int co = id & 63, p = id >> 6;
        float sv = sb[co], tv = tb[co];
        float m = -INFINITY;
#pragma unroll 4
        for (int kk = 0; kk < KNNK; ++kk)
            m = fmaxf(m, lrelu(fmaf(sv, h1t[(p * 20 + kk) * 68 + co], tv)));
        out[(long)b * (192 * 2048) + (long)(cofs + co) * 2048 + n0 + p] = m;
    }
}

// ---------------- EdgeConv layer-2 fp32 (fallback path) ----------------
__global__ __launch_bounds__(256) void edge2_kernel(
    const float* __restrict__ P, const float* __restrict__ Q, const int* __restrict__ idx,
    const float* __restrict__ W2, const float* __restrict__ sa, const float* __restrict__ ta,
    const float* __restrict__ sb, const float* __restrict__ tb, float* __restrict__ out, int cofs) {
    __shared__ __align__(16) float h1[64 * 164];
    __shared__ __align__(16) float w2l[64 * 64];
    __shared__ int idxl[160];
    int b = blockIdx.y, n0 = blockIdx.x * 8, t = threadIdx.x;
    if (t < 160) idxl[t] = idx[((long)b * 2048 + n0) * KNNK + t];
    for (int e = t; e < 4096; e += 256) { int co = e >> 6, ci = e & 63; w2l[ci * 64 + co] = W2[e]; }
    __syncthreads();
    for (int it = t; it < 2560; it += 256) {
        int col = it % 160, cg = it / 160;
        int p = col / 20;
        int j = idxl[col];
        int n = n0 + p;
        float4 pv = *(const float4*)(P + ((long)b * 2048 + j) * 64 + cg * 4);
        float4 qv = *(const float4*)(Q + ((long)b * 2048 + n) * 64 + cg * 4);
        float4 sv = *(const float4*)(sa + cg * 4);
        float4 tv = *(const float4*)(ta + cg * 4);
        h1[(cg * 4 + 0) * 164 + col] = lrelu(fmaf(sv.x, pv.x + qv.x, tv.x));
        h1[(cg * 4 + 1) * 164 + col] = lrelu(fmaf(sv.y, pv.y + qv.y, tv.y));
        h1[(cg * 4 + 2) * 164 + col] = lrelu(fmaf(sv.z, pv.z + qv.z, tv.z));
        h1[(cg * 4 + 3) * 164 + col] = lrelu(fmaf(sv.w, pv.w + qv.w, tv.w));
    }
    __syncthreads();
    int p = t & 7, co2 = t >> 3, c0 = co2 * 2;
    float acc0[20], acc1[20];
#pragma unroll
    for (int q = 0; q < 20; ++q) { acc0[q] = 0.f; acc1[q] = 0.f; }
#pragma unroll 4
    for (int k = 0; k < 64; ++k) {
        float2 w = *(const float2*)(w2l + k * 64 + c0);
        const float* hr = h1 + k * 164 + p * 20;
#pragma unroll
        for (int q = 0; q < 5; ++q) {
            float4 h4 = *(const float4*)(hr + q * 4);
            acc0[q * 4 + 0] = fmaf(w.x, h4.x, acc0[q * 4 + 0]);
            acc0[q * 4 + 1] = fmaf(w.x, h4.y, acc0[q * 4 + 1]);
            acc0[q * 4 + 2] = fmaf(w.x, h4.z, acc0[q * 4 + 2]);
            acc0[q * 4 + 3] = fmaf(w.x, h4.w, acc0[q * 4 + 3]);
            acc1[q * 4 + 0] = fmaf(w.y, h4.x, acc1[q * 4 + 0]);
            acc1[q * 4 + 1] = fmaf(w.y, h4.y, acc1[q * 4 + 1]);
            acc1[q * 4 + 2] = fmaf(w.y, h4.z, acc1[q * 4 + 2]);
            acc1[q * 4 + 3] = fmaf(w.y, h4.w, acc1[q * 4 + 3]);
        }
    }
    float s0 = sb[c0], t0v = tb[c0], s1 = sb[c0 + 1], t1v = tb[c0 + 1];
    float m0 = -INFINITY, m1 = -INFINITY;
#pragma unroll
    for (int q = 0; q < 20; ++q) {
        m0 = fmaxf(m0, lrelu(fmaf(s0, acc0[q], t0v)));
        m1 = fmaxf(m1, lrelu(fmaf(s1, acc1[q], t1v)));
    }
    out[(long)b * (192 * 2048) + (long)(cofs + c0) * 2048 + n0 + p] = m0;
    out[(long)b * (192 * 2048) + (long)(cofs + c0 + 1) * 2048 + n0 + p] = m1;
}

// ---------------- Stage 3: gather + affine + lrelu + max over k ----------------
__global__ __launch_bounds__(256) void edge1_kernel(const float* __restrict__ P, const float* __restrict__ Q,
                                                    const int* __restrict__ idx, const float* __restrict__ s,
                                                    const float* __restrict__ tt, float* __restrict__ out,
                                                    int cofs) {
    __shared__ int idxl[80];
    int b = blockIdx.y, n0 = blockIdx.x * 4, t = threadIdx.x;
    int c = t & 63, p = t >> 6;
    if (t < 80) idxl[t] = idx[((long)b * 2048 + n0) * KNNK + t];
    __syncthreads();
    float qv = Q[((long)b * 2048 + n0 + p) * 64 + c];
    float sc = s[c], tc = tt[c];
    float m = -INFINITY;
    for (int kk = 0; kk < KNNK; ++kk) {
        int j = idxl[p * KNNK + kk];
        float v = P[((long)b * 2048 + j) * 64 + c];
        m = fmaxf(m, lrelu(fmaf(sc, v + qv, tc)));
    }
    out[(long)b * (192 * 2048) + (long)(cofs + c) * 2048 + n0 + p] = m;
}

// ---------------- FP32 head GEMM (fallback only, if workspace too small) ----------------
__global__ __launch_bounds__(256) void gemm_kernel(
    const float* __restrict__ W, int ldw, int Kdim, const float* __restrict__ X, long xbstride,
    const float* __restrict__ s, const float* __restrict__ tvec, const float* __restrict__ bias, int M,
    float* __restrict__ out, long obstride, float* __restrict__ maxout) {
    __shared__ __align__(16) float wl[32 * 68];
    __shared__ __align__(16) float xl[32 * 132];
    int b = blockIdx.z, ct = blockIdx.x * 64, nt = blockIdx.y * 128, t = threadIdx.x;
    const float* Xb = X + (long)b * xbstride;
    int cg = t >> 4, ng = t & 15;
    float acc[4][8];
#pragma unroll
    for (int i = 0; i < 4; ++i)
#pragma unroll
        for (int j = 0; j < 8; ++j) acc[i][j] = 0.f;
    for (int k0 = 0; k0 < Kdim; k0 += 32) {
        __syncthreads();
        for (int e = t; e < 2048; e += 256) {
            int c = e >> 5, k = e & 31;
            wl[k * 68 + c] = W[(long)(ct + c) * ldw + k0 + k];
        }
        for (int e = t; e < 4096; e += 256) {
            int k = e >> 7, j = e & 127;
            xl[k * 132 + j] = Xb[(long)(k0 + k) * 2048 + nt + j];
        }
        __syncthreads();
#pragma unroll 8
        for (int k = 0; k < 32; ++k) {
            float4 w4 = *(const float4*)(wl + k * 68 + cg * 4);
            float4 xa = *(const float4*)(xl + k * 132 + ng * 4);
            float4 xb = *(const float4*)(xl + k * 132 + 64 + ng * 4);
            float wv[4] = {w4.x, w4.y, w4.z, w4.w};
            float xv[8] = {xa.x, xa.y, xa.z, xa.w, xb.x, xb.y, xb.z, xb.w};
#pragma unroll
            for (int i = 0; i < 4; ++i)
#pragma unroll
                for (int j = 0; j < 8; ++j) acc[i][j] = fmaf(wv[i], xv[j], acc[i][j]);
        }
    }
    if (maxout) {
        __syncthreads();
        float* scr = xl;
#pragma unroll
        for (int i = 0; i < 4; ++i) {
            int c = ct + cg * 4 + i;
            float sv = s[c], tv = tvec[c];
            float m = -INFINITY;
#pragma unroll
            for (int j = 0; j < 8; ++j) m = fmaxf(m, lrelu(fmaf(sv, acc[i][j], tv)));
            scr[(cg * 4 + i) * 16 + ng] = m;
        }
        __syncthreads();
        if (t < 64) {
            float m = scr[t * 16];
            for (int j = 1; j < 16; ++j) m = fmaxf(m, scr[t * 16 + j]);
            maxout[((long)b * M + ct + t) * 16 + blockIdx.y] = m;
        }
    } else {
#pragma unroll
        for (int i = 0; i < 4; ++i) {
            int c = ct + cg * 4 + i;
            float bv = bias ? bias[b * M + c] : 0.f;
            float sv = s[c], tv = tvec[c];
            float4 o0, o1;
            o0.x = lrelu(fmaf(sv, acc[i][0] + bv, tv));
            o0.y = lrelu(fmaf(sv, acc[i][1] + bv, tv));
            o0.z = lrelu(fmaf(sv, acc[i][2] + bv, tv));
            o0.w = lrelu(fmaf(sv, acc[i][3] + bv, tv));
            o1.x = lrelu(fmaf(sv, acc[i][4] + bv, tv));
            o1.y = lrelu(fmaf(sv, acc[i][5] + bv, tv));
            o1.z = lrelu(fmaf(sv, acc[i][6] + bv, tv));
            o1.w = lrelu(fmaf(sv, acc[i][7] + bv, tv));
            float* op = out + (long)b * obstride + (long)c * 2048 + nt + ng * 4;
            *(float4*)op = o0;
            *(float4*)(op + 64) = o1;
        }
    }
}

// ---------------- bf16 hi/lo split of a weight matrix: W[m][koff+k] -> packed [M][K] ----------------
__global__ __launch_bounds__(256) void splitw_kernel(const float* __restrict__ W, int ldw, int koff, int K,
                                                     long total, u16* __restrict__ hi, u16* __restrict__ lo) {
    long i = (long)blockIdx.x * 256 + threadIdx.x;
    if (i >= total) return;
    long m = i / K, k = i - m * K;
    float v = W[m * ldw + koff + k];
    u16 h = f2bf(v);
    hi[i] = h;
    lo[i] = f2bf(v - bf2f(h));
}

// ---------------- cat f32 [b][192][2048] -> split-transposed bf16 [b][2048][192] ----------------
__global__ __launch_bounds__(256) void splitx_kernel(const float* __restrict__ cat, u16* __restrict__ hi,
                                                     u16* __restrict__ lo) {
    __shared__ float lds[32][65];
    int b = blockIdx.y;
    int kt = blockIdx.x % 6, nt = blockIdx.x / 6;
    int k0 = kt * 32, n0 = nt * 64;
    int t = threadIdx.x;
#pragma unroll
    for (int i = 0; i < 8; ++i) {
        int e = t + i * 256;
        int k = e >> 6, n = e & 63;
        lds[k][n] = cat[(long)b * (192 * 2048) + (long)(k0 + k) * 2048 + n0 + n];
    }
    __syncthreads();
    int n = t >> 2, kq = t & 3;
    u16 hv[8], lv[8];
#pragma unroll
    for (int i = 0; i < 8; ++i) {
        float v = lds[kq * 8 + i][n];
        u16 h = f2bf(v);
        hv[i] = h;
        lv[i] = f2bf(v - bf2f(h));
    }
    long off = ((long)b * 2048 + n0 + n) * 192 + k0 + kq * 8;
    uint4 uh, ul;
    uh.x = (u32)hv[0] | ((u32)hv[1] << 16); uh.y = (u32)hv[2] | ((u32)hv[3] << 16);
    uh.z = (u32)hv[4] | ((u32)hv[5] << 16); uh.w = (u32)hv[6] | ((u32)hv[7] << 16);
    ul.x = (u32)lv[0] | ((u32)lv[1] << 16); ul.y = (u32)lv[2] | ((u32)lv[3] << 16);
    ul.z = (u32)lv[4] | ((u32)lv[5] << 16); ul.w = (u32)lv[6] | ((u32)lv[7] << 16);
    *(uint4*)(hi + off) = uh;
    *(uint4*)(lo + off) = ul;
}

// ---------------- bf16x3 MFMA head GEMM ----------------
template <int MT, int NT, bool MAXOUT>
__global__ __launch_bounds__(256, 2) void gemm_mfma(
    const u16* __restrict__ Whi, const u16* __restrict__ Wlo, const u16* __restrict__ Xhi,
    const u16* __restrict__ Xlo, int K, int M, const float* __restrict__ s,
    const float* __restrict__ tvec, const float* __restrict__ bias, float* __restrict__ outf,
    long obstride, u16* __restrict__ ohi, u16* __restrict__ olo, int oK, float* __restrict__ maxout) {
    constexpr int BM = MT * 32, BN = NT * 32;
    __shared__ __align__(16) u16 Ah[BM * 32], Al[BM * 32], Bh[BN * 32], Bl[BN * 32];
    __shared__ float scr[MAXOUT ? BM * 2 : 1];

    int b = blockIdx.z;
    int m0 = blockIdx.x * BM;
    int n0 = blockIdx.y * BN;
    int t = threadIdx.x;
    int wave = t >> 6, lane = t & 63;
    int wm = (wave >> 1) * (MT * 16);
    int wn = (wave & 1) * (NT * 16);
    const int l15 = lane & 15, lq = lane >> 4;
    const int kcs = lq ^ ((l15 >> 1) & 3);

    const u16* Xbh = Xhi + (long)b * 2048 * K;
    const u16* Xbl = Xlo + (long)b * 2048 * K;

    f32x4 zero4 = {0.f, 0.f, 0.f, 0.f};
    f32x4 acc[MT][NT];
#pragma unroll
    for (int i = 0; i < MT; ++i)
#pragma unroll
        for (int j = 0; j < NT; ++j) acc[i][j] = zero4;

    for (int k0 = 0; k0 < K; k0 += 32) {
        __syncthreads();
#pragma unroll
        for (int u = t; u < BM * 4; u += 256) {
            int row = u >> 2, kc = (u & 3) ^ ((row >> 1) & 3);
            long ga = (long)(m0 + row) * K + k0 + kc * 8;
            *(uint4*)(Ah + u * 8) = *(const uint4*)(Whi + ga);
            *(uint4*)(Al + u * 8) = *(const uint4*)(Wlo + ga);
        }
#pragma unroll
        for (int u = t; u < BN * 4; u += 256) {
            int row = u >> 2, kc = (u & 3) ^ ((row >> 1) & 3);
            long ga = (long)(n0 + row) * K + k0 + kc * 8;
            *(uint4*)(Bh + u * 8) = *(const uint4*)(Xbh + ga);
            *(uint4*)(Bl + u * 8) = *(const uint4*)(Xbl + ga);
        }
        __syncthreads();
        short8v a_h[MT], a_l[MT], b_h[NT], b_l[NT];
#pragma unroll
        for (int i = 0; i < MT; ++i) {
            int u = (wm + i * 16 + l15) * 4 + kcs;
            a_h[i] = *(const short8v*)(Ah + u * 8);
            a_l[i] = *(const short8v*)(Al + u * 8);
        }
#pragma unroll
        for (int j = 0; j < NT; ++j) {
            int u = (wn + j * 16 + l15) * 4 + kcs;
            b_h[j] = *(const short8v*)(Bh + u * 8);
            b_l[j] = *(const short8v*)(Bl + u * 8);
        }
#pragma unroll
        for (int i = 0; i < MT; ++i)
#pragma unroll
            for (int j = 0; j < NT; ++j) {
                acc[i][j] = __builtin_amdgcn_mfma_f32_16x16x32_bf16(a_h[i], b_h[j], acc[i][j], 0, 0, 0);
                acc[i][j] = __builtin_amdgcn_mfma_f32_16x16x32_bf16(a_h[i], b_l[j], acc[i][j], 0, 0, 0);
                acc[i][j] = __builtin_amdgcn_mfma_f32_16x16x32_bf16(a_l[i], b_h[j], acc[i][j], 0, 0, 0);
            }
    }

    if constexpr (MAXOUT) {
#pragma unroll
        for (int i = 0; i < MT; ++i)
#pragma unroll
            for (int r = 0; r < 4; ++r) {
                int ml = wm + i * 16 + lq * 4 + r;
                int c = m0 + ml;
                float sv = s[c], tv = tvec[c];
                float mx = -INFINITY;
#pragma unroll
                for (int j = 0; j < NT; ++j) mx = fmaxf(mx, lrelu(fmaf(sv, acc[i][j][r], tv)));
                mx = fmaxf(mx, __shfl_xor(mx, 1));
                mx = fmaxf(mx, __shfl_xor(mx, 2));
                mx = fmaxf(mx, __shfl_xor(mx, 4));
                mx = fmaxf(mx, __shfl_xor(mx, 8));
                if (l15 == 0) scr[ml * 2 + (wave & 1)] = mx;
            }
        __syncthreads();
        if (t < BM) maxout[((long)b * M + m0 + t) * 16 + blockIdx.y] = fmaxf(scr[t * 2], scr[t * 2 + 1]);
    } else if (outf) {
#pragma unroll
        for (int i = 0; i < MT; ++i)
#pragma unroll
            for (int r = 0; r < 4; ++r) {
                int c = m0 + wm + i * 16 + lq * 4 + r;
                float sv = s[c], tv = tvec[c];
                float bv = bias ? bias[b * M + c] : 0.f;
                float* op = outf + (long)b * obstride + (long)c * 2048 + n0 + wn;
#pragma unroll
                for (int j = 0; j < NT; ++j) op[j * 16 + l15] = lrelu(fmaf(sv, acc[i][j][r] + bv, tv));
            }
    } else {
#pragma unroll
        for (int i = 0; i < MT; ++i) {
            float sv[4], tv[4], bv[4];
#pragma unroll
            for (int r = 0; r < 4; ++r) {
                int c = m0 + wm + i * 16 + lq * 4 + r;
                sv[r] = s[c];
                tv[r] = tvec[c];
                bv[r] = bias ? bias[b * M + c] : 0.f;
            }
#pragma unroll
            for (int j = 0; j < NT; ++j) {
                long nb = ((long)b * 2048 + n0 + wn + j * 16 + l15) * oK + m0 + wm + i * 16 + lq * 4;
                ushort4 uh, ul;
                float v0 = lrelu(fmaf(sv[0], acc[i][j][0] + bv[0], tv[0]));
                float v1 = lrelu(fmaf(sv[1], acc[i][j][1] + bv[1], tv[1]));
                float v2 = lrelu(fmaf(sv[2], acc[i][j][2] + bv[2], tv[2]));
                float v3 = lrelu(fmaf(sv[3], acc[i][j][3] + bv[3], tv[3]));
                u16 h0 = f2bf(v0), h1 = f2bf(v1), h2 = f2bf(v2), h3 = f2bf(v3);
                uh.x = h0; uh.y = h1; uh.z = h2; uh.w = h3;
                ul.x = f2bf(v0 - bf2f(h0));
                ul.y = f2bf(v1 - bf2f(h1));
                ul.z = f2bf(v2 - bf2f(h2));
                ul.w = f2bf(v3 - bf2f(h3));
                *(ushort4*)(ohi + nb) = uh;
                *(ushort4*)(olo + nb) = ul;
            }
        }
    }
}

// ---------------- finalize g = max over the 16 n-tile partials ----------------
__global__ __launch_bounds__(256) void gmax_final(const float* __restrict__ ep, float* __restrict__ g) {
    int i = blockIdx.x * 256 + threadIdx.x;
    float m = ep[i * 16];
    for (int j = 1; j < 16; ++j) m = fmaxf(m, ep[i * 16 + j]);
    g[i] = m;
}

// ---------------- bias7[b][co] = w7[co, :1024] @ g[b] ----------------
__global__ __launch_bounds__(64) void bias7_kernel(const float* __restrict__ w7, const float* __restrict__ g,
                                                   float* __restrict__ bias7) {
    int o = blockIdx.x;
    int b = o >> 9, co = o & 511;
    int lane = threadIdx.x;
    float acc = 0.f;
    for (int j = lane; j < 1024; j += 64) acc = fmaf(w7[(long)co * 1216 + j], g[b * 1024 + j], acc);
#pragma unroll
    for (int off = 32; off >= 1; off >>= 1) acc += __shfl_xor(acc, off);
    if (lane == 0) bias7[o] = acc;
}

// ---------------- y[b][n] = sigmoid(w9 @ h8[:, n]) ----------------
__global__ __launch_bounds__(256) void w9_kernel(const float* __restrict__ w9, const float* __restrict__ h8,
                                                 float* __restrict__ out) {
    int i = blockIdx.x * 256 + threadIdx.x;
    int b = i >> 11, n = i & 2047;
    const float* hb = h8 + (long)b * 256 * 2048 + n;
    float acc = 0.f;
    for (int c = 0; c < 256; ++c) acc = fmaf(w9[c], hb[c * 2048], acc);
    out[i] = 1.f / (1.f + expf(-acc));
}

extern "C" void kernel_launch(void* const* d_in, const int* in_sizes, int n_in,
                              void* d_out, int out_size, void* d_ws, size_t ws_size,
                              hipStream_t stream) {
    (void)in_sizes; (void)n_in; (void)out_size;
    const float* x  = (const float*)d_in[0];
    const float* w1 = (const float*)d_in[1];
    const float* w2 = (const float*)d_in[2];
    const float* w3 = (const float*)d_in[3];
    const float* w4 = (const float*)d_in[4];
    const float* w5 = (const float*)d_in[5];
    const float* w6 = (const float*)d_in[6];
    const float* w7 = (const float*)d_in[7];
    const float* w8 = (const float*)d_in[8];
    const float* w9 = (const float*)d_in[9];
    const float* s1 = (const float*)d_in[10]; const float* t1 = (const float*)d_in[11];
    const float* s2 = (const float*)d_in[12]; const float* t2 = (const float*)d_in[13];
    const float* s3 = (const float*)d_in[14]; const float* t3 = (const float*)d_in[15];
    const float* s4 = (const float*)d_in[16]; const float* t4 = (const float*)d_in[17];
    const float* s5 = (const float*)d_in[18]; const float* t5 = (const float*)d_in[19];
    const float* s6 = (const float*)d_in[20]; const float* t6 = (const float*)d_in[21];
    const float* s7 = (const float*)d_in[22]; const float* t7 = (const float*)d_in[23];
    const float* s8 = (const float*)d_in[24]; const float* t8 = (const float*)d_in[25];

    // workspace partition (floats, then ushorts)
    float* cat = (float*)d_ws;                       // 16*192*2048      = 6291456
    float* xxb = cat + (long)6291456;                // 16*2048          = 32768
    int* idxb = (int*)(xxb + 32768);                 // 16*2048*20 ints  = 655360
    float* ep = (float*)(idxb + 655360);             // 16*1024*16       = 262144
    float* g  = ep + 262144;                         // 16*1024          = 16384
    float* b7 = g + 16384;                           // 16*512           = 8192
    float* h8 = b7 + 8192;                           // 16*256*2048      = 8388608
    float* P  = h8 + 8388608;                        // 16*2048*64       = 2097152
    float* Q  = P + 2097152;                         // 16*2048*64       = 2097152
    u16* h7hi = (u16*)(Q + 2097152);                 // 16*2048*512 u16  = 16777216
    u16* h7lo = h7hi + 16777216;
    u16* cathi = h7lo + 16777216;                    // 16*2048*192 u16  = 6291456
    u16* catlo = cathi + 6291456;
    u16* w6h = catlo + 6291456;                      // 1024*192 = 196608
    u16* w6l = w6h + 196608;
    u16* w7h = w6l + 196608;                         // 512*192 = 98304
    u16* w7l = w7h + 98304;
    u16* w8h = w7l + 98304;                          // 256*512 = 131072
    u16* w8l = w8h + 131072;
    const size_t NEED = 173375488;                   // bytes for the full mfma layout
    bool big = ws_size >= NEED;

    // edge2 weight limbs alias the start of the h7 region (dead until the head)
    u16* w2L = h7hi;            // w2: h at +0, m at +4096, l at +8192
    u16* w4L = h7hi + 12288;    // w4 likewise

    dim3 blk(256);
    dim3 blk512(512);
    long catstride = 192 * 2048;

    if (big) {
        splitw3_kernel<<<16, blk, 0, stream>>>(w2, w2L, w2L + 4096, w2L + 8192);
        splitw3_kernel<<<16, blk, 0, stream>>>(w4, w4L, w4L + 4096, w4L + 8192);
    }

    // ---- stage 1 (C=2) ----
    xx_kernel<<<128, blk, 0, stream>>>(x, 2 * 2048, 2, xxb);
    knn_kernel<<<dim3(128, 16), blk512, 0, stream>>>(x, 2 * 2048, 2, xxb, idxb);
    pq_kernel<<<dim3(32, 16), blk, 0, stream>>>(x, 2 * 2048, 2, w1, P, Q);
    if (big)
        edge2_mfma_kernel<<<dim3(256, 16), blk, 0, stream>>>(P, Q, idxb, w2L, w2L + 4096, w2L + 8192,
                                                             s1, t1, s2, t2, cat, 0);
    else
        edge2_kernel<<<dim3(256, 16), blk, 0, stream>>>(P, Q, idxb, w2, s1, t1, s2, t2, cat, 0);
    // ---- stage 2 (C=64 on x1) ----
    xx_kernel<<<128, blk, 0, stream>>>(cat, catstride, 64, xxb);
    knn_kernel<<<dim3(128, 16), blk512, 0, stream>>>(cat, catstride, 64, xxb, idxb);
    pq_kernel<<<dim3(32, 16), blk, 0, stream>>>(cat, catstride, 64, w3, P, Q);
    if (big)
        edge2_mfma_kernel<<<dim3(256, 16), blk, 0, stream>>>(P, Q, idxb, w4L, w4L + 4096, w4L + 8192,
                                                             s3, t3, s4, t4, cat, 64);
    else
        edge2_kernel<<<dim3(256, 16), blk, 0, stream>>>(P, Q, idxb, w4, s3, t3, s4, t4, cat, 64);
    // ---- stage 3 (C=64 on x2) ----
    xx_kernel<<<128, blk, 0, stream>>>(cat + 64 * 2048, catstride, 64, xxb);
    knn_kernel<<<dim3(128, 16), blk512, 0, stream>>>(cat + 64 * 2048, catstride, 64, xxb, idxb);
    pq_kernel<<<dim3(32, 16), blk, 0, stream>>>(cat + 64 * 2048, catstride, 64, w5, P, Q);
    edge1_kernel<<<dim3(512, 16), blk, 0, stream>>>(P, Q, idxb, s5, t5, cat, 128);

    if (big) {
        // ---- head: bf16x3 MFMA path ----
        splitw_kernel<<<768, blk, 0, stream>>>(w6, 192, 0, 192, 196608, w6h, w6l);
        splitw_kernel<<<384, blk, 0, stream>>>(w7, 1216, 1024, 192, 98304, w7h, w7l);
        splitw_kernel<<<512, blk, 0, stream>>>(w8, 512, 0, 512, 131072, w8h, w8l);
        splitx_kernel<<<dim3(192, 16), blk, 0, stream>>>(cat, cathi, catlo);
        gemm_mfma<4, 4, true><<<dim3(8, 16, 16), blk, 0, stream>>>(
            w6h, w6l, cathi, catlo, 192, 1024, s6, t6, nullptr, nullptr, 0, nullptr, nullptr, 0, ep);
        gmax_final<<<64, blk, 0, stream>>>(ep, g);
        bias7_kernel<<<dim3(16 * 512), dim3(64), 0, stream>>>(w7, g, b7);
        gemm_mfma<4, 4, false><<<dim3(4, 16, 16), blk, 0, stream>>>(
            w7h, w7l, cathi, catlo, 192, 512, s7, t7, b7, nullptr, 0, h7hi, h7lo, 512, nullptr);
        gemm_mfma<2, 4, false><<<dim3(4, 16, 16), blk, 0, stream>>>(
            w8h, w8l, h7hi, h7lo, 512, 256, s8, t8, nullptr, h8, (long)256 * 2048, nullptr, nullptr, 0,
            nullptr);
        w9_kernel<<<128, blk, 0, stream>>>(w9, h8, (float*)d_out);
    } else {
        // ---- head: fp32 fallback ----
        float* h7f = (float*)h7hi;
        gemm_kernel<<<dim3(16, 16, 16), blk, 0, stream>>>(w6, 192, 192, cat, catstride, s6, t6, nullptr,
                                                          1024, nullptr, 0, ep);
        gmax_final<<<64, blk, 0, stream>>>(ep, g);
        bias7_kernel<<<dim3(16 * 512), dim3(64), 0, stream>>>(w7, g, b7);
        gemm_kernel<<<dim3(8, 16, 16), blk, 0, stream>>>(w7 + 1024, 1216, 192, cat, catstride, s7, t7, b7,
                                                         512, h7f, (long)512 * 2048, nullptr);
        gemm_kernel<<<dim3(4, 16, 16), blk, 0, stream>>>(w8, 512, 512, h7f, (long)512 * 2048, s8, t8,
                                                         nullptr, 256, h8, (long)256 * 2048, nullptr);
        w9_kernel<<<128, blk, 0, stream>>>(w9, h8, (float*)d_out);
    }
}